// Round 4
// baseline (498.689 us; speedup 1.0000x reference)
//
#include <hip/hip_runtime.h>
#include <hip/hip_bf16.h>

#define T_ 4
#define N_ 20000
#define E_ 320000
#define R_ 2
#define DIN 64
#define G_ 256   // H*Dh
#define P_ 8     // T*R
#define BPAD 18432  // 256 * 72 padded B-table halves per 64-k chunk
#define NB_ 32      // CSR-build blocks per p
#define EPB_ 10000  // edges per CSR-build block
#define CHN_ 625    // nodes per scan chunk (N_/32)

typedef unsigned short u16;
typedef __attribute__((ext_vector_type(8))) short bf16x8;
typedef __attribute__((ext_vector_type(4))) float f32x4;

__device__ __forceinline__ float bf2f(u16 u) {
    unsigned int i = ((unsigned int)u) << 16; float f;
    __builtin_memcpy(&f, &i, 4); return f;
}
__device__ __forceinline__ u16 f2bf(float f) {
    unsigned int i; __builtin_memcpy(&i, &f, 4);
    unsigned int r = i + 0x7fffu + ((i >> 16) & 1u);
    return (u16)(r >> 16);
}
__device__ __forceinline__ float sigm(float x) { return 1.f / (1.f + __expf(-x)); }
// fast tanh: 1 - 2/(exp(2x)+1); hardware v_exp_f32, correct saturation at +-inf
__device__ __forceinline__ float ftanh(float x) { return 1.f - 2.f / (__expf(2.f * x) + 1.f); }
// broadcast lane l's float to all lanes (SGPR result); l must be wave-uniform
__device__ __forceinline__ float rdlanef(float v, int l) {
    int i; __builtin_memcpy(&i, &v, 4);
    int r = __builtin_amdgcn_readlane(i, l);
    float f; __builtin_memcpy(&f, &r, 4); return f;
}

// ---------------- LDS-free MFMA GEMM core (bf16 A) ----------------
__device__ __forceinline__ void gemm_direct(
    const u16* __restrict__ A, const u16* __restrict__ Bpad,
    int M, int Astride, int kchunks, int m0, f32x4* acc)
{
    const int tid = threadIdx.x;
    const int lane = tid & 63, wv = tid >> 6;
    const int col = lane & 15, quad = lane >> 4;
    #pragma unroll
    for (int cf = 0; cf < 16; ++cf) { acc[cf][0]=0.f; acc[cf][1]=0.f; acc[cf][2]=0.f; acc[cf][3]=0.f; }

    int row = m0 + wv * 16 + col;
    int row_c = (row < M) ? row : (M - 1);

    for (int kc = 0; kc < kchunks; ++kc) {
        #pragma unroll
        for (int ks = 0; ks < 2; ++ks) {
            bf16x8 a = *(const bf16x8*)(A + (size_t)row_c * Astride + kc * 64 + ks * 32 + quad * 8);
            const u16* bb = Bpad + kc * BPAD + ks * 32 + quad * 8;
            #pragma unroll
            for (int cf = 0; cf < 16; ++cf) {
                bf16x8 b = *(const bf16x8*)(bb + (cf * 16 + col) * 72);
                acc[cf] = __builtin_amdgcn_mfma_f32_16x16x32_bf16(a, b, acc[cf], 0, 0, 0);
            }
        }
    }
}

// ---------------- fold: als/ald GEMVs + x->bf16 cast; wdall staged in LDS ----------------
__global__ __launch_bounds__(256) void k_fold(
    const float* __restrict__ x, const float* __restrict__ wdall,
    float* __restrict__ als_all, float* __restrict__ ald_all, u16* __restrict__ x_bf)
{
    __shared__ float wds[1024];
    {
        int tid = threadIdx.x;
        *(float4*)(wds + tid * 4) = *(const float4*)(wdall + tid * 4);
    }
    __syncthreads();

    int t = blockIdx.y;
    int idx = blockIdx.x * 256 + threadIdx.x;
    if (idx >= N_ * 4) return;
    int n = idx >> 2, q = idx & 3;
    const float* xr = x + ((size_t)t * N_ + n) * 64 + q * 16;
    float4 xv[4];
    #pragma unroll
    for (int i = 0; i < 4; ++i) xv[i] = *(const float4*)(xr + i * 4);

    {
        union { u16 h[16]; ushort4 s4[4]; } cv;
        #pragma unroll
        for (int i = 0; i < 4; ++i) {
            cv.h[i*4+0] = f2bf(xv[i].x); cv.h[i*4+1] = f2bf(xv[i].y);
            cv.h[i*4+2] = f2bf(xv[i].z); cv.h[i*4+3] = f2bf(xv[i].w);
        }
        u16* xo = x_bf + ((size_t)t * N_ + n) * 64 + q * 16;
        #pragma unroll
        for (int i = 0; i < 4; ++i) *(ushort4*)(xo + i * 4) = cv.s4[i];
    }

    float s[16];
    #pragma unroll
    for (int i = 0; i < 16; ++i) s[i] = 0.f;
    #pragma unroll
    for (int i = 0; i < 4; ++i) {
        float xe[4] = {xv[i].x, xv[i].y, xv[i].z, xv[i].w};
        #pragma unroll
        for (int e = 0; e < 4; ++e) {
            int k = q * 16 + i * 4 + e;
            float xk = xe[e];
            #pragma unroll
            for (int tb = 0; tb < 4; ++tb) {
                float4 w = *(const float4*)(wds + tb * 256 + k * 4);
                s[tb*4+0] += xk * w.x; s[tb*4+1] += xk * w.y;
                s[tb*4+2] += xk * w.z; s[tb*4+3] += xk * w.w;
            }
        }
    }
    #pragma unroll
    for (int i = 0; i < 16; ++i) {
        s[i] += __shfl_xor(s[i], 1);
        s[i] += __shfl_xor(s[i], 2);
    }
    if (q == 0) {
        *(float4*)(als_all + ((size_t)(t*2+0) * N_ + n) * 4) = make_float4(s[0], s[1], s[2], s[3]);
        *(float4*)(als_all + ((size_t)(t*2+1) * N_ + n) * 4) = make_float4(s[4], s[5], s[6], s[7]);
        *(float4*)(ald_all + ((size_t)(t*2+0) * N_ + n) * 4) = make_float4(s[8], s[9], s[10], s[11]);
        *(float4*)(ald_all + ((size_t)(t*2+1) * N_ + n) * 4) = make_float4(s[12], s[13], s[14], s[15]);
    }
}

// ---------------- prep: folded GEMV tables, padded B-tables, folded bias ----------------
__global__ void k_prep(const float* __restrict__ Wdst, const float* __restrict__ att_dst,
                       const float* __restrict__ Wih, const float* __restrict__ Whh,
                       const float* __restrict__ bih, const float* __restrict__ bhh,
                       const float* __restrict__ Wsrc, const float* __restrict__ att_src,
                       const float* __restrict__ raW1,
                       const float* __restrict__ Wq, const float* __restrict__ Wk,
                       const float* __restrict__ Wv,
                       float* __restrict__ wdall, float* __restrict__ biasv,
                       u16* __restrict__ raW1_pad, u16* __restrict__ Wc_pad,
                       u16* __restrict__ qkv_pad, u16* __restrict__ postB_pad)
{
    int tid = threadIdx.x, bid = blockIdx.x;
    if (bid == 0) {
        int k = tid >> 2, h = tid & 3;
        for (int r = 0; r < 2; ++r) {
            float ss = 0.f, sd = 0.f;
            for (int c = 0; c < 64; ++c) {
                ss += Wsrc[((size_t)r * 64 + k) * 256 + h * 64 + c] * att_src[r * 256 + h * 64 + c];
                sd += Wdst[((size_t)r * 64 + k) * 256 + h * 64 + c] * att_dst[r * 256 + h * 64 + c];
            }
            wdall[r * 256 + k * 4 + h] = ss;
            wdall[512 + r * 256 + k * 4 + h] = sd;
        }
        biasv[tid] = bih[tid] + bhh[tid];
    }
    for (int i = bid * 256 + tid; i < BPAD; i += gridDim.x * 256) {
        int n = i / 72, kk = i % 72;
        raW1_pad[i] = (kk < 64) ? f2bf(raW1[kk * 256 + n]) : (u16)0;
    }
    for (int i = bid * 256 + tid; i < 2 * BPAD; i += gridDim.x * 256) {
        int kc = i / BPAD, q = i % BPAD, n = q / 72, kk = q % 72;
        const float* W = kc ? Whh : Wih;
        Wc_pad[i] = (kk < 64) ? f2bf(W[n * 64 + kk]) : (u16)0;
    }
    for (int i = bid * 256 + tid; i < 192 * 72; i += gridDim.x * 256) {
        int g = i / 72, kk = i % 72;
        int j = g >> 6, c = g & 63;
        const float* W = (j == 0) ? Wq : (j == 1) ? Wk : Wv;
        qkv_pad[i] = (kk < 64) ? f2bf(W[kk * 64 + c]) : (u16)0;
    }
    for (int i = bid * 256 + tid; i < 2 * 4 * 4608; i += gridDim.x * 256) {
        int r = i / 18432, q = i % 18432, kc = q / 4608, qq = q % 4608;
        int c = qq / 72, kk = qq % 72;
        postB_pad[i] = (kk < 64) ? f2bf(Wsrc[(size_t)r * 16384 + kk * 256 + kc * 64 + c]) : (u16)0;
    }
}

// ---------------- CSR build ----------------
__global__ __launch_bounds__(256) void k_hist(const int* __restrict__ ei,
                                              u16* __restrict__ rank, u16* __restrict__ partial)
{
    __shared__ unsigned int hist[N_ / 2];
    int b = blockIdx.x, p = blockIdx.y, tid = threadIdx.x;
    for (int i = tid; i < N_ / 2; i += 256) hist[i] = 0u;
    __syncthreads();
    const int* dsts = ei + ((size_t)p * 2 + 1) * E_ + b * EPB_;
    u16* rk = rank + (size_t)p * E_ + b * EPB_;
    for (int e = tid; e < EPB_; e += 256) {
        int dst = dsts[e];
        unsigned sh = (unsigned)(dst & 1) * 16u;
        unsigned old = atomicAdd(&hist[dst >> 1], 1u << sh);
        rk[e] = (u16)((old >> sh) & 0xffffu);
    }
    __syncthreads();
    u16* part = partial + ((size_t)p * NB_ + b) * N_;
    for (int n = tid; n < N_; n += 256) {
        unsigned hv = hist[n >> 1];
        part[n] = (u16)((hv >> ((unsigned)(n & 1) * 16u)) & 0xffffu);
    }
}

__global__ __launch_bounds__(256) void k_scan1(u16* __restrict__ partial,
                                               int* __restrict__ offsets, int* __restrict__ chunktot)
{
    int p = blockIdx.y, ch = blockIdx.x;
    int tid = threadIdx.x, lane = tid & 63, wid = tid >> 6;
    __shared__ int wtot[4];
    u16* part = partial + (size_t)p * NB_ * N_;
    int* ofs = offsets + (size_t)p * (N_ + 1);
    int n0 = ch * CHN_;
    int carry = 0;
    for (int rnd = 0; rnd < 3; ++rnd) {
        int i = rnd * 256 + tid;
        int n = n0 + i;
        int v = 0;
        if (i < CHN_) {
            int run = 0;
            #pragma unroll 8
            for (int b = 0; b < NB_; ++b) {
                int pv = part[b * N_ + n];
                part[b * N_ + n] = (u16)run;
                run += pv;
            }
            v = run;
        }
        int incl = v;
        for (int d = 1; d < 64; d <<= 1) { int u = __shfl_up(incl, d); if (lane >= d) incl += u; }
        if (lane == 63) wtot[wid] = incl;
        __syncthreads();
        if (tid < 4) {
            int iv = wtot[tid];
            for (int d = 1; d < 4; d <<= 1) { int u = __shfl_up(iv, d); if (tid >= d) iv += u; }
            wtot[tid] = iv;
        }
        __syncthreads();
        int woff = (wid > 0) ? wtot[wid - 1] : 0;
        int tot = wtot[3];
        int excl = carry + woff + incl - v;
        if (i < CHN_) ofs[n] = excl;
        carry += tot;
        __syncthreads();
    }
    if (tid == 0) chunktot[p * NB_ + ch] = carry;
}

__global__ void k_scan2(const int* __restrict__ chunktot, int* __restrict__ chunkbase) {
    int tid = threadIdx.x;
    if (tid < P_) {
        int run = 0;
        for (int c = 0; c < NB_; ++c) {
            chunkbase[tid * NB_ + c] = run;
            run += chunktot[tid * NB_ + c];
        }
    }
}

__global__ void k_scan3(int* __restrict__ offsets, const int* __restrict__ chunkbase) {
    int p = blockIdx.y;
    int n = blockIdx.x * 256 + threadIdx.x;
    if (n < N_)
        offsets[(size_t)p * (N_ + 1) + n] += chunkbase[p * NB_ + n / CHN_];
    if (n == 0)
        offsets[(size_t)p * (N_ + 1) + N_] = E_;
}

// 1-D grid, p = bid & 7: round-robin dispatch pins each p to one XCD, so the
// random 2B csr writes (640 KB/p) stay in that XCD's L2 (kills the 8x write amp).
__global__ void k_scatter(const int* __restrict__ ei, const int* __restrict__ offsets,
                          const u16* __restrict__ rank, const u16* __restrict__ partial,
                          u16* __restrict__ csr) {
    int bid = blockIdx.x;
    int p = bid & 7;
    int e = (bid >> 3) * 256 + threadIdx.x;
    int src = ei[((size_t)p * 2 + 0) * E_ + e];
    int dst = ei[((size_t)p * 2 + 1) * E_ + e];
    int b = e / EPB_;
    int pos = offsets[p * (N_ + 1) + dst]
            + (int)partial[((size_t)p * NB_ + b) * N_ + dst]
            + (int)rank[(size_t)p * E_ + e];
    csr[(size_t)p * E_ + pos] = (u16)src;
}

// ---------------- GAT aggregation: lane-per-column, register p via readlane ----------------
// Lane = feature column (0..63); 4 head accumulators per lane. Per <=64-edge batch:
// p-phase (lane = edge slot) computes 4 exps/edge into REGISTERS. x-phase broadcasts
// {src, p0..p3} with v_readlane (uniform index) -> SGPRs: the gather gets an SGPR
// base (SALU address math) and the FMAs take the p directly as an SGPR operand.
// Zero LDS in the hot loop (round-3's 2 DS ops/edge were the critical path).
// 1-D grid with p = bid & 7 pins each (t,r) partition to one XCD (x_bf[t] 2.56 MB
// becomes L2-resident on 2 XCDs instead of re-fetched by 8).
__global__ __launch_bounds__(256) void k_agg(
    const int* __restrict__ offsets, const u16* __restrict__ csr,
    const float* __restrict__ als_all, const float* __restrict__ ald_all,
    const u16* __restrict__ x_bf, u16* __restrict__ xagg4)
{
    const int bid = blockIdx.x;
    const int p = bid & 7;
    const int t = p >> 1;
    const int* off   = offsets + (size_t)p * (N_ + 1);
    const u16* srcs  = csr + (size_t)p * E_;
    const float* als = als_all + (size_t)p * N_ * 4;
    const float* ald = ald_all + (size_t)p * N_ * 4;
    const u16* xb    = x_bf + (size_t)t * N_ * 64;

    const int tid = threadIdx.x, lane = tid & 63, wv = tid >> 6;
    const int n = (bid >> 3) * 4 + wv;
    const int o0 = off[n], o1 = off[n + 1];
    const float4 aldv = *(const float4*)(ald + (size_t)n * 4);

    float a0 = 0.f, a1 = 0.f, a2 = 0.f, a3 = 0.f;
    float d0 = 0.f, d1 = 0.f, d2 = 0.f, d3 = 0.f;

    for (int base = o0; base < o1; base += 64) {
        int cnt = o1 - base; if (cnt > 64) cnt = 64;
        int sv = 0;
        float p0 = 0.f, p1 = 0.f, p2 = 0.f, p3 = 0.f;
        if (lane < cnt) {
            sv = (int)srcs[base + lane];
            float4 av = *(const float4*)(als + (size_t)sv * 4);
            float e0 = av.x + aldv.x, e1 = av.y + aldv.y;
            float e2 = av.z + aldv.z, e3 = av.w + aldv.w;
            e0 = (e0 > 0.f) ? e0 : 0.2f * e0;
            e1 = (e1 > 0.f) ? e1 : 0.2f * e1;
            e2 = (e2 > 0.f) ? e2 : 0.2f * e2;
            e3 = (e3 > 0.f) ? e3 : 0.2f * e3;
            p0 = __expf(e0); p1 = __expf(e1); p2 = __expf(e2); p3 = __expf(e3);
        }
        d0 += p0; d1 += p1; d2 += p2; d3 += p3;
        // uniform trip count so readlane indices are provably wave-uniform
        int cntR = __builtin_amdgcn_readfirstlane((cnt + 7) & ~7);
        for (int j0 = 0; j0 < cntR; j0 += 8) {
            u16 xv[8];
            #pragma unroll
            for (int jj = 0; jj < 8; ++jj) {
                int s = __builtin_amdgcn_readlane(sv, j0 + jj);
                xv[jj] = xb[((size_t)(unsigned)s << 6) + lane];
            }
            #pragma unroll
            for (int jj = 0; jj < 8; ++jj) {
                float f = bf2f(xv[jj]);
                a0 += rdlanef(p0, j0 + jj) * f;
                a1 += rdlanef(p1, j0 + jj) * f;
                a2 += rdlanef(p2, j0 + jj) * f;
                a3 += rdlanef(p3, j0 + jj) * f;
            }
        }
    }
    #pragma unroll
    for (int m = 1; m < 64; m <<= 1) {
        d0 += __shfl_xor(d0, m); d1 += __shfl_xor(d1, m);
        d2 += __shfl_xor(d2, m); d3 += __shfl_xor(d3, m);
    }
    float s0 = 0.25f / (d0 + 1e-16f), s1 = 0.25f / (d1 + 1e-16f);
    float s2 = 0.25f / (d2 + 1e-16f), s3 = 0.25f / (d3 + 1e-16f);
    u16* outp = xagg4 + ((size_t)p * N_ + n) * 256 + lane;
    outp[0]   = f2bf(a0 * s0);
    outp[64]  = f2bf(a1 * s1);
    outp[128] = f2bf(a2 * s2);
    outp[192] = f2bf(a3 * s3);
}

// ---------------- post-projection: intra = xagg @ B~ (all t in one dispatch) ----------------
__global__ __launch_bounds__(256) void k_post(
    const u16* __restrict__ xagg4, const u16* __restrict__ postB_pad,
    u16* __restrict__ intra)
{
    const int t = blockIdx.z, r = blockIdx.y;
    const u16* A = xagg4 + ((size_t)(t * 2 + r)) * N_ * 256;
    const u16* Bp = postB_pad + (size_t)r * 4 * 4608;
    const int tid = threadIdx.x, lane = tid & 63, wv = tid >> 6;
    const int col = lane & 15, quad = lane >> 4;
    int m0 = blockIdx.x * 64;
    int row = m0 + wv * 16 + col;
    int row_c = (row < N_) ? row : (N_ - 1);

    f32x4 acc[4];
    #pragma unroll
    for (int cf = 0; cf < 4; ++cf) { acc[cf][0]=0.f; acc[cf][1]=0.f; acc[cf][2]=0.f; acc[cf][3]=0.f; }
    #pragma unroll
    for (int kc = 0; kc < 4; ++kc) {
        #pragma unroll
        for (int ks = 0; ks < 2; ++ks) {
            bf16x8 a = *(const bf16x8*)(A + (size_t)row_c * 256 + kc * 64 + ks * 32 + quad * 8);
            const u16* bb = Bp + kc * 4608 + ks * 32 + quad * 8;
            #pragma unroll
            for (int cf = 0; cf < 4; ++cf) {
                bf16x8 b = *(const bf16x8*)(bb + (cf * 16 + col) * 72);
                acc[cf] = __builtin_amdgcn_mfma_f32_16x16x32_bf16(a, b, acc[cf], 0, 0, 0);
            }
        }
    }
    int rowbase = m0 + wv * 16 + quad * 4;
    #pragma unroll
    for (int cf = 0; cf < 4; ++cf) {
        int c = cf * 16 + col;
        #pragma unroll
        for (int reg = 0; reg < 4; ++reg) {
            int rr = rowbase + reg;
            if (rr < N_)
                intra[(((size_t)t * N_ + rr) * 2 + r) * 64 + c] = f2bf(acc[cf][reg]);
        }
    }
}

// ---------------- RelationAgg GEMM with fused ftanh(.)@W2 epilogue + fused beta sums ----------------
__global__ __launch_bounds__(256) void k_relagg(
    const u16* __restrict__ A, const u16* __restrict__ W1pad, const float* __restrict__ b1,
    const float* __restrict__ W2, float* __restrict__ ssum)
{
    int m0 = blockIdx.x * 64;
    f32x4 acc[16];
    gemm_direct(A, W1pad, T_ * N_ * R_, 64, 1, m0, acc);

    const int tid = threadIdx.x, lane = tid & 63, wv = tid >> 6;
    const int col = lane & 15;
    float sp[4] = {0.f, 0.f, 0.f, 0.f};
    #pragma unroll
    for (int cf = 0; cf < 16; ++cf) {
        int gcol = cf * 16 + col;
        float bb = b1[gcol];
        float ww = W2[gcol];
        #pragma unroll
        for (int reg = 0; reg < 4; ++reg)
            sp[reg] += ftanh(acc[cf][reg] + bb) * ww;
    }
    #pragma unroll
    for (int reg = 0; reg < 4; ++reg) {
        float v = sp[reg];
        v += __shfl_xor(v, 1); v += __shfl_xor(v, 2);
        v += __shfl_xor(v, 4); v += __shfl_xor(v, 8);
        sp[reg] = v;
    }
    // rows = m0 + wv*16 + quad*4 + reg ; rowbase is even so reg parity == r
    float se = sp[0] + sp[2];   // r = 0 rows of this lane's quad
    float so = sp[1] + sp[3];   // r = 1 rows
    se += __shfl_xor(se, 16); se += __shfl_xor(se, 32);
    so += __shfl_xor(so, 16); so += __shfl_xor(so, 32);
    __shared__ float red[8];
    if (lane == 0) { red[wv * 2] = se; red[wv * 2 + 1] = so; }
    __syncthreads();
    if (tid == 0) {
        float s0 = red[0] + red[2] + red[4] + red[6];
        float s1 = red[1] + red[3] + red[5] + red[7];
        int t = m0 / (N_ * R_);
        atomicAdd(&ssum[t * 2 + 0], s0);
        atomicAdd(&ssum[t * 2 + 1], s1);
    }
}

// ---------------- LSTM: all 4 timesteps in one kernel; c in regs, h in LDS ----------------
__global__ __launch_bounds__(256) void k_lstm(
    const u16* __restrict__ intra, const float* __restrict__ ssum,
    const u16* __restrict__ Wc_pad, const float* __restrict__ biasv,
    u16* __restrict__ feats)
{
    __shared__ __align__(16) u16 hl[64][72];   // h state, bf16, wave-private 16-row stripes
    const int tid = threadIdx.x, lane = tid & 63, wv = tid >> 6;
    const int col = lane & 15, quad = lane >> 4;
    int m0 = blockIdx.x * 64;
    int row = m0 + wv * 16 + col;
    int row_c = (row < N_) ? row : (N_ - 1);
    int rowbase = m0 + wv * 16 + quad * 4;

    float betas[8];
    #pragma unroll
    for (int t = 0; t < 4; ++t) {
        float s0 = ssum[t * 2] * (1.f / N_), s1 = ssum[t * 2 + 1] * (1.f / N_);
        float mx = fmaxf(s0, s1);
        float e0 = __expf(s0 - mx), e1 = __expf(s1 - mx);
        float inv = 1.f / (e0 + e1);
        betas[t * 2] = e0 * inv; betas[t * 2 + 1] = e1 * inv;
    }

    float cc[4][4];
    #pragma unroll
    for (int j = 0; j < 4; ++j)
        #pragma unroll
        for (int reg = 0; reg < 4; ++reg) cc[j][reg] = 0.f;

    for (int t = 0; t < 4; ++t) {
        float b0 = betas[t * 2], b1 = betas[t * 2 + 1];
        const u16* ib = intra + ((size_t)t * N_ + row_c) * 128;

        f32x4 acc[16];
        #pragma unroll
        for (int cf = 0; cf < 16; ++cf) { acc[cf][0]=0.f; acc[cf][1]=0.f; acc[cf][2]=0.f; acc[cf][3]=0.f; }

        #pragma unroll
        for (int ks = 0; ks < 2; ++ks) {
            int coff = ks * 32 + quad * 8;
            bf16x8 i0 = *(const bf16x8*)(ib + coff);
            bf16x8 i1 = *(const bf16x8*)(ib + 64 + coff);
            union { u16 h[8]; bf16x8 v; } cv;
            #pragma unroll
            for (int j = 0; j < 8; ++j)
                cv.h[j] = f2bf(b0 * bf2f((u16)i0[j]) + b1 * bf2f((u16)i1[j]));
            const u16* bb = Wc_pad + ks * 32 + quad * 8;
            #pragma unroll
            for (int cf = 0; cf < 16; ++cf) {
                bf16x8 b = *(const bf16x8*)(bb + (cf * 16 + col) * 72);
                acc[cf] = __builtin_amdgcn_mfma_f32_16x16x32_bf16(cv.v, b, acc[cf], 0, 0, 0);
            }
        }
        if (t > 0) {
            #pragma unroll
            for (int ks = 0; ks < 2; ++ks) {
                bf16x8 a = *(const bf16x8*)&hl[wv * 16 + col][ks * 32 + quad * 8];
                const u16* bb = Wc_pad + BPAD + ks * 32 + quad * 8;
                #pragma unroll
                for (int cf = 0; cf < 16; ++cf) {
                    bf16x8 b = *(const bf16x8*)(bb + (cf * 16 + col) * 72);
                    acc[cf] = __builtin_amdgcn_mfma_f32_16x16x32_bf16(a, b, acc[cf], 0, 0, 0);
                }
            }
        }

        #pragma unroll
        for (int j = 0; j < 4; ++j) {
            int c = j * 16 + col;
            float bi = biasv[c], bf_ = biasv[64 + c], bg = biasv[128 + c], bo = biasv[192 + c];
            #pragma unroll
            for (int reg = 0; reg < 4; ++reg) {
                float gi = acc[j][reg] + bi;
                float gf = acc[j + 4][reg] + bf_;
                float gg = acc[j + 8][reg] + bg;
                float go = acc[j + 12][reg] + bo;
                float c2 = sigm(gf) * cc[j][reg] + sigm(gi) * ftanh(gg);
                float hh = sigm(go) * ftanh(c2);
                cc[j][reg] = c2;
                u16 hb = f2bf(hh);
                hl[wv * 16 + quad * 4 + reg][c] = hb;
                int rr = rowbase + reg;
                if (rr < N_)
                    feats[(size_t)rr * 256 + t * 64 + c] = hb;
            }
        }
    }
}

// ---------------- temporal causal MHA: MFMA QKV + per-lane attention ----------------
__global__ __launch_bounds__(256) void k_attn(
    const u16* __restrict__ feats, const float* __restrict__ pos_emb,
    const u16* __restrict__ qkv_pad, float* __restrict__ out)
{
    __shared__ float qkv_s[64 * 200];
    const int tid = threadIdx.x, lane = tid & 63, wv = tid >> 6;
    const int col = lane & 15, quad = lane >> 4;
    int m0 = blockIdx.x * 64;
    int row = m0 + wv * 16 + col;
    int trow = row & 3;

    f32x4 acc[12];
    #pragma unroll
    for (int cf = 0; cf < 12; ++cf) { acc[cf][0]=0.f; acc[cf][1]=0.f; acc[cf][2]=0.f; acc[cf][3]=0.f; }
    #pragma unroll
    for (int ks = 0; ks < 2; ++ks) {
        int coff = ks * 32 + quad * 8;
        bf16x8 fv = *(const bf16x8*)(feats + (size_t)row * 64 + coff);
        float4 p0 = *(const float4*)(pos_emb + trow * 64 + coff);
        float4 p1 = *(const float4*)(pos_emb + trow * 64 + coff + 4);
        union { u16 h[8]; bf16x8 v; } cv;
        cv.h[0] = f2bf(bf2f((u16)fv[0]) + p0.x); cv.h[1] = f2bf(bf2f((u16)fv[1]) + p0.y);
        cv.h[2] = f2bf(bf2f((u16)fv[2]) + p0.z); cv.h[3] = f2bf(bf2f((u16)fv[3]) + p0.w);
        cv.h[4] = f2bf(bf2f((u16)fv[4]) + p1.x); cv.h[5] = f2bf(bf2f((u16)fv[5]) + p1.y);
        cv.h[6] = f2bf(bf2f((u16)fv[6]) + p1.z); cv.h[7] = f2bf(bf2f((u16)fv[7]) + p1.w);
        bf16x8 a = cv.v;
        const u16* bb = qkv_pad + ks * 32 + quad * 8;
        #pragma unroll
        for (int cf = 0; cf < 12; ++cf) {
            bf16x8 b = *(const bf16x8*)(bb + (cf * 16 + col) * 72);
            acc[cf] = __builtin_amdgcn_mfma_f32_16x16x32_bf16(a, b, acc[cf], 0, 0, 0);
        }
    }
    #pragma unroll
    for (int cf = 0; cf < 12; ++cf) {
        int g = cf * 16 + col;
        #pragma unroll
        for (int reg = 0; reg < 4; ++reg) {
            int rl = wv * 16 + quad * 4 + reg;
            qkv_s[rl * 200 + g] = acc[cf][reg];
        }
    }
    __syncthreads();

    int nl = wv * 4 + (lane >> 4);
    int sub = lane & 15;
    int h = sub >> 2, tq = sub & 3;
    const float* qrow = qkv_s + (nl * 4 + tq) * 200 + h * 16;

    float s[4];
    #pragma unroll
    for (int tk = 0; tk < 4; ++tk) {
        const float* krow = qkv_s + (nl * 4 + tk) * 200 + 64 + h * 16;
        float d = 0.f;
        #pragma unroll
        for (int j = 0; j < 16; ++j) d += qrow[j] * krow[j];
        s[tk] = (tk > tq) ? -4294967295.0f : d * 0.5f;
    }
    float mx = fmaxf(fmaxf(s[0], s[1]), fmaxf(s[2], s[3]));
    float a0 = __expf(s[0]-mx), a1 = __expf(s[1]-mx), a2 = __expf(s[2]-mx), a3 = __expf(s[3]-mx);
    float inv = 1.f / (a0 + a1 + a2 + a3);
    a0 *= inv; a1 *= inv; a2 *= inv; a3 *= inv;

    int n = blockIdx.x * 16 + nl;
    const float* v0 = qkv_s + (nl * 4 + 0) * 200 + 128 + h * 16;
    const float* v1 = v0 + 200, *v2 = v0 + 400, *v3 = v0 + 600;
    #pragma unroll
    for (int cc4 = 0; cc4 < 4; ++cc4) {
        float4 o;
        o.x = a0*v0[cc4*4+0] + a1*v1[cc4*4+0] + a2*v2[cc4*4+0] + a3*v3[cc4*4+0];
        o.y = a0*v0[cc4*4+1] + a1*v1[cc4*4+1] + a2*v2[cc4*4+1] + a3*v3[cc4*4+1];
        o.z = a0*v0[cc4*4+2] + a1*v1[cc4*4+2] + a2*v2[cc4*4+2] + a3*v3[cc4*4+2];
        o.w = a0*v0[cc4*4+3] + a1*v1[cc4*4+3] + a2*v2[cc4*4+3] + a3*v3[cc4*4+3];
        *(float4*)(out + (size_t)n * 256 + tq * 64 + h * 16 + cc4 * 4) = o;
    }
}

// ---------------- launcher ----------------
extern "C" void kernel_launch(void* const* d_in, const int* in_sizes, int n_in,
                              void* d_out, int out_size, void* d_ws, size_t ws_size,
                              hipStream_t stream) {
    const float* x     = (const float*)d_in[0];
    const int* ei      = (const int*)d_in[1];
    const float* Wsrc  = (const float*)d_in[2];
    const float* Wdst  = (const float*)d_in[3];
    const float* att_src = (const float*)d_in[4];
    const float* att_dst = (const float*)d_in[5];
    const float* raW1  = (const float*)d_in[6];
    const float* rab1  = (const float*)d_in[7];
    const float* raW2  = (const float*)d_in[8];
    const float* Wih   = (const float*)d_in[9];
    const float* Whh   = (const float*)d_in[10];
    const float* bih   = (const float*)d_in[11];
    const float* bhh   = (const float*)d_in[12];
    const float* pos   = (const float*)d_in[13];
    const float* Wq    = (const float*)d_in[14];
    const float* Wk    = (const float*)d_in[15];
    const float* Wv    = (const float*)d_in[16];
    float* out = (float*)d_out;

    char* w = (char*)d_ws;
    size_t off = 0;
    auto alloc = [&](size_t bytes) -> char* {
        char* pp = w + off; off += (bytes + 255) & ~(size_t)255; return pp;
    };
    // ---- long-lived ----
    u16*   intra     = (u16*)  alloc((size_t)T_ * N_ * R_ * 64 * 2);  // 20.48 MB
    u16*   x_bf      = (u16*)  alloc((size_t)T_ * N_ * 64 * 2);       // 10.24 MB
    float* ssum      = (float*)alloc(256);
    float* wdall     = (float*)alloc(1024 * 4);
    float* biasv     = (float*)alloc(256 * 4);
    u16*   raW1_pad  = (u16*)  alloc(BPAD * 2);
    u16*   Wc_pad    = (u16*)  alloc(2 * BPAD * 2);
    u16*   qkv_pad   = (u16*)  alloc(192 * 72 * 2);
    u16*   postB_pad = (u16*)  alloc(2 * 4 * 4608 * 2);
    int*   chunktot  = (int*)  alloc(P_ * NB_ * 4);
    int*   chunkbase = (int*)  alloc(P_ * NB_ * 4);
    // ---- union region ----
    char*  ubase   = alloc(0);
    size_t uoff = 0;
    auto ualloc = [&](size_t bytes) -> char* {
        char* pp = ubase + uoff; uoff += (bytes + 255) & ~(size_t)255; return pp;
    };
    int*   offsets = (int*)  ualloc((size_t)P_ * (N_ + 1) * 4);
    u16*   csr     = (u16*)  ualloc((size_t)P_ * E_ * 2);
    float* als_all = (float*)ualloc((size_t)P_ * N_ * 4 * 4);
    float* ald_all = (float*)ualloc((size_t)P_ * N_ * 4 * 4);
    u16*   partial = (u16*)  ualloc((size_t)P_ * NB_ * N_ * 2);
    u16*   xagg4   = (u16*)  ualloc((size_t)P_ * N_ * 256 * 2);   // 81.92 MB (all t,r)
    u16*   rank    = (u16*)  xagg4;   // overlay: rank dead before k_agg
    // phase 2 overlay (phase-1 sub-buffers dead after k_post)
    u16*   feats   = (u16*)  ubase;   // 10.24 MB
    (void)ws_size; (void)in_sizes; (void)n_in; (void)out_size;

    k_prep<<<72, 256, 0, stream>>>(Wdst, att_dst, Wih, Whh, bih, bhh, Wsrc, att_src, raW1,
                                   Wq, Wk, Wv, wdall, biasv, raW1_pad, Wc_pad, qkv_pad, postB_pad);
    k_hist<<<dim3(NB_, 8), 256, 0, stream>>>(ei, rank, partial);
    k_scan1<<<dim3(NB_, 8), 256, 0, stream>>>(partial, offsets, chunktot);
    k_scan2<<<1, 64, 0, stream>>>(chunktot, chunkbase);
    k_scan3<<<dim3(79, 8), 256, 0, stream>>>(offsets, chunkbase);
    k_scatter<<<10000, 256, 0, stream>>>(ei, offsets, rank, partial, csr);
    k_fold<<<dim3(313, 4), 256, 0, stream>>>(x, wdall, als_all, ald_all, x_bf);
    k_agg<<<40000, 256, 0, stream>>>(offsets, csr, als_all, ald_all, x_bf, xagg4);
    k_post<<<dim3(313, 2, 4), 256, 0, stream>>>(xagg4, postB_pad, intra);
    hipMemsetAsync(ssum, 0, 32, stream);
    k_relagg<<<2500, 256, 0, stream>>>(intra, raW1_pad, rab1, raW2, ssum);
    k_lstm<<<313, 256, 0, stream>>>(intra, ssum, Wc_pad, biasv, feats);
    k_attn<<<1250, 256, 0, stream>>>(feats, pos, qkv_pad, out);
}

// Round 5
// 461.893 us; speedup vs baseline: 1.0797x; 1.0797x over previous
//
#include <hip/hip_runtime.h>
#include <hip/hip_bf16.h>

#define T_ 4
#define N_ 20000
#define E_ 320000
#define R_ 2
#define DIN 64
#define G_ 256   // H*Dh
#define P_ 8     // T*R
#define BPAD 18432  // 256 * 72 padded B-table halves per 64-k chunk
#define NB_ 32      // CSR-build blocks per p
#define EPB_ 10000  // edges per CSR-build block
#define CHN_ 625    // nodes per scan chunk (N_/32)

typedef unsigned short u16;
typedef __attribute__((ext_vector_type(8))) short bf16x8;
typedef __attribute__((ext_vector_type(2))) _Float16 h2;
typedef __attribute__((ext_vector_type(4))) float f32x4;

__device__ __forceinline__ float bf2f(u16 u) {
    unsigned int i = ((unsigned int)u) << 16; float f;
    __builtin_memcpy(&f, &i, 4); return f;
}
__device__ __forceinline__ u16 f2bf(float f) {
    unsigned int i; __builtin_memcpy(&i, &f, 4);
    unsigned int r = i + 0x7fffu + ((i >> 16) & 1u);
    return (u16)(r >> 16);
}
__device__ __forceinline__ u16 f2h(float f) {
    union { _Float16 h; u16 u; } c; c.h = (_Float16)f; return c.u;
}
__device__ __forceinline__ float sigm(float x) { return 1.f / (1.f + __expf(-x)); }
// fast tanh: 1 - 2/(exp(2x)+1); hardware v_exp_f32, correct saturation at +-inf
__device__ __forceinline__ float ftanh(float x) { return 1.f - 2.f / (__expf(2.f * x) + 1.f); }
// v_dot2_f32_f16: a.x*b.x + a.y*b.y + c in one VALU op
__device__ __forceinline__ float fdot2(h2 a, h2 b, float c) {
#if __has_builtin(__builtin_amdgcn_fdot2)
    return __builtin_amdgcn_fdot2(a, b, c, false);
#else
    float r;
    asm("v_dot2_f32_f16 %0, %1, %2, %3" : "=v"(r) : "v"(a), "v"(b), "v"(c));
    return r;
#endif
}

// ---------------- LDS-free MFMA GEMM core (bf16 A) ----------------
__device__ __forceinline__ void gemm_direct(
    const u16* __restrict__ A, const u16* __restrict__ Bpad,
    int M, int Astride, int kchunks, int m0, f32x4* acc)
{
    const int tid = threadIdx.x;
    const int lane = tid & 63, wv = tid >> 6;
    const int col = lane & 15, quad = lane >> 4;
    #pragma unroll
    for (int cf = 0; cf < 16; ++cf) { acc[cf][0]=0.f; acc[cf][1]=0.f; acc[cf][2]=0.f; acc[cf][3]=0.f; }

    int row = m0 + wv * 16 + col;
    int row_c = (row < M) ? row : (M - 1);

    for (int kc = 0; kc < kchunks; ++kc) {
        #pragma unroll
        for (int ks = 0; ks < 2; ++ks) {
            bf16x8 a = *(const bf16x8*)(A + (size_t)row_c * Astride + kc * 64 + ks * 32 + quad * 8);
            const u16* bb = Bpad + kc * BPAD + ks * 32 + quad * 8;
            #pragma unroll
            for (int cf = 0; cf < 16; ++cf) {
                bf16x8 b = *(const bf16x8*)(bb + (cf * 16 + col) * 72);
                acc[cf] = __builtin_amdgcn_mfma_f32_16x16x32_bf16(a, b, acc[cf], 0, 0, 0);
            }
        }
    }
}

// ---------------- fold: als/ald GEMVs + x->f16 cast; wdall staged in LDS ----------------
__global__ __launch_bounds__(256) void k_fold(
    const float* __restrict__ x, const float* __restrict__ wdall,
    float* __restrict__ als_all, float* __restrict__ ald_all, u16* __restrict__ x_h)
{
    __shared__ float wds[1024];
    {
        int tid = threadIdx.x;
        *(float4*)(wds + tid * 4) = *(const float4*)(wdall + tid * 4);
    }
    __syncthreads();

    int t = blockIdx.y;
    int idx = blockIdx.x * 256 + threadIdx.x;
    if (idx >= N_ * 4) return;
    int n = idx >> 2, q = idx & 3;
    const float* xr = x + ((size_t)t * N_ + n) * 64 + q * 16;
    float4 xv[4];
    #pragma unroll
    for (int i = 0; i < 4; ++i) xv[i] = *(const float4*)(xr + i * 4);

    {
        union { u16 h[16]; ushort4 s4[4]; } cv;
        #pragma unroll
        for (int i = 0; i < 4; ++i) {
            cv.h[i*4+0] = f2h(xv[i].x); cv.h[i*4+1] = f2h(xv[i].y);
            cv.h[i*4+2] = f2h(xv[i].z); cv.h[i*4+3] = f2h(xv[i].w);
        }
        u16* xo = x_h + ((size_t)t * N_ + n) * 64 + q * 16;
        #pragma unroll
        for (int i = 0; i < 4; ++i) *(ushort4*)(xo + i * 4) = cv.s4[i];
    }

    float s[16];
    #pragma unroll
    for (int i = 0; i < 16; ++i) s[i] = 0.f;
    #pragma unroll
    for (int i = 0; i < 4; ++i) {
        float xe[4] = {xv[i].x, xv[i].y, xv[i].z, xv[i].w};
        #pragma unroll
        for (int e = 0; e < 4; ++e) {
            int k = q * 16 + i * 4 + e;
            float xk = xe[e];
            #pragma unroll
            for (int tb = 0; tb < 4; ++tb) {
                float4 w = *(const float4*)(wds + tb * 256 + k * 4);
                s[tb*4+0] += xk * w.x; s[tb*4+1] += xk * w.y;
                s[tb*4+2] += xk * w.z; s[tb*4+3] += xk * w.w;
            }
        }
    }
    #pragma unroll
    for (int i = 0; i < 16; ++i) {
        s[i] += __shfl_xor(s[i], 1);
        s[i] += __shfl_xor(s[i], 2);
    }
    if (q == 0) {
        *(float4*)(als_all + ((size_t)(t*2+0) * N_ + n) * 4) = make_float4(s[0], s[1], s[2], s[3]);
        *(float4*)(als_all + ((size_t)(t*2+1) * N_ + n) * 4) = make_float4(s[4], s[5], s[6], s[7]);
        *(float4*)(ald_all + ((size_t)(t*2+0) * N_ + n) * 4) = make_float4(s[8], s[9], s[10], s[11]);
        *(float4*)(ald_all + ((size_t)(t*2+1) * N_ + n) * 4) = make_float4(s[12], s[13], s[14], s[15]);
    }
}

// ---------------- prep: folded GEMV tables, padded B-tables, folded bias ----------------
__global__ void k_prep(const float* __restrict__ Wdst, const float* __restrict__ att_dst,
                       const float* __restrict__ Wih, const float* __restrict__ Whh,
                       const float* __restrict__ bih, const float* __restrict__ bhh,
                       const float* __restrict__ Wsrc, const float* __restrict__ att_src,
                       const float* __restrict__ raW1,
                       const float* __restrict__ Wq, const float* __restrict__ Wk,
                       const float* __restrict__ Wv,
                       float* __restrict__ wdall, float* __restrict__ biasv,
                       u16* __restrict__ raW1_pad, u16* __restrict__ Wc_pad,
                       u16* __restrict__ qkv_pad, u16* __restrict__ postB_pad)
{
    int tid = threadIdx.x, bid = blockIdx.x;
    if (bid == 0) {
        int k = tid >> 2, h = tid & 3;
        for (int r = 0; r < 2; ++r) {
            float ss = 0.f, sd = 0.f;
            for (int c = 0; c < 64; ++c) {
                ss += Wsrc[((size_t)r * 64 + k) * 256 + h * 64 + c] * att_src[r * 256 + h * 64 + c];
                sd += Wdst[((size_t)r * 64 + k) * 256 + h * 64 + c] * att_dst[r * 256 + h * 64 + c];
            }
            wdall[r * 256 + k * 4 + h] = ss;
            wdall[512 + r * 256 + k * 4 + h] = sd;
        }
        biasv[tid] = bih[tid] + bhh[tid];
    }
    for (int i = bid * 256 + tid; i < BPAD; i += gridDim.x * 256) {
        int n = i / 72, kk = i % 72;
        raW1_pad[i] = (kk < 64) ? f2bf(raW1[kk * 256 + n]) : (u16)0;
    }
    for (int i = bid * 256 + tid; i < 2 * BPAD; i += gridDim.x * 256) {
        int kc = i / BPAD, q = i % BPAD, n = q / 72, kk = q % 72;
        const float* W = kc ? Whh : Wih;
        Wc_pad[i] = (kk < 64) ? f2bf(W[n * 64 + kk]) : (u16)0;
    }
    for (int i = bid * 256 + tid; i < 192 * 72; i += gridDim.x * 256) {
        int g = i / 72, kk = i % 72;
        int j = g >> 6, c = g & 63;
        const float* W = (j == 0) ? Wq : (j == 1) ? Wk : Wv;
        qkv_pad[i] = (kk < 64) ? f2bf(W[kk * 64 + c]) : (u16)0;
    }
    for (int i = bid * 256 + tid; i < 2 * 4 * 4608; i += gridDim.x * 256) {
        int r = i / 18432, q = i % 18432, kc = q / 4608, qq = q % 4608;
        int c = qq / 72, kk = qq % 72;
        postB_pad[i] = (kk < 64) ? f2bf(Wsrc[(size_t)r * 16384 + kk * 256 + kc * 64 + c]) : (u16)0;
    }
}

// ---------------- CSR build ----------------
__global__ __launch_bounds__(256) void k_hist(const int* __restrict__ ei,
                                              u16* __restrict__ rank, u16* __restrict__ partial)
{
    __shared__ unsigned int hist[N_ / 2];
    int b = blockIdx.x, p = blockIdx.y, tid = threadIdx.x;
    for (int i = tid; i < N_ / 2; i += 256) hist[i] = 0u;
    __syncthreads();
    const int* dsts = ei + ((size_t)p * 2 + 1) * E_ + b * EPB_;
    u16* rk = rank + (size_t)p * E_ + b * EPB_;
    for (int e = tid; e < EPB_; e += 256) {
        int dst = dsts[e];
        unsigned sh = (unsigned)(dst & 1) * 16u;
        unsigned old = atomicAdd(&hist[dst >> 1], 1u << sh);
        rk[e] = (u16)((old >> sh) & 0xffffu);
    }
    __syncthreads();
    u16* part = partial + ((size_t)p * NB_ + b) * N_;
    for (int n = tid; n < N_; n += 256) {
        unsigned hv = hist[n >> 1];
        part[n] = (u16)((hv >> ((unsigned)(n & 1) * 16u)) & 0xffffu);
    }
}

__global__ __launch_bounds__(256) void k_scan1(u16* __restrict__ partial,
                                               int* __restrict__ offsets, int* __restrict__ chunktot)
{
    int p = blockIdx.y, ch = blockIdx.x;
    int tid = threadIdx.x, lane = tid & 63, wid = tid >> 6;
    __shared__ int wtot[4];
    u16* part = partial + (size_t)p * NB_ * N_;
    int* ofs = offsets + (size_t)p * (N_ + 1);
    int n0 = ch * CHN_;
    int carry = 0;
    for (int rnd = 0; rnd < 3; ++rnd) {
        int i = rnd * 256 + tid;
        int n = n0 + i;
        int v = 0;
        if (i < CHN_) {
            int run = 0;
            #pragma unroll 8
            for (int b = 0; b < NB_; ++b) {
                int pv = part[b * N_ + n];
                part[b * N_ + n] = (u16)run;
                run += pv;
            }
            v = run;
        }
        int incl = v;
        for (int d = 1; d < 64; d <<= 1) { int u = __shfl_up(incl, d); if (lane >= d) incl += u; }
        if (lane == 63) wtot[wid] = incl;
        __syncthreads();
        if (tid < 4) {
            int iv = wtot[tid];
            for (int d = 1; d < 4; d <<= 1) { int u = __shfl_up(iv, d); if (tid >= d) iv += u; }
            wtot[tid] = iv;
        }
        __syncthreads();
        int woff = (wid > 0) ? wtot[wid - 1] : 0;
        int tot = wtot[3];
        int excl = carry + woff + incl - v;
        if (i < CHN_) ofs[n] = excl;
        carry += tot;
        __syncthreads();
    }
    if (tid == 0) chunktot[p * NB_ + ch] = carry;
}

__global__ void k_scan2(const int* __restrict__ chunktot, int* __restrict__ chunkbase) {
    int tid = threadIdx.x;
    if (tid < P_) {
        int run = 0;
        for (int c = 0; c < NB_; ++c) {
            chunkbase[tid * NB_ + c] = run;
            run += chunktot[tid * NB_ + c];
        }
    }
}

__global__ void k_scan3(int* __restrict__ offsets, const int* __restrict__ chunkbase) {
    int p = blockIdx.y;
    int n = blockIdx.x * 256 + threadIdx.x;
    if (n < N_)
        offsets[(size_t)p * (N_ + 1) + n] += chunkbase[p * NB_ + n / CHN_];
    if (n == 0)
        offsets[(size_t)p * (N_ + 1) + N_] = E_;
}

// 1-D grid, p = bid & 7: round-robin dispatch pins each p to one XCD, so the
// random 2B csr writes (640 KB/p) stay in that XCD's L2 (kills the 8x write amp).
__global__ void k_scatter(const int* __restrict__ ei, const int* __restrict__ offsets,
                          const u16* __restrict__ rank, const u16* __restrict__ partial,
                          u16* __restrict__ csr) {
    int bid = blockIdx.x;
    int p = bid & 7;
    int e = (bid >> 3) * 256 + threadIdx.x;
    int src = ei[((size_t)p * 2 + 0) * E_ + e];
    int dst = ei[((size_t)p * 2 + 1) * E_ + e];
    int b = e / EPB_;
    int pos = offsets[p * (N_ + 1) + dst]
            + (int)partial[((size_t)p * NB_ + b) * N_ + dst]
            + (int)rank[(size_t)p * E_ + e];
    csr[(size_t)p * E_ + pos] = (u16)src;
}

// ---------------- GAT aggregation: dot2 edge pairs, f16 x and p ----------------
// Lane = feature column (0..63); 4 head accumulators per lane. Per <=64-edge batch:
// p-phase (lane = edge slot) computes 4 exps/edge, writes f16 p's into a packed
// pair table (4x ds_write_b16); src indices stay in registers. x-phase processes
// edges in PAIRS: 2 readlane (src -> SGPR gather base), 2 ushort loads, 1 pack,
// one uniform ds_read_b128 broadcasts all 4 head p-pairs, then 4 v_dot2_f32_f16
// do all 8 FMAs. ~2 VALU + 0.5 DS per edge vs round-3's ~6 VALU + 4 DS.
// 1-D grid with p = bid & 7 pins each (t,r) partition to one XCD.
__global__ __launch_bounds__(256) void k_agg(
    const int* __restrict__ offsets, const u16* __restrict__ csr,
    const float* __restrict__ als_all, const float* __restrict__ ald_all,
    const u16* __restrict__ x_h, u16* __restrict__ xagg4)
{
    // [wv][pair*8 + h*2 + (edge&1)] u16 -> u32 at pair*16+h*4 = (p_h(odd)<<16)|p_h(even)
    __shared__ __align__(16) u16 ptab[4][256];
    const int bid = blockIdx.x;
    const int p = bid & 7;
    const int t = p >> 1;
    const int* off   = offsets + (size_t)p * (N_ + 1);
    const u16* srcs  = csr + (size_t)p * E_;
    const float* als = als_all + (size_t)p * N_ * 4;
    const float* ald = ald_all + (size_t)p * N_ * 4;
    const u16* xb    = x_h + (size_t)t * N_ * 64;

    const int tid = threadIdx.x, lane = tid & 63, wv = tid >> 6;
    const int n = (bid >> 3) * 4 + wv;
    const int o0 = off[n], o1 = off[n + 1];
    const float4 aldv = *(const float4*)(ald + (size_t)n * 4);
    u16* pt = &ptab[wv][0];
    const int pw = (lane >> 1) * 8 + (lane & 1);

    float a0 = 0.f, a1 = 0.f, a2 = 0.f, a3 = 0.f;
    float d0 = 0.f, d1 = 0.f, d2 = 0.f, d3 = 0.f;

    for (int base = o0; base < o1; base += 64) {
        int cnt = o1 - base; if (cnt > 64) cnt = 64;
        int sv = 0;
        float p0 = 0.f, p1 = 0.f, p2 = 0.f, p3 = 0.f;
        if (lane < cnt) {
            sv = (int)srcs[base + lane];
            float4 av = *(const float4*)(als + (size_t)sv * 4);
            float e0 = av.x + aldv.x, e1 = av.y + aldv.y;
            float e2 = av.z + aldv.z, e3 = av.w + aldv.w;
            e0 = (e0 > 0.f) ? e0 : 0.2f * e0;
            e1 = (e1 > 0.f) ? e1 : 0.2f * e1;
            e2 = (e2 > 0.f) ? e2 : 0.2f * e2;
            e3 = (e3 > 0.f) ? e3 : 0.2f * e3;
            p0 = __expf(e0); p1 = __expf(e1); p2 = __expf(e2); p3 = __expf(e3);
        }
        d0 += p0; d1 += p1; d2 += p2; d3 += p3;
        pt[pw + 0] = f2h(p0); pt[pw + 2] = f2h(p1);
        pt[pw + 4] = f2h(p2); pt[pw + 6] = f2h(p3);
        // uniform trip count; lanes >= cnt wrote p=0 -> padded pairs contribute zero
        int cntR = __builtin_amdgcn_readfirstlane((cnt + 7) & ~7);
        for (int j0 = 0; j0 < cntR; j0 += 8) {
            #pragma unroll
            for (int pr = 0; pr < 4; ++pr) {
                int j = j0 + pr * 2;
                int s0 = __builtin_amdgcn_readlane(sv, j);
                int s1 = __builtin_amdgcn_readlane(sv, j + 1);
                unsigned x0 = xb[((size_t)(unsigned)s0 << 6) + lane];
                unsigned x1 = xb[((size_t)(unsigned)s1 << 6) + lane];
                unsigned xp = x0 | (x1 << 16);
                uint4 pp = *(const uint4*)(pt + (j >> 1) * 8);
                h2 xv, q0, q1, q2, q3;
                __builtin_memcpy(&xv, &xp, 4);
                __builtin_memcpy(&q0, &pp.x, 4);
                __builtin_memcpy(&q1, &pp.y, 4);
                __builtin_memcpy(&q2, &pp.z, 4);
                __builtin_memcpy(&q3, &pp.w, 4);
                a0 = fdot2(xv, q0, a0);
                a1 = fdot2(xv, q1, a1);
                a2 = fdot2(xv, q2, a2);
                a3 = fdot2(xv, q3, a3);
            }
        }
    }
    #pragma unroll
    for (int m = 1; m < 64; m <<= 1) {
        d0 += __shfl_xor(d0, m); d1 += __shfl_xor(d1, m);
        d2 += __shfl_xor(d2, m); d3 += __shfl_xor(d3, m);
    }
    float s0 = 0.25f / (d0 + 1e-16f), s1 = 0.25f / (d1 + 1e-16f);
    float s2 = 0.25f / (d2 + 1e-16f), s3 = 0.25f / (d3 + 1e-16f);
    u16* outp = xagg4 + ((size_t)p * N_ + n) * 256 + lane;
    outp[0]   = f2bf(a0 * s0);
    outp[64]  = f2bf(a1 * s1);
    outp[128] = f2bf(a2 * s2);
    outp[192] = f2bf(a3 * s3);
}

// ---------------- post-projection: intra = xagg @ B~ (all t in one dispatch) ----------------
__global__ __launch_bounds__(256) void k_post(
    const u16* __restrict__ xagg4, const u16* __restrict__ postB_pad,
    u16* __restrict__ intra)
{
    const int t = blockIdx.z, r = blockIdx.y;
    const u16* A = xagg4 + ((size_t)(t * 2 + r)) * N_ * 256;
    const u16* Bp = postB_pad + (size_t)r * 4 * 4608;
    const int tid = threadIdx.x, lane = tid & 63, wv = tid >> 6;
    const int col = lane & 15, quad = lane >> 4;
    int m0 = blockIdx.x * 64;
    int row = m0 + wv * 16 + col;
    int row_c = (row < N_) ? row : (N_ - 1);

    f32x4 acc[4];
    #pragma unroll
    for (int cf = 0; cf < 4; ++cf) { acc[cf][0]=0.f; acc[cf][1]=0.f; acc[cf][2]=0.f; acc[cf][3]=0.f; }
    #pragma unroll
    for (int kc = 0; kc < 4; ++kc) {
        #pragma unroll
        for (int ks = 0; ks < 2; ++ks) {
            bf16x8 a = *(const bf16x8*)(A + (size_t)row_c * 256 + kc * 64 + ks * 32 + quad * 8);
            const u16* bb = Bp + kc * 4608 + ks * 32 + quad * 8;
            #pragma unroll
            for (int cf = 0; cf < 4; ++cf) {
                bf16x8 b = *(const bf16x8*)(bb + (cf * 16 + col) * 72);
                acc[cf] = __builtin_amdgcn_mfma_f32_16x16x32_bf16(a, b, acc[cf], 0, 0, 0);
            }
        }
    }
    int rowbase = m0 + wv * 16 + quad * 4;
    #pragma unroll
    for (int cf = 0; cf < 4; ++cf) {
        int c = cf * 16 + col;
        #pragma unroll
        for (int reg = 0; reg < 4; ++reg) {
            int rr = rowbase + reg;
            if (rr < N_)
                intra[(((size_t)t * N_ + rr) * 2 + r) * 64 + c] = f2bf(acc[cf][reg]);
        }
    }
}

// ---------------- RelationAgg GEMM with fused ftanh(.)@W2 epilogue + fused beta sums ----------------
__global__ __launch_bounds__(256) void k_relagg(
    const u16* __restrict__ A, const u16* __restrict__ W1pad, const float* __restrict__ b1,
    const float* __restrict__ W2, float* __restrict__ ssum)
{
    int m0 = blockIdx.x * 64;
    f32x4 acc[16];
    gemm_direct(A, W1pad, T_ * N_ * R_, 64, 1, m0, acc);

    const int tid = threadIdx.x, lane = tid & 63, wv = tid >> 6;
    const int col = lane & 15;
    float sp[4] = {0.f, 0.f, 0.f, 0.f};
    #pragma unroll
    for (int cf = 0; cf < 16; ++cf) {
        int gcol = cf * 16 + col;
        float bb = b1[gcol];
        float ww = W2[gcol];
        #pragma unroll
        for (int reg = 0; reg < 4; ++reg)
            sp[reg] += ftanh(acc[cf][reg] + bb) * ww;
    }
    #pragma unroll
    for (int reg = 0; reg < 4; ++reg) {
        float v = sp[reg];
        v += __shfl_xor(v, 1); v += __shfl_xor(v, 2);
        v += __shfl_xor(v, 4); v += __shfl_xor(v, 8);
        sp[reg] = v;
    }
    // rows = m0 + wv*16 + quad*4 + reg ; rowbase is even so reg parity == r
    float se = sp[0] + sp[2];   // r = 0 rows of this lane's quad
    float so = sp[1] + sp[3];   // r = 1 rows
    se += __shfl_xor(se, 16); se += __shfl_xor(se, 32);
    so += __shfl_xor(so, 16); so += __shfl_xor(so, 32);
    __shared__ float red[8];
    if (lane == 0) { red[wv * 2] = se; red[wv * 2 + 1] = so; }
    __syncthreads();
    if (tid == 0) {
        float s0 = red[0] + red[2] + red[4] + red[6];
        float s1 = red[1] + red[3] + red[5] + red[7];
        int t = m0 / (N_ * R_);
        atomicAdd(&ssum[t * 2 + 0], s0);
        atomicAdd(&ssum[t * 2 + 1], s1);
    }
}

// ---------------- LSTM: all 4 timesteps in one kernel; c in regs, h in LDS ----------------
__global__ __launch_bounds__(256) void k_lstm(
    const u16* __restrict__ intra, const float* __restrict__ ssum,
    const u16* __restrict__ Wc_pad, const float* __restrict__ biasv,
    u16* __restrict__ feats)
{
    __shared__ __align__(16) u16 hl[64][72];   // h state, bf16, wave-private 16-row stripes
    const int tid = threadIdx.x, lane = tid & 63, wv = tid >> 6;
    const int col = lane & 15, quad = lane >> 4;
    int m0 = blockIdx.x * 64;
    int row = m0 + wv * 16 + col;
    int row_c = (row < N_) ? row : (N_ - 1);
    int rowbase = m0 + wv * 16 + quad * 4;

    float betas[8];
    #pragma unroll
    for (int t = 0; t < 4; ++t) {
        float s0 = ssum[t * 2] * (1.f / N_), s1 = ssum[t * 2 + 1] * (1.f / N_);
        float mx = fmaxf(s0, s1);
        float e0 = __expf(s0 - mx), e1 = __expf(s1 - mx);
        float inv = 1.f / (e0 + e1);
        betas[t * 2] = e0 * inv; betas[t * 2 + 1] = e1 * inv;
    }

    float cc[4][4];
    #pragma unroll
    for (int j = 0; j < 4; ++j)
        #pragma unroll
        for (int reg = 0; reg < 4; ++reg) cc[j][reg] = 0.f;

    for (int t = 0; t < 4; ++t) {
        float b0 = betas[t * 2], b1 = betas[t * 2 + 1];
        const u16* ib = intra + ((size_t)t * N_ + row_c) * 128;

        f32x4 acc[16];
        #pragma unroll
        for (int cf = 0; cf < 16; ++cf) { acc[cf][0]=0.f; acc[cf][1]=0.f; acc[cf][2]=0.f; acc[cf][3]=0.f; }

        #pragma unroll
        for (int ks = 0; ks < 2; ++ks) {
            int coff = ks * 32 + quad * 8;
            bf16x8 i0 = *(const bf16x8*)(ib + coff);
            bf16x8 i1 = *(const bf16x8*)(ib + 64 + coff);
            union { u16 h[8]; bf16x8 v; } cv;
            #pragma unroll
            for (int j = 0; j < 8; ++j)
                cv.h[j] = f2bf(b0 * bf2f((u16)i0[j]) + b1 * bf2f((u16)i1[j]));
            const u16* bb = Wc_pad + ks * 32 + quad * 8;
            #pragma unroll
            for (int cf = 0; cf < 16; ++cf) {
                bf16x8 b = *(const bf16x8*)(bb + (cf * 16 + col) * 72);
                acc[cf] = __builtin_amdgcn_mfma_f32_16x16x32_bf16(cv.v, b, acc[cf], 0, 0, 0);
            }
        }
        if (t > 0) {
            #pragma unroll
            for (int ks = 0; ks < 2; ++ks) {
                bf16x8 a = *(const bf16x8*)&hl[wv * 16 + col][ks * 32 + quad * 8];
                const u16* bb = Wc_pad + BPAD + ks * 32 + quad * 8;
                #pragma unroll
                for (int cf = 0; cf < 16; ++cf) {
                    bf16x8 b = *(const bf16x8*)(bb + (cf * 16 + col) * 72);
                    acc[cf] = __builtin_amdgcn_mfma_f32_16x16x32_bf16(a, b, acc[cf], 0, 0, 0);
                }
            }
        }

        #pragma unroll
        for (int j = 0; j < 4; ++j) {
            int c = j * 16 + col;
            float bi = biasv[c], bf_ = biasv[64 + c], bg = biasv[128 + c], bo = biasv[192 + c];
            #pragma unroll
            for (int reg = 0; reg < 4; ++reg) {
                float gi = acc[j][reg] + bi;
                float gf = acc[j + 4][reg] + bf_;
                float gg = acc[j + 8][reg] + bg;
                float go = acc[j + 12][reg] + bo;
                float c2 = sigm(gf) * cc[j][reg] + sigm(gi) * ftanh(gg);
                float hh = sigm(go) * ftanh(c2);
                cc[j][reg] = c2;
                u16 hb = f2bf(hh);
                hl[wv * 16 + quad * 4 + reg][c] = hb;
                int rr = rowbase + reg;
                if (rr < N_)
                    feats[(size_t)rr * 256 + t * 64 + c] = hb;
            }
        }
    }
}

// ---------------- temporal causal MHA: MFMA QKV + per-lane attention ----------------
__global__ __launch_bounds__(256) void k_attn(
    const u16* __restrict__ feats, const float* __restrict__ pos_emb,
    const u16* __restrict__ qkv_pad, float* __restrict__ out)
{
    __shared__ float qkv_s[64 * 200];
    const int tid = threadIdx.x, lane = tid & 63, wv = tid >> 6;
    const int col = lane & 15, quad = lane >> 4;
    int m0 = blockIdx.x * 64;
    int row = m0 + wv * 16 + col;
    int trow = row & 3;

    f32x4 acc[12];
    #pragma unroll
    for (int cf = 0; cf < 12; ++cf) { acc[cf][0]=0.f; acc[cf][1]=0.f; acc[cf][2]=0.f; acc[cf][3]=0.f; }
    #pragma unroll
    for (int ks = 0; ks < 2; ++ks) {
        int coff = ks * 32 + quad * 8;
        bf16x8 fv = *(const bf16x8*)(feats + (size_t)row * 64 + coff);
        float4 p0 = *(const float4*)(pos_emb + trow * 64 + coff);
        float4 p1 = *(const float4*)(pos_emb + trow * 64 + coff + 4);
        union { u16 h[8]; bf16x8 v; } cv;
        cv.h[0] = f2bf(bf2f((u16)fv[0]) + p0.x); cv.h[1] = f2bf(bf2f((u16)fv[1]) + p0.y);
        cv.h[2] = f2bf(bf2f((u16)fv[2]) + p0.z); cv.h[3] = f2bf(bf2f((u16)fv[3]) + p0.w);
        cv.h[4] = f2bf(bf2f((u16)fv[4]) + p1.x); cv.h[5] = f2bf(bf2f((u16)fv[5]) + p1.y);
        cv.h[6] = f2bf(bf2f((u16)fv[6]) + p1.z); cv.h[7] = f2bf(bf2f((u16)fv[7]) + p1.w);
        bf16x8 a = cv.v;
        const u16* bb = qkv_pad + ks * 32 + quad * 8;
        #pragma unroll
        for (int cf = 0; cf < 12; ++cf) {
            bf16x8 b = *(const bf16x8*)(bb + (cf * 16 + col) * 72);
            acc[cf] = __builtin_amdgcn_mfma_f32_16x16x32_bf16(a, b, acc[cf], 0, 0, 0);
        }
    }
    #pragma unroll
    for (int cf = 0; cf < 12; ++cf) {
        int g = cf * 16 + col;
        #pragma unroll
        for (int reg = 0; reg < 4; ++reg) {
            int rl = wv * 16 + quad * 4 + reg;
            qkv_s[rl * 200 + g] = acc[cf][reg];
        }
    }
    __syncthreads();

    int nl = wv * 4 + (lane >> 4);
    int sub = lane & 15;
    int h = sub >> 2, tq = sub & 3;
    const float* qrow = qkv_s + (nl * 4 + tq) * 200 + h * 16;

    float s[4];
    #pragma unroll
    for (int tk = 0; tk < 4; ++tk) {
        const float* krow = qkv_s + (nl * 4 + tk) * 200 + 64 + h * 16;
        float d = 0.f;
        #pragma unroll
        for (int j = 0; j < 16; ++j) d += qrow[j] * krow[j];
        s[tk] = (tk > tq) ? -4294967295.0f : d * 0.5f;
    }
    float mx = fmaxf(fmaxf(s[0], s[1]), fmaxf(s[2], s[3]));
    float a0 = __expf(s[0]-mx), a1 = __expf(s[1]-mx), a2 = __expf(s[2]-mx), a3 = __expf(s[3]-mx);
    float inv = 1.f / (a0 + a1 + a2 + a3);
    a0 *= inv; a1 *= inv; a2 *= inv; a3 *= inv;

    int n = blockIdx.x * 16 + nl;
    const float* v0 = qkv_s + (nl * 4 + 0) * 200 + 128 + h * 16;
    const float* v1 = v0 + 200, *v2 = v0 + 400, *v3 = v0 + 600;
    #pragma unroll
    for (int cc4 = 0; cc4 < 4; ++cc4) {
        float4 o;
        o.x = a0*v0[cc4*4+0] + a1*v1[cc4*4+0] + a2*v2[cc4*4+0] + a3*v3[cc4*4+0];
        o.y = a0*v0[cc4*4+1] + a1*v1[cc4*4+1] + a2*v2[cc4*4+1] + a3*v3[cc4*4+1];
        o.z = a0*v0[cc4*4+2] + a1*v1[cc4*4+2] + a2*v2[cc4*4+2] + a3*v3[cc4*4+2];
        o.w = a0*v0[cc4*4+3] + a1*v1[cc4*4+3] + a2*v2[cc4*4+3] + a3*v3[cc4*4+3];
        *(float4*)(out + (size_t)n * 256 + tq * 64 + h * 16 + cc4 * 4) = o;
    }
}

// ---------------- launcher ----------------
extern "C" void kernel_launch(void* const* d_in, const int* in_sizes, int n_in,
                              void* d_out, int out_size, void* d_ws, size_t ws_size,
                              hipStream_t stream) {
    const float* x     = (const float*)d_in[0];
    const int* ei      = (const int*)d_in[1];
    const float* Wsrc  = (const float*)d_in[2];
    const float* Wdst  = (const float*)d_in[3];
    const float* att_src = (const float*)d_in[4];
    const float* att_dst = (const float*)d_in[5];
    const float* raW1  = (const float*)d_in[6];
    const float* rab1  = (const float*)d_in[7];
    const float* raW2  = (const float*)d_in[8];
    const float* Wih   = (const float*)d_in[9];
    const float* Whh   = (const float*)d_in[10];
    const float* bih   = (const float*)d_in[11];
    const float* bhh   = (const float*)d_in[12];
    const float* pos   = (const float*)d_in[13];
    const float* Wq    = (const float*)d_in[14];
    const float* Wk    = (const float*)d_in[15];
    const float* Wv    = (const float*)d_in[16];
    float* out = (float*)d_out;

    char* w = (char*)d_ws;
    size_t off = 0;
    auto alloc = [&](size_t bytes) -> char* {
        char* pp = w + off; off += (bytes + 255) & ~(size_t)255; return pp;
    };
    // ---- long-lived ----
    u16*   intra     = (u16*)  alloc((size_t)T_ * N_ * R_ * 64 * 2);  // 20.48 MB
    u16*   x_h       = (u16*)  alloc((size_t)T_ * N_ * 64 * 2);       // 10.24 MB (f16)
    float* ssum      = (float*)alloc(256);
    float* wdall     = (float*)alloc(1024 * 4);
    float* biasv     = (float*)alloc(256 * 4);
    u16*   raW1_pad  = (u16*)  alloc(BPAD * 2);
    u16*   Wc_pad    = (u16*)  alloc(2 * BPAD * 2);
    u16*   qkv_pad   = (u16*)  alloc(192 * 72 * 2);
    u16*   postB_pad = (u16*)  alloc(2 * 4 * 4608 * 2);
    int*   chunktot  = (int*)  alloc(P_ * NB_ * 4);
    int*   chunkbase = (int*)  alloc(P_ * NB_ * 4);
    // ---- union region ----
    char*  ubase   = alloc(0);
    size_t uoff = 0;
    auto ualloc = [&](size_t bytes) -> char* {
        char* pp = ubase + uoff; uoff += (bytes + 255) & ~(size_t)255; return pp;
    };
    int*   offsets = (int*)  ualloc((size_t)P_ * (N_ + 1) * 4);
    u16*   csr     = (u16*)  ualloc((size_t)P_ * E_ * 2);
    float* als_all = (float*)ualloc((size_t)P_ * N_ * 4 * 4);
    float* ald_all = (float*)ualloc((size_t)P_ * N_ * 4 * 4);
    u16*   partial = (u16*)  ualloc((size_t)P_ * NB_ * N_ * 2);
    u16*   xagg4   = (u16*)  ualloc((size_t)P_ * N_ * 256 * 2);   // 81.92 MB (all t,r)
    u16*   rank    = (u16*)  xagg4;   // overlay: rank dead before k_agg
    // phase 2 overlay (phase-1 sub-buffers dead after k_post)
    u16*   feats   = (u16*)  ubase;   // 10.24 MB
    (void)ws_size; (void)in_sizes; (void)n_in; (void)out_size;

    k_prep<<<72, 256, 0, stream>>>(Wdst, att_dst, Wih, Whh, bih, bhh, Wsrc, att_src, raW1,
                                   Wq, Wk, Wv, wdall, biasv, raW1_pad, Wc_pad, qkv_pad, postB_pad);
    k_hist<<<dim3(NB_, 8), 256, 0, stream>>>(ei, rank, partial);
    k_scan1<<<dim3(NB_, 8), 256, 0, stream>>>(partial, offsets, chunktot);
    k_scan2<<<1, 64, 0, stream>>>(chunktot, chunkbase);
    k_scan3<<<dim3(79, 8), 256, 0, stream>>>(offsets, chunkbase);
    k_scatter<<<10000, 256, 0, stream>>>(ei, offsets, rank, partial, csr);
    k_fold<<<dim3(313, 4), 256, 0, stream>>>(x, wdall, als_all, ald_all, x_h);
    k_agg<<<40000, 256, 0, stream>>>(offsets, csr, als_all, ald_all, x_h, xagg4);
    k_post<<<dim3(313, 2, 4), 256, 0, stream>>>(xagg4, postB_pad, intra);
    hipMemsetAsync(ssum, 0, 32, stream);
    k_relagg<<<2500, 256, 0, stream>>>(intra, raW1_pad, rab1, raW2, ssum);
    k_lstm<<<313, 256, 0, stream>>>(intra, ssum, Wc_pad, biasv, feats);
    k_attn<<<1250, 256, 0, stream>>>(feats, pos, qkv_pad, out);
}

// Round 6
// 450.752 us; speedup vs baseline: 1.1064x; 1.0247x over previous
//
#include <hip/hip_runtime.h>
#include <hip/hip_bf16.h>

#define T_ 4
#define N_ 20000
#define E_ 320000
#define R_ 2
#define DIN 64
#define G_ 256   // H*Dh
#define P_ 8     // T*R
#define BPAD 18432  // 256 * 72 padded B-table halves per 64-k chunk
#define NB_ 32      // CSR-build blocks per p
#define EPB_ 10000  // edges per CSR-build block
#define CHN_ 625    // nodes per scan chunk (N_/32)

typedef unsigned short u16;
typedef __attribute__((ext_vector_type(8))) short bf16x8;
typedef __attribute__((ext_vector_type(2))) _Float16 h2;
typedef __attribute__((ext_vector_type(4))) float f32x4;

__device__ __forceinline__ float bf2f(u16 u) {
    unsigned int i = ((unsigned int)u) << 16; float f;
    __builtin_memcpy(&f, &i, 4); return f;
}
__device__ __forceinline__ u16 f2bf(float f) {
    unsigned int i; __builtin_memcpy(&i, &f, 4);
    unsigned int r = i + 0x7fffu + ((i >> 16) & 1u);
    return (u16)(r >> 16);
}
__device__ __forceinline__ u16 f2h(float f) {
    union { _Float16 h; u16 u; } c; c.h = (_Float16)f; return c.u;
}
__device__ __forceinline__ float sigm(float x) { return 1.f / (1.f + __expf(-x)); }
// fast tanh: 1 - 2/(exp(2x)+1); hardware v_exp_f32, correct saturation at +-inf
__device__ __forceinline__ float ftanh(float x) { return 1.f - 2.f / (__expf(2.f * x) + 1.f); }
// broadcast lane l's float to all lanes (SGPR result); l must be wave-uniform
__device__ __forceinline__ float rdlanef(float v, int l) {
    int i; __builtin_memcpy(&i, &v, 4);
    int r = __builtin_amdgcn_readlane(i, l);
    float f; __builtin_memcpy(&f, &r, 4); return f;
}
// v_dot2_f32_f16: a.x*b.x + a.y*b.y + c in one VALU op
__device__ __forceinline__ float fdot2(h2 a, h2 b, float c) {
#if __has_builtin(__builtin_amdgcn_fdot2)
    return __builtin_amdgcn_fdot2(a, b, c, false);
#else
    float r;
    asm("v_dot2_f32_f16 %0, %1, %2, %3" : "=v"(r) : "v"(a), "v"(b), "v"(c));
    return r;
#endif
}
// pack 2 f32 -> 2 bf16 (RNE) in one VALU op
__device__ __forceinline__ unsigned cvtpk_bf16(float lo, float hi) {
    unsigned r;
    asm("v_cvt_pk_bf16_f32 %0, %1, %2" : "=v"(r) : "v"(lo), "v"(hi));
    return r;
}

// ---------------- LDS-free MFMA GEMM core (bf16 A) ----------------
__device__ __forceinline__ void gemm_direct(
    const u16* __restrict__ A, const u16* __restrict__ Bpad,
    int M, int Astride, int kchunks, int m0, f32x4* acc)
{
    const int tid = threadIdx.x;
    const int lane = tid & 63, wv = tid >> 6;
    const int col = lane & 15, quad = lane >> 4;
    #pragma unroll
    for (int cf = 0; cf < 16; ++cf) { acc[cf][0]=0.f; acc[cf][1]=0.f; acc[cf][2]=0.f; acc[cf][3]=0.f; }

    int row = m0 + wv * 16 + col;
    int row_c = (row < M) ? row : (M - 1);

    for (int kc = 0; kc < kchunks; ++kc) {
        #pragma unroll
        for (int ks = 0; ks < 2; ++ks) {
            bf16x8 a = *(const bf16x8*)(A + (size_t)row_c * Astride + kc * 64 + ks * 32 + quad * 8);
            const u16* bb = Bpad + kc * BPAD + ks * 32 + quad * 8;
            #pragma unroll
            for (int cf = 0; cf < 16; ++cf) {
                bf16x8 b = *(const bf16x8*)(bb + (cf * 16 + col) * 72);
                acc[cf] = __builtin_amdgcn_mfma_f32_16x16x32_bf16(a, b, acc[cf], 0, 0, 0);
            }
        }
    }
}

// ---------------- fold: als/ald GEMVs + x->f16 cast; wdall staged in LDS ----------------
__global__ __launch_bounds__(256) void k_fold(
    const float* __restrict__ x, const float* __restrict__ wdall,
    float* __restrict__ als_all, float* __restrict__ ald_all, u16* __restrict__ x_h)
{
    __shared__ float wds[1024];
    {
        int tid = threadIdx.x;
        *(float4*)(wds + tid * 4) = *(const float4*)(wdall + tid * 4);
    }
    __syncthreads();

    int t = blockIdx.y;
    int idx = blockIdx.x * 256 + threadIdx.x;
    if (idx >= N_ * 4) return;
    int n = idx >> 2, q = idx & 3;
    const float* xr = x + ((size_t)t * N_ + n) * 64 + q * 16;
    float4 xv[4];
    #pragma unroll
    for (int i = 0; i < 4; ++i) xv[i] = *(const float4*)(xr + i * 4);

    {
        union { u16 h[16]; ushort4 s4[4]; } cv;
        #pragma unroll
        for (int i = 0; i < 4; ++i) {
            cv.h[i*4+0] = f2h(xv[i].x); cv.h[i*4+1] = f2h(xv[i].y);
            cv.h[i*4+2] = f2h(xv[i].z); cv.h[i*4+3] = f2h(xv[i].w);
        }
        u16* xo = x_h + ((size_t)t * N_ + n) * 64 + q * 16;
        #pragma unroll
        for (int i = 0; i < 4; ++i) *(ushort4*)(xo + i * 4) = cv.s4[i];
    }

    float s[16];
    #pragma unroll
    for (int i = 0; i < 16; ++i) s[i] = 0.f;
    #pragma unroll
    for (int i = 0; i < 4; ++i) {
        float xe[4] = {xv[i].x, xv[i].y, xv[i].z, xv[i].w};
        #pragma unroll
        for (int e = 0; e < 4; ++e) {
            int k = q * 16 + i * 4 + e;
            float xk = xe[e];
            #pragma unroll
            for (int tb = 0; tb < 4; ++tb) {
                float4 w = *(const float4*)(wds + tb * 256 + k * 4);
                s[tb*4+0] += xk * w.x; s[tb*4+1] += xk * w.y;
                s[tb*4+2] += xk * w.z; s[tb*4+3] += xk * w.w;
            }
        }
    }
    #pragma unroll
    for (int i = 0; i < 16; ++i) {
        s[i] += __shfl_xor(s[i], 1);
        s[i] += __shfl_xor(s[i], 2);
    }
    if (q == 0) {
        *(float4*)(als_all + ((size_t)(t*2+0) * N_ + n) * 4) = make_float4(s[0], s[1], s[2], s[3]);
        *(float4*)(als_all + ((size_t)(t*2+1) * N_ + n) * 4) = make_float4(s[4], s[5], s[6], s[7]);
        *(float4*)(ald_all + ((size_t)(t*2+0) * N_ + n) * 4) = make_float4(s[8], s[9], s[10], s[11]);
        *(float4*)(ald_all + ((size_t)(t*2+1) * N_ + n) * 4) = make_float4(s[12], s[13], s[14], s[15]);
    }
}

// ---------------- prep: folded GEMV tables, padded B-tables, folded bias ----------------
__global__ void k_prep(const float* __restrict__ Wdst, const float* __restrict__ att_dst,
                       const float* __restrict__ Wih, const float* __restrict__ Whh,
                       const float* __restrict__ bih, const float* __restrict__ bhh,
                       const float* __restrict__ Wsrc, const float* __restrict__ att_src,
                       const float* __restrict__ raW1,
                       const float* __restrict__ Wq, const float* __restrict__ Wk,
                       const float* __restrict__ Wv,
                       float* __restrict__ wdall, float* __restrict__ biasv,
                       u16* __restrict__ raW1_pad, u16* __restrict__ Wc_pad,
                       u16* __restrict__ qkv_pad, u16* __restrict__ postB_pad)
{
    int tid = threadIdx.x, bid = blockIdx.x;
    if (bid == 0) {
        int k = tid >> 2, h = tid & 3;
        for (int r = 0; r < 2; ++r) {
            float ss = 0.f, sd = 0.f;
            for (int c = 0; c < 64; ++c) {
                ss += Wsrc[((size_t)r * 64 + k) * 256 + h * 64 + c] * att_src[r * 256 + h * 64 + c];
                sd += Wdst[((size_t)r * 64 + k) * 256 + h * 64 + c] * att_dst[r * 256 + h * 64 + c];
            }
            wdall[r * 256 + k * 4 + h] = ss;
            wdall[512 + r * 256 + k * 4 + h] = sd;
        }
        biasv[tid] = bih[tid] + bhh[tid];
    }
    for (int i = bid * 256 + tid; i < BPAD; i += gridDim.x * 256) {
        int n = i / 72, kk = i % 72;
        raW1_pad[i] = (kk < 64) ? f2bf(raW1[kk * 256 + n]) : (u16)0;
    }
    for (int i = bid * 256 + tid; i < 2 * BPAD; i += gridDim.x * 256) {
        int kc = i / BPAD, q = i % BPAD, n = q / 72, kk = q % 72;
        const float* W = kc ? Whh : Wih;
        Wc_pad[i] = (kk < 64) ? f2bf(W[n * 64 + kk]) : (u16)0;
    }
    for (int i = bid * 256 + tid; i < 192 * 72; i += gridDim.x * 256) {
        int g = i / 72, kk = i % 72;
        int j = g >> 6, c = g & 63;
        const float* W = (j == 0) ? Wq : (j == 1) ? Wk : Wv;
        qkv_pad[i] = (kk < 64) ? f2bf(W[kk * 64 + c]) : (u16)0;
    }
    for (int i = bid * 256 + tid; i < 2 * 4 * 4608; i += gridDim.x * 256) {
        int r = i / 18432, q = i % 18432, kc = q / 4608, qq = q % 4608;
        int c = qq / 72, kk = qq % 72;
        postB_pad[i] = (kk < 64) ? f2bf(Wsrc[(size_t)r * 16384 + kk * 256 + kc * 64 + c]) : (u16)0;
    }
}

// ---------------- CSR build ----------------
__global__ __launch_bounds__(256) void k_hist(const int* __restrict__ ei,
                                              u16* __restrict__ rank, u16* __restrict__ partial)
{
    __shared__ unsigned int hist[N_ / 2];
    int b = blockIdx.x, p = blockIdx.y, tid = threadIdx.x;
    for (int i = tid; i < N_ / 2; i += 256) hist[i] = 0u;
    __syncthreads();
    const int* dsts = ei + ((size_t)p * 2 + 1) * E_ + b * EPB_;
    u16* rk = rank + (size_t)p * E_ + b * EPB_;
    for (int e = tid; e < EPB_; e += 256) {
        int dst = dsts[e];
        unsigned sh = (unsigned)(dst & 1) * 16u;
        unsigned old = atomicAdd(&hist[dst >> 1], 1u << sh);
        rk[e] = (u16)((old >> sh) & 0xffffu);
    }
    __syncthreads();
    u16* part = partial + ((size_t)p * NB_ + b) * N_;
    for (int n = tid; n < N_; n += 256) {
        unsigned hv = hist[n >> 1];
        part[n] = (u16)((hv >> ((unsigned)(n & 1) * 16u)) & 0xffffu);
    }
}

__global__ __launch_bounds__(256) void k_scan1(u16* __restrict__ partial,
                                               int* __restrict__ offsets, int* __restrict__ chunktot)
{
    int p = blockIdx.y, ch = blockIdx.x;
    int tid = threadIdx.x, lane = tid & 63, wid = tid >> 6;
    __shared__ int wtot[4];
    u16* part = partial + (size_t)p * NB_ * N_;
    int* ofs = offsets + (size_t)p * (N_ + 1);
    int n0 = ch * CHN_;
    int carry = 0;
    for (int rnd = 0; rnd < 3; ++rnd) {
        int i = rnd * 256 + tid;
        int n = n0 + i;
        int v = 0;
        if (i < CHN_) {
            int run = 0;
            #pragma unroll 8
            for (int b = 0; b < NB_; ++b) {
                int pv = part[b * N_ + n];
                part[b * N_ + n] = (u16)run;
                run += pv;
            }
            v = run;
        }
        int incl = v;
        for (int d = 1; d < 64; d <<= 1) { int u = __shfl_up(incl, d); if (lane >= d) incl += u; }
        if (lane == 63) wtot[wid] = incl;
        __syncthreads();
        if (tid < 4) {
            int iv = wtot[tid];
            for (int d = 1; d < 4; d <<= 1) { int u = __shfl_up(iv, d); if (tid >= d) iv += u; }
            wtot[tid] = iv;
        }
        __syncthreads();
        int woff = (wid > 0) ? wtot[wid - 1] : 0;
        int tot = wtot[3];
        int excl = carry + woff + incl - v;
        if (i < CHN_) ofs[n] = excl;
        carry += tot;
        __syncthreads();
    }
    if (tid == 0) chunktot[p * NB_ + ch] = carry;
}

// scan3 now also does scan2's 32-element prefix locally (kills a 1-block launch)
__global__ void k_scan3(int* __restrict__ offsets, const int* __restrict__ chunktot) {
    __shared__ int cb[NB_];
    int p = blockIdx.y;
    int tid = threadIdx.x;
    if (tid < 64) {
        int v = (tid < NB_) ? chunktot[p * NB_ + tid] : 0;
        #pragma unroll
        for (int d = 1; d < NB_; d <<= 1) { int u = __shfl_up(v, d); if (tid >= d) v += u; }
        if (tid < NB_) cb[tid] = v;   // inclusive prefix
    }
    __syncthreads();
    int n = blockIdx.x * 256 + tid;
    if (n < N_) {
        int c = n / CHN_;
        int base = (c > 0) ? cb[c - 1] : 0;
        offsets[(size_t)p * (N_ + 1) + n] += base;
    }
    if (n == 0)
        offsets[(size_t)p * (N_ + 1) + N_] = E_;
}

// 1-D grid, p = bid & 7: round-robin dispatch pins each p to one XCD, so the
// random 2B csr writes (640 KB/p) stay in that XCD's L2 (kills the 8x write amp).
__global__ void k_scatter(const int* __restrict__ ei, const int* __restrict__ offsets,
                          const u16* __restrict__ rank, const u16* __restrict__ partial,
                          u16* __restrict__ csr) {
    int bid = blockIdx.x;
    int p = bid & 7;
    int e = (bid >> 3) * 256 + threadIdx.x;
    int src = ei[((size_t)p * 2 + 0) * E_ + e];
    int dst = ei[((size_t)p * 2 + 1) * E_ + e];
    int b = e / EPB_;
    int pos = offsets[p * (N_ + 1) + dst]
            + (int)partial[((size_t)p * NB_ + b) * N_ + dst]
            + (int)rank[(size_t)p * E_ + e];
    csr[(size_t)p * E_ + pos] = (u16)src;
}

// ---------------- GAT aggregation: 4 nodes per wave, dot2 pairs ----------------
// Per-wave fixed costs (p-phase, den-reduce, loop control) amortized over 4 nodes:
// p-phase lane = (node-group g = lane>>4, edge slot el = lane&15) -> all 64 lanes
// compute useful exps per 16-edge round; den-reduce is 4 xor levels within the
// 16-lane group. x-phase: lane = column; per node q (uniform scalar skip when
// exhausted) 8 edge-pairs: 2 readlane -> SGPR gather base, pack, uniform
// ds_read_b128 of 4 head p-pairs, 4 v_dot2_f32_f16. Epilogue via v_cvt_pk_bf16.
// 1-D grid with p = bid & 7 pins each (t,r) partition to one XCD.
__global__ __launch_bounds__(256) void k_agg(
    const int* __restrict__ offsets, const u16* __restrict__ csr,
    const float* __restrict__ als_all, const float* __restrict__ ald_all,
    const u16* __restrict__ x_h, u16* __restrict__ xagg4)
{
    // ptab[wv][g][pair*8 + h*2 + (el&1)]  (per-g 128B regions, 16B aligned)
    __shared__ __align__(16) u16 ptab[4][4][64];
    const int bid = blockIdx.x;
    const int p = bid & 7;
    const int t = p >> 1;
    const int* off   = offsets + (size_t)p * (N_ + 1);
    const u16* srcs  = csr + (size_t)p * E_;
    const float* als = als_all + (size_t)p * N_ * 4;
    const float* ald = ald_all + (size_t)p * N_ * 4;
    const u16* xb    = x_h + (size_t)t * N_ * 64;

    const int tid = threadIdx.x, lane = tid & 63, wv = tid >> 6;
    const int g = lane >> 4, el = lane & 15;
    const int n0 = (bid >> 3) * 16 + wv * 4;   // 4 nodes per wave
    const int ng = n0 + g;
    const int o0 = off[ng], o1 = off[ng + 1];
    const int deg = o1 - o0;
    const float4 aldv = *(const float4*)(ald + (size_t)ng * 4);
    u16* pt = &ptab[wv][0][0];
    const int pw = g * 64 + (el >> 1) * 8 + (el & 1);

    int sdeg[4];
    #pragma unroll
    for (int q = 0; q < 4; ++q) sdeg[q] = __builtin_amdgcn_readlane(deg, q * 16);
    int mdeg = max(max(sdeg[0], sdeg[1]), max(sdeg[2], sdeg[3]));
    int nrounds = (mdeg + 15) >> 4;

    float acc[4][4];
    #pragma unroll
    for (int q = 0; q < 4; ++q)
        #pragma unroll
        for (int h = 0; h < 4; ++h) acc[q][h] = 0.f;
    float d0 = 0.f, d1 = 0.f, d2 = 0.f, d3 = 0.f;

    for (int rr = 0; rr < nrounds; ++rr) {
        int e = rr * 16 + el;
        int sv = 0;
        float p0 = 0.f, p1 = 0.f, p2 = 0.f, p3 = 0.f;
        if (e < deg) {
            sv = (int)srcs[o0 + e];
            float4 av = *(const float4*)(als + (size_t)sv * 4);
            float e0 = av.x + aldv.x, e1 = av.y + aldv.y;
            float e2 = av.z + aldv.z, e3 = av.w + aldv.w;
            e0 = fmaxf(e0, 0.2f * e0); e1 = fmaxf(e1, 0.2f * e1);
            e2 = fmaxf(e2, 0.2f * e2); e3 = fmaxf(e3, 0.2f * e3);
            p0 = __expf(e0); p1 = __expf(e1); p2 = __expf(e2); p3 = __expf(e3);
        }
        d0 += p0; d1 += p1; d2 += p2; d3 += p3;
        pt[pw + 0] = f2h(p0); pt[pw + 2] = f2h(p1);
        pt[pw + 4] = f2h(p2); pt[pw + 6] = f2h(p3);
        // x-phase: in-order DS within the wave -> ptab written above is visible
        #pragma unroll
        for (int q = 0; q < 4; ++q) {
            if (sdeg[q] > rr * 16) {
                const u16* ptq = pt + q * 64;
                #pragma unroll
                for (int pr = 0; pr < 8; ++pr) {
                    int s0i = __builtin_amdgcn_readlane(sv, q * 16 + pr * 2);
                    int s1i = __builtin_amdgcn_readlane(sv, q * 16 + pr * 2 + 1);
                    unsigned x0 = xb[((size_t)(unsigned)s0i << 6) + lane];
                    unsigned x1 = xb[((size_t)(unsigned)s1i << 6) + lane];
                    unsigned xp = x0 | (x1 << 16);
                    uint4 ppv = *(const uint4*)(ptq + pr * 8);
                    h2 xv, q0, q1, q2, q3;
                    __builtin_memcpy(&xv, &xp, 4);
                    __builtin_memcpy(&q0, &ppv.x, 4);
                    __builtin_memcpy(&q1, &ppv.y, 4);
                    __builtin_memcpy(&q2, &ppv.z, 4);
                    __builtin_memcpy(&q3, &ppv.w, 4);
                    acc[q][0] = fdot2(xv, q0, acc[q][0]);
                    acc[q][1] = fdot2(xv, q1, acc[q][1]);
                    acc[q][2] = fdot2(xv, q2, acc[q][2]);
                    acc[q][3] = fdot2(xv, q3, acc[q][3]);
                }
            }
        }
    }
    // den reduce within each 16-lane group (xor masks < 16 stay in-group)
    d0 += __shfl_xor(d0, 1); d0 += __shfl_xor(d0, 2);
    d0 += __shfl_xor(d0, 4); d0 += __shfl_xor(d0, 8);
    d1 += __shfl_xor(d1, 1); d1 += __shfl_xor(d1, 2);
    d1 += __shfl_xor(d1, 4); d1 += __shfl_xor(d1, 8);
    d2 += __shfl_xor(d2, 1); d2 += __shfl_xor(d2, 2);
    d2 += __shfl_xor(d2, 4); d2 += __shfl_xor(d2, 8);
    d3 += __shfl_xor(d3, 1); d3 += __shfl_xor(d3, 2);
    d3 += __shfl_xor(d3, 4); d3 += __shfl_xor(d3, 8);
    #pragma unroll
    for (int q = 0; q < 4; ++q) {
        float s0 = 0.25f / (rdlanef(d0, q * 16) + 1e-16f);
        float s1 = 0.25f / (rdlanef(d1, q * 16) + 1e-16f);
        float s2 = 0.25f / (rdlanef(d2, q * 16) + 1e-16f);
        float s3 = 0.25f / (rdlanef(d3, q * 16) + 1e-16f);
        unsigned w01 = cvtpk_bf16(acc[q][0] * s0, acc[q][1] * s1);
        unsigned w23 = cvtpk_bf16(acc[q][2] * s2, acc[q][3] * s3);
        u16* outp = xagg4 + ((size_t)p * N_ + n0 + q) * 256 + lane;
        outp[0]   = (u16)w01;  outp[64]  = (u16)(w01 >> 16);
        outp[128] = (u16)w23;  outp[192] = (u16)(w23 >> 16);
    }
}

// ---------------- post-projection: intra = xagg @ B~ (all t in one dispatch) ----------------
__global__ __launch_bounds__(256) void k_post(
    const u16* __restrict__ xagg4, const u16* __restrict__ postB_pad,
    u16* __restrict__ intra)
{
    const int t = blockIdx.z, r = blockIdx.y;
    const u16* A = xagg4 + ((size_t)(t * 2 + r)) * N_ * 256;
    const u16* Bp = postB_pad + (size_t)r * 4 * 4608;
    const int tid = threadIdx.x, lane = tid & 63, wv = tid >> 6;
    const int col = lane & 15, quad = lane >> 4;
    int m0 = blockIdx.x * 64;
    int row = m0 + wv * 16 + col;
    int row_c = (row < N_) ? row : (N_ - 1);

    f32x4 acc[4];
    #pragma unroll
    for (int cf = 0; cf < 4; ++cf) { acc[cf][0]=0.f; acc[cf][1]=0.f; acc[cf][2]=0.f; acc[cf][3]=0.f; }
    #pragma unroll
    for (int kc = 0; kc < 4; ++kc) {
        #pragma unroll
        for (int ks = 0; ks < 2; ++ks) {
            bf16x8 a = *(const bf16x8*)(A + (size_t)row_c * 256 + kc * 64 + ks * 32 + quad * 8);
            const u16* bb = Bp + kc * 4608 + ks * 32 + quad * 8;
            #pragma unroll
            for (int cf = 0; cf < 4; ++cf) {
                bf16x8 b = *(const bf16x8*)(bb + (cf * 16 + col) * 72);
                acc[cf] = __builtin_amdgcn_mfma_f32_16x16x32_bf16(a, b, acc[cf], 0, 0, 0);
            }
        }
    }
    int rowbase = m0 + wv * 16 + quad * 4;
    #pragma unroll
    for (int cf = 0; cf < 4; ++cf) {
        int c = cf * 16 + col;
        #pragma unroll
        for (int reg = 0; reg < 4; ++reg) {
            int rr = rowbase + reg;
            if (rr < N_)
                intra[(((size_t)t * N_ + rr) * 2 + r) * 64 + c] = f2bf(acc[cf][reg]);
        }
    }
}

// ---------------- RelationAgg GEMM with fused ftanh(.)@W2 epilogue + fused beta sums ----------------
__global__ __launch_bounds__(256) void k_relagg(
    const u16* __restrict__ A, const u16* __restrict__ W1pad, const float* __restrict__ b1,
    const float* __restrict__ W2, float* __restrict__ ssum)
{
    int m0 = blockIdx.x * 64;
    f32x4 acc[16];
    gemm_direct(A, W1pad, T_ * N_ * R_, 64, 1, m0, acc);

    const int tid = threadIdx.x, lane = tid & 63, wv = tid >> 6;
    const int col = lane & 15;
    float sp[4] = {0.f, 0.f, 0.f, 0.f};
    #pragma unroll
    for (int cf = 0; cf < 16; ++cf) {
        int gcol = cf * 16 + col;
        float bb = b1[gcol];
        float ww = W2[gcol];
        #pragma unroll
        for (int reg = 0; reg < 4; ++reg)
            sp[reg] += ftanh(acc[cf][reg] + bb) * ww;
    }
    #pragma unroll
    for (int reg = 0; reg < 4; ++reg) {
        float v = sp[reg];
        v += __shfl_xor(v, 1); v += __shfl_xor(v, 2);
        v += __shfl_xor(v, 4); v += __shfl_xor(v, 8);
        sp[reg] = v;
    }
    // rows = m0 + wv*16 + quad*4 + reg ; rowbase is even so reg parity == r
    float se = sp[0] + sp[2];   // r = 0 rows of this lane's quad
    float so = sp[1] + sp[3];   // r = 1 rows
    se += __shfl_xor(se, 16); se += __shfl_xor(se, 32);
    so += __shfl_xor(so, 16); so += __shfl_xor(so, 32);
    __shared__ float red[8];
    if (lane == 0) { red[wv * 2] = se; red[wv * 2 + 1] = so; }
    __syncthreads();
    if (tid == 0) {
        float s0 = red[0] + red[2] + red[4] + red[6];
        float s1 = red[1] + red[3] + red[5] + red[7];
        int t = m0 / (N_ * R_);
        atomicAdd(&ssum[t * 2 + 0], s0);
        atomicAdd(&ssum[t * 2 + 1], s1);
    }
}

// ---------------- LSTM: all 4 timesteps in one kernel; c in regs, h in LDS ----------------
__global__ __launch_bounds__(256) void k_lstm(
    const u16* __restrict__ intra, const float* __restrict__ ssum,
    const u16* __restrict__ Wc_pad, const float* __restrict__ biasv,
    u16* __restrict__ feats)
{
    __shared__ __align__(16) u16 hl[64][72];   // h state, bf16, wave-private 16-row stripes
    const int tid = threadIdx.x, lane = tid & 63, wv = tid >> 6;
    const int col = lane & 15, quad = lane >> 4;
    int m0 = blockIdx.x * 64;
    int row = m0 + wv * 16 + col;
    int row_c = (row < N_) ? row : (N_ - 1);
    int rowbase = m0 + wv * 16 + quad * 4;

    float betas[8];
    #pragma unroll
    for (int t = 0; t < 4; ++t) {
        float s0 = ssum[t * 2] * (1.f / N_), s1 = ssum[t * 2 + 1] * (1.f / N_);
        float mx = fmaxf(s0, s1);
        float e0 = __expf(s0 - mx), e1 = __expf(s1 - mx);
        float inv = 1.f / (e0 + e1);
        betas[t * 2] = e0 * inv; betas[t * 2 + 1] = e1 * inv;
    }

    float cc[4][4];
    #pragma unroll
    for (int j = 0; j < 4; ++j)
        #pragma unroll
        for (int reg = 0; reg < 4; ++reg) cc[j][reg] = 0.f;

    for (int t = 0; t < 4; ++t) {
        float b0 = betas[t * 2], b1 = betas[t * 2 + 1];
        const u16* ib = intra + ((size_t)t * N_ + row_c) * 128;

        f32x4 acc[16];
        #pragma unroll
        for (int cf = 0; cf < 16; ++cf) { acc[cf][0]=0.f; acc[cf][1]=0.f; acc[cf][2]=0.f; acc[cf][3]=0.f; }

        #pragma unroll
        for (int ks = 0; ks < 2; ++ks) {
            int coff = ks * 32 + quad * 8;
            bf16x8 i0 = *(const bf16x8*)(ib + coff);
            bf16x8 i1 = *(const bf16x8*)(ib + 64 + coff);
            union { u16 h[8]; bf16x8 v; } cv;
            #pragma unroll
            for (int j = 0; j < 8; ++j)
                cv.h[j] = f2bf(b0 * bf2f((u16)i0[j]) + b1 * bf2f((u16)i1[j]));
            const u16* bb = Wc_pad + ks * 32 + quad * 8;
            #pragma unroll
            for (int cf = 0; cf < 16; ++cf) {
                bf16x8 b = *(const bf16x8*)(bb + (cf * 16 + col) * 72);
                acc[cf] = __builtin_amdgcn_mfma_f32_16x16x32_bf16(cv.v, b, acc[cf], 0, 0, 0);
            }
        }
        if (t > 0) {
            #pragma unroll
            for (int ks = 0; ks < 2; ++ks) {
                bf16x8 a = *(const bf16x8*)&hl[wv * 16 + col][ks * 32 + quad * 8];
                const u16* bb = Wc_pad + BPAD + ks * 32 + quad * 8;
                #pragma unroll
                for (int cf = 0; cf < 16; ++cf) {
                    bf16x8 b = *(const bf16x8*)(bb + (cf * 16 + col) * 72);
                    acc[cf] = __builtin_amdgcn_mfma_f32_16x16x32_bf16(a, b, acc[cf], 0, 0, 0);
                }
            }
        }

        #pragma unroll
        for (int j = 0; j < 4; ++j) {
            int c = j * 16 + col;
            float bi = biasv[c], bf_ = biasv[64 + c], bg = biasv[128 + c], bo = biasv[192 + c];
            #pragma unroll
            for (int reg = 0; reg < 4; ++reg) {
                float gi = acc[j][reg] + bi;
                float gf = acc[j + 4][reg] + bf_;
                float gg = acc[j + 8][reg] + bg;
                float go = acc[j + 12][reg] + bo;
                float c2 = sigm(gf) * cc[j][reg] + sigm(gi) * ftanh(gg);
                float hh = sigm(go) * ftanh(c2);
                cc[j][reg] = c2;
                u16 hb = f2bf(hh);
                hl[wv * 16 + quad * 4 + reg][c] = hb;
                int rr = rowbase + reg;
                if (rr < N_)
                    feats[(size_t)rr * 256 + t * 64 + c] = hb;
            }
        }
    }
}

// ---------------- temporal causal MHA: MFMA QKV + per-lane attention ----------------
__global__ __launch_bounds__(256) void k_attn(
    const u16* __restrict__ feats, const float* __restrict__ pos_emb,
    const u16* __restrict__ qkv_pad, float* __restrict__ out)
{
    __shared__ float qkv_s[64 * 200];
    const int tid = threadIdx.x, lane = tid & 63, wv = tid >> 6;
    const int col = lane & 15, quad = lane >> 4;
    int m0 = blockIdx.x * 64;
    int row = m0 + wv * 16 + col;
    int trow = row & 3;

    f32x4 acc[12];
    #pragma unroll
    for (int cf = 0; cf < 12; ++cf) { acc[cf][0]=0.f; acc[cf][1]=0.f; acc[cf][2]=0.f; acc[cf][3]=0.f; }
    #pragma unroll
    for (int ks = 0; ks < 2; ++ks) {
        int coff = ks * 32 + quad * 8;
        bf16x8 fv = *(const bf16x8*)(feats + (size_t)row * 64 + coff);
        float4 p0 = *(const float4*)(pos_emb + trow * 64 + coff);
        float4 p1 = *(const float4*)(pos_emb + trow * 64 + coff + 4);
        union { u16 h[8]; bf16x8 v; } cv;
        cv.h[0] = f2bf(bf2f((u16)fv[0]) + p0.x); cv.h[1] = f2bf(bf2f((u16)fv[1]) + p0.y);
        cv.h[2] = f2bf(bf2f((u16)fv[2]) + p0.z); cv.h[3] = f2bf(bf2f((u16)fv[3]) + p0.w);
        cv.h[4] = f2bf(bf2f((u16)fv[4]) + p1.x); cv.h[5] = f2bf(bf2f((u16)fv[5]) + p1.y);
        cv.h[6] = f2bf(bf2f((u16)fv[6]) + p1.z); cv.h[7] = f2bf(bf2f((u16)fv[7]) + p1.w);
        bf16x8 a = cv.v;
        const u16* bb = qkv_pad + ks * 32 + quad * 8;
        #pragma unroll
        for (int cf = 0; cf < 12; ++cf) {
            bf16x8 b = *(const bf16x8*)(bb + (cf * 16 + col) * 72);
            acc[cf] = __builtin_amdgcn_mfma_f32_16x16x32_bf16(a, b, acc[cf], 0, 0, 0);
        }
    }
    #pragma unroll
    for (int cf = 0; cf < 12; ++cf) {
        int g = cf * 16 + col;
        #pragma unroll
        for (int reg = 0; reg < 4; ++reg) {
            int rl = wv * 16 + quad * 4 + reg;
            qkv_s[rl * 200 + g] = acc[cf][reg];
        }
    }
    __syncthreads();

    int nl = wv * 4 + (lane >> 4);
    int sub = lane & 15;
    int h = sub >> 2, tq = sub & 3;
    const float* qrow = qkv_s + (nl * 4 + tq) * 200 + h * 16;

    float s[4];
    #pragma unroll
    for (int tk = 0; tk < 4; ++tk) {
        const float* krow = qkv_s + (nl * 4 + tk) * 200 + 64 + h * 16;
        float d = 0.f;
        #pragma unroll
        for (int j = 0; j < 16; ++j) d += qrow[j] * krow[j];
        s[tk] = (tk > tq) ? -4294967295.0f : d * 0.5f;
    }
    float mx = fmaxf(fmaxf(s[0], s[1]), fmaxf(s[2], s[3]));
    float a0 = __expf(s[0]-mx), a1 = __expf(s[1]-mx), a2 = __expf(s[2]-mx), a3 = __expf(s[3]-mx);
    float inv = 1.f / (a0 + a1 + a2 + a3);
    a0 *= inv; a1 *= inv; a2 *= inv; a3 *= inv;

    int n = blockIdx.x * 16 + nl;
    const float* v0 = qkv_s + (nl * 4 + 0) * 200 + 128 + h * 16;
    const float* v1 = v0 + 200, *v2 = v0 + 400, *v3 = v0 + 600;
    #pragma unroll
    for (int cc4 = 0; cc4 < 4; ++cc4) {
        float4 o;
        o.x = a0*v0[cc4*4+0] + a1*v1[cc4*4+0] + a2*v2[cc4*4+0] + a3*v3[cc4*4+0];
        o.y = a0*v0[cc4*4+1] + a1*v1[cc4*4+1] + a2*v2[cc4*4+1] + a3*v3[cc4*4+1];
        o.z = a0*v0[cc4*4+2] + a1*v1[cc4*4+2] + a2*v2[cc4*4+2] + a3*v3[cc4*4+2];
        o.w = a0*v0[cc4*4+3] + a1*v1[cc4*4+3] + a2*v2[cc4*4+3] + a3*v3[cc4*4+3];
        *(float4*)(out + (size_t)n * 256 + tq * 64 + h * 16 + cc4 * 4) = o;
    }
}

// ---------------- launcher ----------------
extern "C" void kernel_launch(void* const* d_in, const int* in_sizes, int n_in,
                              void* d_out, int out_size, void* d_ws, size_t ws_size,
                              hipStream_t stream) {
    const float* x     = (const float*)d_in[0];
    const int* ei      = (const int*)d_in[1];
    const float* Wsrc  = (const float*)d_in[2];
    const float* Wdst  = (const float*)d_in[3];
    const float* att_src = (const float*)d_in[4];
    const float* att_dst = (const float*)d_in[5];
    const float* raW1  = (const float*)d_in[6];
    const float* rab1  = (const float*)d_in[7];
    const float* raW2  = (const float*)d_in[8];
    const float* Wih   = (const float*)d_in[9];
    const float* Whh   = (const float*)d_in[10];
    const float* bih   = (const float*)d_in[11];
    const float* bhh   = (const float*)d_in[12];
    const float* pos   = (const float*)d_in[13];
    const float* Wq    = (const float*)d_in[14];
    const float* Wk    = (const float*)d_in[15];
    const float* Wv    = (const float*)d_in[16];
    float* out = (float*)d_out;

    char* w = (char*)d_ws;
    size_t off = 0;
    auto alloc = [&](size_t bytes) -> char* {
        char* pp = w + off; off += (bytes + 255) & ~(size_t)255; return pp;
    };
    // ---- long-lived ----
    u16*   intra     = (u16*)  alloc((size_t)T_ * N_ * R_ * 64 * 2);  // 20.48 MB
    u16*   x_h       = (u16*)  alloc((size_t)T_ * N_ * 64 * 2);       // 10.24 MB (f16)
    float* ssum      = (float*)alloc(256);
    float* wdall     = (float*)alloc(1024 * 4);
    float* biasv     = (float*)alloc(256 * 4);
    u16*   raW1_pad  = (u16*)  alloc(BPAD * 2);
    u16*   Wc_pad    = (u16*)  alloc(2 * BPAD * 2);
    u16*   qkv_pad   = (u16*)  alloc(192 * 72 * 2);
    u16*   postB_pad = (u16*)  alloc(2 * 4 * 4608 * 2);
    int*   chunktot  = (int*)  alloc(P_ * NB_ * 4);
    // ---- union region ----
    char*  ubase   = alloc(0);
    size_t uoff = 0;
    auto ualloc = [&](size_t bytes) -> char* {
        char* pp = ubase + uoff; uoff += (bytes + 255) & ~(size_t)255; return pp;
    };
    int*   offsets = (int*)  ualloc((size_t)P_ * (N_ + 1) * 4);
    u16*   csr     = (u16*)  ualloc((size_t)P_ * E_ * 2);
    float* als_all = (float*)ualloc((size_t)P_ * N_ * 4 * 4);
    float* ald_all = (float*)ualloc((size_t)P_ * N_ * 4 * 4);
    u16*   partial = (u16*)  ualloc((size_t)P_ * NB_ * N_ * 2);
    u16*   xagg4   = (u16*)  ualloc((size_t)P_ * N_ * 256 * 2);   // 81.92 MB (all t,r)
    u16*   rank    = (u16*)  xagg4;   // overlay: rank dead before k_agg
    // phase 2 overlay (phase-1 sub-buffers dead after k_post)
    u16*   feats   = (u16*)  ubase;   // 10.24 MB
    (void)ws_size; (void)in_sizes; (void)n_in; (void)out_size;

    k_prep<<<72, 256, 0, stream>>>(Wdst, att_dst, Wih, Whh, bih, bhh, Wsrc, att_src, raW1,
                                   Wq, Wk, Wv, wdall, biasv, raW1_pad, Wc_pad, qkv_pad, postB_pad);
    k_hist<<<dim3(NB_, 8), 256, 0, stream>>>(ei, rank, partial);
    k_scan1<<<dim3(NB_, 8), 256, 0, stream>>>(partial, offsets, chunktot);
    k_scan3<<<dim3(79, 8), 256, 0, stream>>>(offsets, chunktot);
    k_scatter<<<10000, 256, 0, stream>>>(ei, offsets, rank, partial, csr);
    k_fold<<<dim3(313, 4), 256, 0, stream>>>(x, wdall, als_all, ald_all, x_h);
    k_agg<<<10000, 256, 0, stream>>>(offsets, csr, als_all, ald_all, x_h, xagg4);
    k_post<<<dim3(313, 2, 4), 256, 0, stream>>>(xagg4, postB_pad, intra);
    hipMemsetAsync(ssum, 0, 32, stream);
    k_relagg<<<2500, 256, 0, stream>>>(intra, raW1_pad, rab1, raW2, ssum);
    k_lstm<<<313, 256, 0, stream>>>(intra, ssum, Wc_pad, biasv, feats);
    k_attn<<<1250, 256, 0, stream>>>(feats, pos, qkv_pad, out);
}

// Round 7
// 438.006 us; speedup vs baseline: 1.1385x; 1.0291x over previous
//
#include <hip/hip_runtime.h>
#include <hip/hip_bf16.h>

#define T_ 4
#define N_ 20000
#define E_ 320000
#define R_ 2
#define DIN 64
#define G_ 256   // H*Dh
#define P_ 8     // T*R
#define BPAD 18432  // 256 * 72 padded B-table halves per 64-k chunk
#define NB_ 32      // CSR-build blocks per p
#define EPB_ 10000  // edges per CSR-build block
#define CHN_ 625    // nodes per scan chunk (N_/32)

typedef unsigned short u16;
typedef __attribute__((ext_vector_type(8))) short bf16x8;
typedef __attribute__((ext_vector_type(2))) _Float16 h2;
typedef __attribute__((ext_vector_type(4))) float f32x4;

__device__ __forceinline__ float bf2f(u16 u) {
    unsigned int i = ((unsigned int)u) << 16; float f;
    __builtin_memcpy(&f, &i, 4); return f;
}
__device__ __forceinline__ u16 f2bf(float f) {
    unsigned int i; __builtin_memcpy(&i, &f, 4);
    unsigned int r = i + 0x7fffu + ((i >> 16) & 1u);
    return (u16)(r >> 16);
}
__device__ __forceinline__ u16 f2h(float f) {
    union { _Float16 h; u16 u; } c; c.h = (_Float16)f; return c.u;
}
__device__ __forceinline__ float sigm(float x) { return 1.f / (1.f + __expf(-x)); }
// fast tanh: 1 - 2/(exp(2x)+1); hardware v_exp_f32, correct saturation at +-inf
__device__ __forceinline__ float ftanh(float x) { return 1.f - 2.f / (__expf(2.f * x) + 1.f); }
// broadcast lane l's float to all lanes (SGPR result); l must be wave-uniform
__device__ __forceinline__ float rdlanef(float v, int l) {
    int i; __builtin_memcpy(&i, &v, 4);
    int r = __builtin_amdgcn_readlane(i, l);
    float f; __builtin_memcpy(&f, &r, 4); return f;
}
// v_dot2_f32_f16: a.x*b.x + a.y*b.y + c in one VALU op
__device__ __forceinline__ float fdot2(h2 a, h2 b, float c) {
#if __has_builtin(__builtin_amdgcn_fdot2)
    return __builtin_amdgcn_fdot2(a, b, c, false);
#else
    float r;
    asm("v_dot2_f32_f16 %0, %1, %2, %3" : "=v"(r) : "v"(a), "v"(b), "v"(c));
    return r;
#endif
}
// pack 2 f32 -> 2 bf16 (RNE) in one VALU op
__device__ __forceinline__ unsigned cvtpk_bf16(float lo, float hi) {
    unsigned r;
    asm("v_cvt_pk_bf16_f32 %0, %1, %2" : "=v"(r) : "v"(lo), "v"(hi));
    return r;
}

// ---------------- LDS-free MFMA GEMM core (bf16 A) ----------------
__device__ __forceinline__ void gemm_direct(
    const u16* __restrict__ A, const u16* __restrict__ Bpad,
    int M, int Astride, int kchunks, int m0, f32x4* acc)
{
    const int tid = threadIdx.x;
    const int lane = tid & 63, wv = tid >> 6;
    const int col = lane & 15, quad = lane >> 4;
    #pragma unroll
    for (int cf = 0; cf < 16; ++cf) { acc[cf][0]=0.f; acc[cf][1]=0.f; acc[cf][2]=0.f; acc[cf][3]=0.f; }

    int row = m0 + wv * 16 + col;
    int row_c = (row < M) ? row : (M - 1);

    for (int kc = 0; kc < kchunks; ++kc) {
        #pragma unroll
        for (int ks = 0; ks < 2; ++ks) {
            bf16x8 a = *(const bf16x8*)(A + (size_t)row_c * Astride + kc * 64 + ks * 32 + quad * 8);
            const u16* bb = Bpad + kc * BPAD + ks * 32 + quad * 8;
            #pragma unroll
            for (int cf = 0; cf < 16; ++cf) {
                bf16x8 b = *(const bf16x8*)(bb + (cf * 16 + col) * 72);
                acc[cf] = __builtin_amdgcn_mfma_f32_16x16x32_bf16(a, b, acc[cf], 0, 0, 0);
            }
        }
    }
}

// ---------------- fold: als/ald GEMVs + x->f16 cast; wdall staged in LDS ----------------
__global__ __launch_bounds__(256) void k_fold(
    const float* __restrict__ x, const float* __restrict__ wdall,
    float* __restrict__ als_all, float* __restrict__ ald_all, u16* __restrict__ x_h)
{
    __shared__ float wds[1024];
    {
        int tid = threadIdx.x;
        *(float4*)(wds + tid * 4) = *(const float4*)(wdall + tid * 4);
    }
    __syncthreads();

    int t = blockIdx.y;
    int idx = blockIdx.x * 256 + threadIdx.x;
    if (idx >= N_ * 4) return;
    int n = idx >> 2, q = idx & 3;
    const float* xr = x + ((size_t)t * N_ + n) * 64 + q * 16;
    float4 xv[4];
    #pragma unroll
    for (int i = 0; i < 4; ++i) xv[i] = *(const float4*)(xr + i * 4);

    {
        union { u16 h[16]; ushort4 s4[4]; } cv;
        #pragma unroll
        for (int i = 0; i < 4; ++i) {
            cv.h[i*4+0] = f2h(xv[i].x); cv.h[i*4+1] = f2h(xv[i].y);
            cv.h[i*4+2] = f2h(xv[i].z); cv.h[i*4+3] = f2h(xv[i].w);
        }
        u16* xo = x_h + ((size_t)t * N_ + n) * 64 + q * 16;
        #pragma unroll
        for (int i = 0; i < 4; ++i) *(ushort4*)(xo + i * 4) = cv.s4[i];
    }

    float s[16];
    #pragma unroll
    for (int i = 0; i < 16; ++i) s[i] = 0.f;
    #pragma unroll
    for (int i = 0; i < 4; ++i) {
        float xe[4] = {xv[i].x, xv[i].y, xv[i].z, xv[i].w};
        #pragma unroll
        for (int e = 0; e < 4; ++e) {
            int k = q * 16 + i * 4 + e;
            float xk = xe[e];
            #pragma unroll
            for (int tb = 0; tb < 4; ++tb) {
                float4 w = *(const float4*)(wds + tb * 256 + k * 4);
                s[tb*4+0] += xk * w.x; s[tb*4+1] += xk * w.y;
                s[tb*4+2] += xk * w.z; s[tb*4+3] += xk * w.w;
            }
        }
    }
    #pragma unroll
    for (int i = 0; i < 16; ++i) {
        s[i] += __shfl_xor(s[i], 1);
        s[i] += __shfl_xor(s[i], 2);
    }
    if (q == 0) {
        *(float4*)(als_all + ((size_t)(t*2+0) * N_ + n) * 4) = make_float4(s[0], s[1], s[2], s[3]);
        *(float4*)(als_all + ((size_t)(t*2+1) * N_ + n) * 4) = make_float4(s[4], s[5], s[6], s[7]);
        *(float4*)(ald_all + ((size_t)(t*2+0) * N_ + n) * 4) = make_float4(s[8], s[9], s[10], s[11]);
        *(float4*)(ald_all + ((size_t)(t*2+1) * N_ + n) * 4) = make_float4(s[12], s[13], s[14], s[15]);
    }
}

// ---------------- prep: folded GEMV tables, padded B-tables, folded bias ----------------
__global__ void k_prep(const float* __restrict__ Wdst, const float* __restrict__ att_dst,
                       const float* __restrict__ Wih, const float* __restrict__ Whh,
                       const float* __restrict__ bih, const float* __restrict__ bhh,
                       const float* __restrict__ Wsrc, const float* __restrict__ att_src,
                       const float* __restrict__ raW1,
                       const float* __restrict__ Wq, const float* __restrict__ Wk,
                       const float* __restrict__ Wv,
                       float* __restrict__ wdall, float* __restrict__ biasv,
                       u16* __restrict__ raW1_pad, u16* __restrict__ Wc_pad,
                       u16* __restrict__ qkv_pad, u16* __restrict__ postB_pad,
                       float* __restrict__ ssum)
{
    int tid = threadIdx.x, bid = blockIdx.x;
    if (bid == 0) {
        if (tid < 8) ssum[tid] = 0.f;
        int k = tid >> 2, h = tid & 3;
        for (int r = 0; r < 2; ++r) {
            float ss = 0.f, sd = 0.f;
            for (int c = 0; c < 64; ++c) {
                ss += Wsrc[((size_t)r * 64 + k) * 256 + h * 64 + c] * att_src[r * 256 + h * 64 + c];
                sd += Wdst[((size_t)r * 64 + k) * 256 + h * 64 + c] * att_dst[r * 256 + h * 64 + c];
            }
            wdall[r * 256 + k * 4 + h] = ss;
            wdall[512 + r * 256 + k * 4 + h] = sd;
        }
        biasv[tid] = bih[tid] + bhh[tid];
    }
    for (int i = bid * 256 + tid; i < BPAD; i += gridDim.x * 256) {
        int n = i / 72, kk = i % 72;
        raW1_pad[i] = (kk < 64) ? f2bf(raW1[kk * 256 + n]) : (u16)0;
    }
    for (int i = bid * 256 + tid; i < 2 * BPAD; i += gridDim.x * 256) {
        int kc = i / BPAD, q = i % BPAD, n = q / 72, kk = q % 72;
        const float* W = kc ? Whh : Wih;
        Wc_pad[i] = (kk < 64) ? f2bf(W[n * 64 + kk]) : (u16)0;
    }
    for (int i = bid * 256 + tid; i < 192 * 72; i += gridDim.x * 256) {
        int g = i / 72, kk = i % 72;
        int j = g >> 6, c = g & 63;
        const float* W = (j == 0) ? Wq : (j == 1) ? Wk : Wv;
        qkv_pad[i] = (kk < 64) ? f2bf(W[kk * 64 + c]) : (u16)0;
    }
    // K-permuted post-projection table: xagg K index K' = d*4 + h (d = input dim,
    // h = head), matching k_agg's packed uint2 epilogue. B~[g][K'] = Wsrc[d][h*64+g].
    for (int i = bid * 256 + tid; i < 2 * 4 * 4608; i += gridDim.x * 256) {
        int r = i / 18432, q = i % 18432, kc = q / 4608, qq = q % 4608;
        int c = qq / 72, kk = qq % 72;
        int d = kc * 16 + (kk >> 2), h = kk & 3;
        postB_pad[i] = (kk < 64) ? f2bf(Wsrc[(size_t)r * 16384 + d * 256 + h * 64 + c]) : (u16)0;
    }
}

// ---------------- CSR build ----------------
__global__ __launch_bounds__(256) void k_hist(const int* __restrict__ ei,
                                              u16* __restrict__ rank, u16* __restrict__ partial)
{
    __shared__ unsigned int hist[N_ / 2];
    int b = blockIdx.x, p = blockIdx.y, tid = threadIdx.x;
    for (int i = tid; i < N_ / 2; i += 256) hist[i] = 0u;
    __syncthreads();
    const int* dsts = ei + ((size_t)p * 2 + 1) * E_ + b * EPB_;
    u16* rk = rank + (size_t)p * E_ + b * EPB_;
    for (int e = tid; e < EPB_; e += 256) {
        int dst = dsts[e];
        unsigned sh = (unsigned)(dst & 1) * 16u;
        unsigned old = atomicAdd(&hist[dst >> 1], 1u << sh);
        rk[e] = (u16)((old >> sh) & 0xffffu);
    }
    __syncthreads();
    u16* part = partial + ((size_t)p * NB_ + b) * N_;
    for (int n = tid; n < N_; n += 256) {
        unsigned hv = hist[n >> 1];
        part[n] = (u16)((hv >> ((unsigned)(n & 1) * 16u)) & 0xffffu);
    }
}

__global__ __launch_bounds__(256) void k_scan1(u16* __restrict__ partial,
                                               int* __restrict__ offsets, int* __restrict__ chunktot)
{
    int p = blockIdx.y, ch = blockIdx.x;
    int tid = threadIdx.x, lane = tid & 63, wid = tid >> 6;
    __shared__ int wtot[4];
    u16* part = partial + (size_t)p * NB_ * N_;
    int* ofs = offsets + (size_t)p * (N_ + 1);
    int n0 = ch * CHN_;
    int carry = 0;
    for (int rnd = 0; rnd < 3; ++rnd) {
        int i = rnd * 256 + tid;
        int n = n0 + i;
        int v = 0;
        if (i < CHN_) {
            int run = 0;
            #pragma unroll 8
            for (int b = 0; b < NB_; ++b) {
                int pv = part[b * N_ + n];
                part[b * N_ + n] = (u16)run;
                run += pv;
            }
            v = run;
        }
        int incl = v;
        for (int d = 1; d < 64; d <<= 1) { int u = __shfl_up(incl, d); if (lane >= d) incl += u; }
        if (lane == 63) wtot[wid] = incl;
        __syncthreads();
        if (tid < 4) {
            int iv = wtot[tid];
            for (int d = 1; d < 4; d <<= 1) { int u = __shfl_up(iv, d); if (tid >= d) iv += u; }
            wtot[tid] = iv;
        }
        __syncthreads();
        int woff = (wid > 0) ? wtot[wid - 1] : 0;
        int tot = wtot[3];
        int excl = carry + woff + incl - v;
        if (i < CHN_) ofs[n] = excl;
        carry += tot;
        __syncthreads();
    }
    if (tid == 0) chunktot[p * NB_ + ch] = carry;
}

// scan3 also does scan2's 32-element prefix locally
__global__ void k_scan3(int* __restrict__ offsets, const int* __restrict__ chunktot) {
    __shared__ int cb[NB_];
    int p = blockIdx.y;
    int tid = threadIdx.x;
    if (tid < 64) {
        int v = (tid < NB_) ? chunktot[p * NB_ + tid] : 0;
        #pragma unroll
        for (int d = 1; d < NB_; d <<= 1) { int u = __shfl_up(v, d); if (tid >= d) v += u; }
        if (tid < NB_) cb[tid] = v;   // inclusive prefix
    }
    __syncthreads();
    int n = blockIdx.x * 256 + tid;
    if (n < N_) {
        int c = n / CHN_;
        int base = (c > 0) ? cb[c - 1] : 0;
        offsets[(size_t)p * (N_ + 1) + n] += base;
    }
    if (n == 0)
        offsets[(size_t)p * (N_ + 1) + N_] = E_;
}

// 1-D grid, p = bid & 7: round-robin dispatch pins each p to one XCD, so the
// random 2B csr writes (640 KB/p) stay in that XCD's L2 (kills the 8x write amp).
__global__ void k_scatter(const int* __restrict__ ei, const int* __restrict__ offsets,
                          const u16* __restrict__ rank, const u16* __restrict__ partial,
                          u16* __restrict__ csr) {
    int bid = blockIdx.x;
    int p = bid & 7;
    int e = (bid >> 3) * 256 + threadIdx.x;
    int src = ei[((size_t)p * 2 + 0) * E_ + e];
    int dst = ei[((size_t)p * 2 + 1) * E_ + e];
    int b = e / EPB_;
    int pos = offsets[p * (N_ + 1) + dst]
            + (int)partial[((size_t)p * NB_ + b) * N_ + dst]
            + (int)rank[(size_t)p * E_ + e];
    csr[(size_t)p * E_ + pos] = (u16)src;
}

// ---------------- GAT aggregation: 4 nodes/wave, batched gather, dot2 pairs ----------------
// Latency-oriented x-phase: per node q, issue ALL 16 gather loads into registers
// back-to-back (one latency exposure per q instead of per pair), then consume with
// pack + uniform ds_read_b128 + 4 dot2 per pair. Scalar fine-skip (pr*2 < rem)
// kills the padded-slot work. Epilogue: K-packed layout (K' = d*4 + h) -> one
// coalesced uint2 store per node per lane; rcp hoisted before lane-broadcast.
__global__ __launch_bounds__(256) void k_agg(
    const int* __restrict__ offsets, const u16* __restrict__ csr,
    const float* __restrict__ als_all, const float* __restrict__ ald_all,
    const u16* __restrict__ x_h, u16* __restrict__ xagg4)
{
    // ptab[wv][g][pair*8 + h*2 + (el&1)]  (per-g 128B regions, 16B aligned)
    __shared__ __align__(16) u16 ptab[4][4][64];
    const int bid = blockIdx.x;
    const int p = bid & 7;
    const int t = p >> 1;
    const int* off   = offsets + (size_t)p * (N_ + 1);
    const u16* srcs  = csr + (size_t)p * E_;
    const float* als = als_all + (size_t)p * N_ * 4;
    const float* ald = ald_all + (size_t)p * N_ * 4;
    const u16* xb    = x_h + (size_t)t * N_ * 64;

    const int tid = threadIdx.x, lane = tid & 63, wv = tid >> 6;
    const int g = lane >> 4, el = lane & 15;
    const int n0 = (bid >> 3) * 16 + wv * 4;   // 4 nodes per wave
    const int ng = n0 + g;
    const int o0 = off[ng], o1 = off[ng + 1];
    const int deg = o1 - o0;
    const float4 aldv = *(const float4*)(ald + (size_t)ng * 4);
    u16* pt = &ptab[wv][0][0];
    const int pw = g * 64 + (el >> 1) * 8 + (el & 1);

    int sdeg[4];
    #pragma unroll
    for (int q = 0; q < 4; ++q) sdeg[q] = __builtin_amdgcn_readlane(deg, q * 16);
    int mdeg = max(max(sdeg[0], sdeg[1]), max(sdeg[2], sdeg[3]));
    int nrounds = (mdeg + 15) >> 4;

    float acc[4][4];
    #pragma unroll
    for (int q = 0; q < 4; ++q)
        #pragma unroll
        for (int h = 0; h < 4; ++h) acc[q][h] = 0.f;
    float d0 = 0.f, d1 = 0.f, d2 = 0.f, d3 = 0.f;

    for (int rr = 0; rr < nrounds; ++rr) {
        int e = rr * 16 + el;
        int sv = 0;
        float p0 = 0.f, p1 = 0.f, p2 = 0.f, p3 = 0.f;
        if (e < deg) {
            sv = (int)srcs[o0 + e];
            float4 av = *(const float4*)(als + (size_t)sv * 4);
            float e0 = av.x + aldv.x, e1 = av.y + aldv.y;
            float e2 = av.z + aldv.z, e3 = av.w + aldv.w;
            e0 = fmaxf(e0, 0.2f * e0); e1 = fmaxf(e1, 0.2f * e1);
            e2 = fmaxf(e2, 0.2f * e2); e3 = fmaxf(e3, 0.2f * e3);
            p0 = __expf(e0); p1 = __expf(e1); p2 = __expf(e2); p3 = __expf(e3);
        }
        d0 += p0; d1 += p1; d2 += p2; d3 += p3;
        pt[pw + 0] = f2h(p0); pt[pw + 2] = f2h(p1);
        pt[pw + 4] = f2h(p2); pt[pw + 6] = f2h(p3);
        // x-phase: in-order DS within the wave -> ptab written above is visible
        #pragma unroll
        for (int q = 0; q < 4; ++q) {
            int rem = sdeg[q] - rr * 16;   // scalar -> uniform branches
            if (rem > 0) {
                const u16* ptq = pt + q * 64;
                unsigned xl0[8], xl1[8];
                #pragma unroll
                for (int pr = 0; pr < 8; ++pr) {
                    if (pr * 2 < rem) {
                        int s0i = __builtin_amdgcn_readlane(sv, q * 16 + pr * 2);
                        int s1i = __builtin_amdgcn_readlane(sv, q * 16 + pr * 2 + 1);
                        xl0[pr] = xb[((size_t)(unsigned)s0i << 6) + lane];
                        xl1[pr] = xb[((size_t)(unsigned)s1i << 6) + lane];
                    }
                }
                #pragma unroll
                for (int pr = 0; pr < 8; ++pr) {
                    if (pr * 2 < rem) {
                        unsigned xp = xl0[pr] | (xl1[pr] << 16);
                        uint4 ppv = *(const uint4*)(ptq + pr * 8);
                        h2 xv, q0, q1, q2, q3;
                        __builtin_memcpy(&xv, &xp, 4);
                        __builtin_memcpy(&q0, &ppv.x, 4);
                        __builtin_memcpy(&q1, &ppv.y, 4);
                        __builtin_memcpy(&q2, &ppv.z, 4);
                        __builtin_memcpy(&q3, &ppv.w, 4);
                        acc[q][0] = fdot2(xv, q0, acc[q][0]);
                        acc[q][1] = fdot2(xv, q1, acc[q][1]);
                        acc[q][2] = fdot2(xv, q2, acc[q][2]);
                        acc[q][3] = fdot2(xv, q3, acc[q][3]);
                    }
                }
            }
        }
    }
    // den reduce within each 16-lane group (xor masks < 16 stay in-group)
    d0 += __shfl_xor(d0, 1); d0 += __shfl_xor(d0, 2);
    d0 += __shfl_xor(d0, 4); d0 += __shfl_xor(d0, 8);
    d1 += __shfl_xor(d1, 1); d1 += __shfl_xor(d1, 2);
    d1 += __shfl_xor(d1, 4); d1 += __shfl_xor(d1, 8);
    d2 += __shfl_xor(d2, 1); d2 += __shfl_xor(d2, 2);
    d2 += __shfl_xor(d2, 4); d2 += __shfl_xor(d2, 8);
    d3 += __shfl_xor(d3, 1); d3 += __shfl_xor(d3, 2);
    d3 += __shfl_xor(d3, 4); d3 += __shfl_xor(d3, 8);
    float inv0 = 0.25f / (d0 + 1e-16f);
    float inv1 = 0.25f / (d1 + 1e-16f);
    float inv2 = 0.25f / (d2 + 1e-16f);
    float inv3 = 0.25f / (d3 + 1e-16f);
    #pragma unroll
    for (int q = 0; q < 4; ++q) {
        float s0 = rdlanef(inv0, q * 16);
        float s1 = rdlanef(inv1, q * 16);
        float s2 = rdlanef(inv2, q * 16);
        float s3 = rdlanef(inv3, q * 16);
        // K' = d*4 + h packing: lane (=d) writes [h0,h1,h2,h3] as one uint2
        unsigned w01 = cvtpk_bf16(acc[q][0] * s0, acc[q][1] * s1);
        unsigned w23 = cvtpk_bf16(acc[q][2] * s2, acc[q][3] * s3);
        *(uint2*)(xagg4 + ((size_t)p * N_ + n0 + q) * 256 + lane * 4) = make_uint2(w01, w23);
    }
}

// ---------------- post-projection: intra = xagg @ B~ (all t in one dispatch) ----------------
__global__ __launch_bounds__(256) void k_post(
    const u16* __restrict__ xagg4, const u16* __restrict__ postB_pad,
    u16* __restrict__ intra)
{
    const int t = blockIdx.z, r = blockIdx.y;
    const u16* A = xagg4 + ((size_t)(t * 2 + r)) * N_ * 256;
    const u16* Bp = postB_pad + (size_t)r * 4 * 4608;
    const int tid = threadIdx.x, lane = tid & 63, wv = tid >> 6;
    const int col = lane & 15, quad = lane >> 4;
    int m0 = blockIdx.x * 64;
    int row = m0 + wv * 16 + col;
    int row_c = (row < N_) ? row : (N_ - 1);

    f32x4 acc[4];
    #pragma unroll
    for (int cf = 0; cf < 4; ++cf) { acc[cf][0]=0.f; acc[cf][1]=0.f; acc[cf][2]=0.f; acc[cf][3]=0.f; }
    #pragma unroll
    for (int kc = 0; kc < 4; ++kc) {
        #pragma unroll
        for (int ks = 0; ks < 2; ++ks) {
            bf16x8 a = *(const bf16x8*)(A + (size_t)row_c * 256 + kc * 64 + ks * 32 + quad * 8);
            const u16* bb = Bp + kc * 4608 + ks * 32 + quad * 8;
            #pragma unroll
            for (int cf = 0; cf < 4; ++cf) {
                bf16x8 b = *(const bf16x8*)(bb + (cf * 16 + col) * 72);
                acc[cf] = __builtin_amdgcn_mfma_f32_16x16x32_bf16(a, b, acc[cf], 0, 0, 0);
            }
        }
    }
    int rowbase = m0 + wv * 16 + quad * 4;
    #pragma unroll
    for (int cf = 0; cf < 4; ++cf) {
        int c = cf * 16 + col;
        #pragma unroll
        for (int reg = 0; reg < 4; ++reg) {
            int rr = rowbase + reg;
            if (rr < N_)
                intra[(((size_t)t * N_ + rr) * 2 + r) * 64 + c] = f2bf(acc[cf][reg]);
        }
    }
}

// ---------------- RelationAgg GEMM with fused ftanh(.)@W2 epilogue + fused beta sums ----------------
__global__ __launch_bounds__(256) void k_relagg(
    const u16* __restrict__ A, const u16* __restrict__ W1pad, const float* __restrict__ b1,
    const float* __restrict__ W2, float* __restrict__ ssum)
{
    int m0 = blockIdx.x * 64;
    f32x4 acc[16];
    gemm_direct(A, W1pad, T_ * N_ * R_, 64, 1, m0, acc);

    const int tid = threadIdx.x, lane = tid & 63, wv = tid >> 6;
    const int col = lane & 15;
    float sp[4] = {0.f, 0.f, 0.f, 0.f};
    #pragma unroll
    for (int cf = 0; cf < 16; ++cf) {
        int gcol = cf * 16 + col;
        float bb = b1[gcol];
        float ww = W2[gcol];
        #pragma unroll
        for (int reg = 0; reg < 4; ++reg)
            sp[reg] += ftanh(acc[cf][reg] + bb) * ww;
    }
    #pragma unroll
    for (int reg = 0; reg < 4; ++reg) {
        float v = sp[reg];
        v += __shfl_xor(v, 1); v += __shfl_xor(v, 2);
        v += __shfl_xor(v, 4); v += __shfl_xor(v, 8);
        sp[reg] = v;
    }
    // rows = m0 + wv*16 + quad*4 + reg ; rowbase is even so reg parity == r
    float se = sp[0] + sp[2];   // r = 0 rows of this lane's quad
    float so = sp[1] + sp[3];   // r = 1 rows
    se += __shfl_xor(se, 16); se += __shfl_xor(se, 32);
    so += __shfl_xor(so, 16); so += __shfl_xor(so, 32);
    __shared__ float red[8];
    if (lane == 0) { red[wv * 2] = se; red[wv * 2 + 1] = so; }
    __syncthreads();
    if (tid == 0) {
        float s0 = red[0] + red[2] + red[4] + red[6];
        float s1 = red[1] + red[3] + red[5] + red[7];
        int t = m0 / (N_ * R_);
        atomicAdd(&ssum[t * 2 + 0], s0);
        atomicAdd(&ssum[t * 2 + 1], s1);
    }
}

// ---------------- LSTM: all 4 timesteps in one kernel; c in regs, h in LDS ----------------
__global__ __launch_bounds__(256) void k_lstm(
    const u16* __restrict__ intra, const float* __restrict__ ssum,
    const u16* __restrict__ Wc_pad, const float* __restrict__ biasv,
    u16* __restrict__ feats)
{
    __shared__ __align__(16) u16 hl[64][72];   // h state, bf16, wave-private 16-row stripes
    const int tid = threadIdx.x, lane = tid & 63, wv = tid >> 6;
    const int col = lane & 15, quad = lane >> 4;
    int m0 = blockIdx.x * 64;
    int row = m0 + wv * 16 + col;
    int row_c = (row < N_) ? row : (N_ - 1);
    int rowbase = m0 + wv * 16 + quad * 4;

    float betas[8];
    #pragma unroll
    for (int t = 0; t < 4; ++t) {
        float s0 = ssum[t * 2] * (1.f / N_), s1 = ssum[t * 2 + 1] * (1.f / N_);
        float mx = fmaxf(s0, s1);
        float e0 = __expf(s0 - mx), e1 = __expf(s1 - mx);
        float inv = 1.f / (e0 + e1);
        betas[t * 2] = e0 * inv; betas[t * 2 + 1] = e1 * inv;
    }

    float cc[4][4];
    #pragma unroll
    for (int j = 0; j < 4; ++j)
        #pragma unroll
        for (int reg = 0; reg < 4; ++reg) cc[j][reg] = 0.f;

    for (int t = 0; t < 4; ++t) {
        float b0 = betas[t * 2], b1 = betas[t * 2 + 1];
        const u16* ib = intra + ((size_t)t * N_ + row_c) * 128;

        f32x4 acc[16];
        #pragma unroll
        for (int cf = 0; cf < 16; ++cf) { acc[cf][0]=0.f; acc[cf][1]=0.f; acc[cf][2]=0.f; acc[cf][3]=0.f; }

        #pragma unroll
        for (int ks = 0; ks < 2; ++ks) {
            int coff = ks * 32 + quad * 8;
            bf16x8 i0 = *(const bf16x8*)(ib + coff);
            bf16x8 i1 = *(const bf16x8*)(ib + 64 + coff);
            union { u16 h[8]; bf16x8 v; } cv;
            #pragma unroll
            for (int j = 0; j < 8; ++j)
                cv.h[j] = f2bf(b0 * bf2f((u16)i0[j]) + b1 * bf2f((u16)i1[j]));
            const u16* bb = Wc_pad + ks * 32 + quad * 8;
            #pragma unroll
            for (int cf = 0; cf < 16; ++cf) {
                bf16x8 b = *(const bf16x8*)(bb + (cf * 16 + col) * 72);
                acc[cf] = __builtin_amdgcn_mfma_f32_16x16x32_bf16(cv.v, b, acc[cf], 0, 0, 0);
            }
        }
        if (t > 0) {
            #pragma unroll
            for (int ks = 0; ks < 2; ++ks) {
                bf16x8 a = *(const bf16x8*)&hl[wv * 16 + col][ks * 32 + quad * 8];
                const u16* bb = Wc_pad + BPAD + ks * 32 + quad * 8;
                #pragma unroll
                for (int cf = 0; cf < 16; ++cf) {
                    bf16x8 b = *(const bf16x8*)(bb + (cf * 16 + col) * 72);
                    acc[cf] = __builtin_amdgcn_mfma_f32_16x16x32_bf16(a, b, acc[cf], 0, 0, 0);
                }
            }
        }

        #pragma unroll
        for (int j = 0; j < 4; ++j) {
            int c = j * 16 + col;
            float bi = biasv[c], bf_ = biasv[64 + c], bg = biasv[128 + c], bo = biasv[192 + c];
            #pragma unroll
            for (int reg = 0; reg < 4; ++reg) {
                float gi = acc[j][reg] + bi;
                float gf = acc[j + 4][reg] + bf_;
                float gg = acc[j + 8][reg] + bg;
                float go = acc[j + 12][reg] + bo;
                float c2 = sigm(gf) * cc[j][reg] + sigm(gi) * ftanh(gg);
                float hh = sigm(go) * ftanh(c2);
                cc[j][reg] = c2;
                u16 hb = f2bf(hh);
                hl[wv * 16 + quad * 4 + reg][c] = hb;
                int rr = rowbase + reg;
                if (rr < N_)
                    feats[(size_t)rr * 256 + t * 64 + c] = hb;
            }
        }
    }
}

// ---------------- temporal causal MHA: MFMA QKV + per-lane attention ----------------
__global__ __launch_bounds__(256) void k_attn(
    const u16* __restrict__ feats, const float* __restrict__ pos_emb,
    const u16* __restrict__ qkv_pad, float* __restrict__ out)
{
    __shared__ float qkv_s[64 * 200];
    const int tid = threadIdx.x, lane = tid & 63, wv = tid >> 6;
    const int col = lane & 15, quad = lane >> 4;
    int m0 = blockIdx.x * 64;
    int row = m0 + wv * 16 + col;
    int trow = row & 3;

    f32x4 acc[12];
    #pragma unroll
    for (int cf = 0; cf < 12; ++cf) { acc[cf][0]=0.f; acc[cf][1]=0.f; acc[cf][2]=0.f; acc[cf][3]=0.f; }
    #pragma unroll
    for (int ks = 0; ks < 2; ++ks) {
        int coff = ks * 32 + quad * 8;
        bf16x8 fv = *(const bf16x8*)(feats + (size_t)row * 64 + coff);
        float4 p0 = *(const float4*)(pos_emb + trow * 64 + coff);
        float4 p1 = *(const float4*)(pos_emb + trow * 64 + coff + 4);
        union { u16 h[8]; bf16x8 v; } cv;
        cv.h[0] = f2bf(bf2f((u16)fv[0]) + p0.x); cv.h[1] = f2bf(bf2f((u16)fv[1]) + p0.y);
        cv.h[2] = f2bf(bf2f((u16)fv[2]) + p0.z); cv.h[3] = f2bf(bf2f((u16)fv[3]) + p0.w);
        cv.h[4] = f2bf(bf2f((u16)fv[4]) + p1.x); cv.h[5] = f2bf(bf2f((u16)fv[5]) + p1.y);
        cv.h[6] = f2bf(bf2f((u16)fv[6]) + p1.z); cv.h[7] = f2bf(bf2f((u16)fv[7]) + p1.w);
        bf16x8 a = cv.v;
        const u16* bb = qkv_pad + ks * 32 + quad * 8;
        #pragma unroll
        for (int cf = 0; cf < 12; ++cf) {
            bf16x8 b = *(const bf16x8*)(bb + (cf * 16 + col) * 72);
            acc[cf] = __builtin_amdgcn_mfma_f32_16x16x32_bf16(a, b, acc[cf], 0, 0, 0);
        }
    }
    #pragma unroll
    for (int cf = 0; cf < 12; ++cf) {
        int g = cf * 16 + col;
        #pragma unroll
        for (int reg = 0; reg < 4; ++reg) {
            int rl = wv * 16 + quad * 4 + reg;
            qkv_s[rl * 200 + g] = acc[cf][reg];
        }
    }
    __syncthreads();

    int nl = wv * 4 + (lane >> 4);
    int sub = lane & 15;
    int h = sub >> 2, tq = sub & 3;
    const float* qrow = qkv_s + (nl * 4 + tq) * 200 + h * 16;

    float s[4];
    #pragma unroll
    for (int tk = 0; tk < 4; ++tk) {
        const float* krow = qkv_s + (nl * 4 + tk) * 200 + 64 + h * 16;
        float d = 0.f;
        #pragma unroll
        for (int j = 0; j < 16; ++j) d += qrow[j] * krow[j];
        s[tk] = (tk > tq) ? -4294967295.0f : d * 0.5f;
    }
    float mx = fmaxf(fmaxf(s[0], s[1]), fmaxf(s[2], s[3]));
    float a0 = __expf(s[0]-mx), a1 = __expf(s[1]-mx), a2 = __expf(s[2]-mx), a3 = __expf(s[3]-mx);
    float inv = 1.f / (a0 + a1 + a2 + a3);
    a0 *= inv; a1 *= inv; a2 *= inv; a3 *= inv;

    int n = blockIdx.x * 16 + nl;
    const float* v0 = qkv_s + (nl * 4 + 0) * 200 + 128 + h * 16;
    const float* v1 = v0 + 200, *v2 = v0 + 400, *v3 = v0 + 600;
    #pragma unroll
    for (int cc4 = 0; cc4 < 4; ++cc4) {
        float4 o;
        o.x = a0*v0[cc4*4+0] + a1*v1[cc4*4+0] + a2*v2[cc4*4+0] + a3*v3[cc4*4+0];
        o.y = a0*v0[cc4*4+1] + a1*v1[cc4*4+1] + a2*v2[cc4*4+1] + a3*v3[cc4*4+1];
        o.z = a0*v0[cc4*4+2] + a1*v1[cc4*4+2] + a2*v2[cc4*4+2] + a3*v3[cc4*4+2];
        o.w = a0*v0[cc4*4+3] + a1*v1[cc4*4+3] + a2*v2[cc4*4+3] + a3*v3[cc4*4+3];
        *(float4*)(out + (size_t)n * 256 + tq * 64 + h * 16 + cc4 * 4) = o;
    }
}

// ---------------- launcher ----------------
extern "C" void kernel_launch(void* const* d_in, const int* in_sizes, int n_in,
                              void* d_out, int out_size, void* d_ws, size_t ws_size,
                              hipStream_t stream) {
    const float* x     = (const float*)d_in[0];
    const int* ei      = (const int*)d_in[1];
    const float* Wsrc  = (const float*)d_in[2];
    const float* Wdst  = (const float*)d_in[3];
    const float* att_src = (const float*)d_in[4];
    const float* att_dst = (const float*)d_in[5];
    const float* raW1  = (const float*)d_in[6];
    const float* rab1  = (const float*)d_in[7];
    const float* raW2  = (const float*)d_in[8];
    const float* Wih   = (const float*)d_in[9];
    const float* Whh   = (const float*)d_in[10];
    const float* bih   = (const float*)d_in[11];
    const float* bhh   = (const float*)d_in[12];
    const float* pos   = (const float*)d_in[13];
    const float* Wq    = (const float*)d_in[14];
    const float* Wk    = (const float*)d_in[15];
    const float* Wv    = (const float*)d_in[16];
    float* out = (float*)d_out;

    char* w = (char*)d_ws;
    size_t off = 0;
    auto alloc = [&](size_t bytes) -> char* {
        char* pp = w + off; off += (bytes + 255) & ~(size_t)255; return pp;
    };
    // ---- long-lived ----
    u16*   intra     = (u16*)  alloc((size_t)T_ * N_ * R_ * 64 * 2);  // 20.48 MB
    u16*   x_h       = (u16*)  alloc((size_t)T_ * N_ * 64 * 2);       // 10.24 MB (f16)
    float* ssum      = (float*)alloc(256);
    float* wdall     = (float*)alloc(1024 * 4);
    float* biasv     = (float*)alloc(256 * 4);
    u16*   raW1_pad  = (u16*)  alloc(BPAD * 2);
    u16*   Wc_pad    = (u16*)  alloc(2 * BPAD * 2);
    u16*   qkv_pad   = (u16*)  alloc(192 * 72 * 2);
    u16*   postB_pad = (u16*)  alloc(2 * 4 * 4608 * 2);
    int*   chunktot  = (int*)  alloc(P_ * NB_ * 4);
    // ---- union region ----
    char*  ubase   = alloc(0);
    size_t uoff = 0;
    auto ualloc = [&](size_t bytes) -> char* {
        char* pp = ubase + uoff; uoff += (bytes + 255) & ~(size_t)255; return pp;
    };
    int*   offsets = (int*)  ualloc((size_t)P_ * (N_ + 1) * 4);
    u16*   csr     = (u16*)  ualloc((size_t)P_ * E_ * 2);
    float* als_all = (float*)ualloc((size_t)P_ * N_ * 4 * 4);
    float* ald_all = (float*)ualloc((size_t)P_ * N_ * 4 * 4);
    u16*   partial = (u16*)  ualloc((size_t)P_ * NB_ * N_ * 2);
    u16*   xagg4   = (u16*)  ualloc((size_t)P_ * N_ * 256 * 2);   // 81.92 MB (all t,r)
    u16*   rank    = (u16*)  xagg4;   // overlay: rank dead before k_agg
    // phase 2 overlay (phase-1 sub-buffers dead after k_post)
    u16*   feats   = (u16*)  ubase;   // 10.24 MB
    (void)ws_size; (void)in_sizes; (void)n_in; (void)out_size;

    k_prep<<<72, 256, 0, stream>>>(Wdst, att_dst, Wih, Whh, bih, bhh, Wsrc, att_src, raW1,
                                   Wq, Wk, Wv, wdall, biasv, raW1_pad, Wc_pad, qkv_pad,
                                   postB_pad, ssum);
    k_hist<<<dim3(NB_, 8), 256, 0, stream>>>(ei, rank, partial);
    k_scan1<<<dim3(NB_, 8), 256, 0, stream>>>(partial, offsets, chunktot);
    k_scan3<<<dim3(79, 8), 256, 0, stream>>>(offsets, chunktot);
    k_scatter<<<10000, 256, 0, stream>>>(ei, offsets, rank, partial, csr);
    k_fold<<<dim3(313, 4), 256, 0, stream>>>(x, wdall, als_all, ald_all, x_h);
    k_agg<<<10000, 256, 0, stream>>>(offsets, csr, als_all, ald_all, x_h, xagg4);
    k_post<<<dim3(313, 2, 4), 256, 0, stream>>>(xagg4, postB_pad, intra);
    k_relagg<<<2500, 256, 0, stream>>>(intra, raW1_pad, rab1, raW2, ssum);
    k_lstm<<<313, 256, 0, stream>>>(intra, ssum, Wc_pad, biasv, feats);
    k_attn<<<1250, 256, 0, stream>>>(feats, pos, qkv_pad, out);
}

// Round 8
// 430.921 us; speedup vs baseline: 1.1573x; 1.0164x over previous
//
#include <hip/hip_runtime.h>
#include <hip/hip_bf16.h>

#define T_ 4
#define N_ 20000
#define E_ 320000
#define R_ 2
#define DIN 64
#define G_ 256   // H*Dh
#define P_ 8     // T*R
#define BPAD 16384  // 256 * 64 dense B-table halves per 64-k chunk (global loads: no pad)
#define NB_ 32      // CSR-build blocks per p
#define EPB_ 10000  // edges per CSR-build block
#define CHN_ 625    // nodes per scan chunk (N_/32)

typedef unsigned short u16;
typedef __attribute__((ext_vector_type(8))) short bf16x8;
typedef __attribute__((ext_vector_type(2))) _Float16 h2;
typedef __attribute__((ext_vector_type(4))) float f32x4;

__device__ __forceinline__ float bf2f(u16 u) {
    unsigned int i = ((unsigned int)u) << 16; float f;
    __builtin_memcpy(&f, &i, 4); return f;
}
__device__ __forceinline__ u16 f2bf(float f) {
    unsigned int i; __builtin_memcpy(&i, &f, 4);
    unsigned int r = i + 0x7fffu + ((i >> 16) & 1u);
    return (u16)(r >> 16);
}
__device__ __forceinline__ u16 f2h(float f) {
    union { _Float16 h; u16 u; } c; c.h = (_Float16)f; return c.u;
}
__device__ __forceinline__ float sigm(float x) { return 1.f / (1.f + __expf(-x)); }
// fast tanh: 1 - 2/(exp(2x)+1); hardware v_exp_f32, correct saturation at +-inf
__device__ __forceinline__ float ftanh(float x) { return 1.f - 2.f / (__expf(2.f * x) + 1.f); }
// broadcast lane l's float to all lanes (SGPR result); l must be wave-uniform
__device__ __forceinline__ float rdlanef(float v, int l) {
    int i; __builtin_memcpy(&i, &v, 4);
    int r = __builtin_amdgcn_readlane(i, l);
    float f; __builtin_memcpy(&f, &r, 4); return f;
}
// v_dot2_f32_f16: a.x*b.x + a.y*b.y + c in one VALU op
__device__ __forceinline__ float fdot2(h2 a, h2 b, float c) {
#if __has_builtin(__builtin_amdgcn_fdot2)
    return __builtin_amdgcn_fdot2(a, b, c, false);
#else
    float r;
    asm("v_dot2_f32_f16 %0, %1, %2, %3" : "=v"(r) : "v"(a), "v"(b), "v"(c));
    return r;
#endif
}
// pack 2 f32 -> 2 bf16 (RNE) in one VALU op
__device__ __forceinline__ unsigned cvtpk_bf16(float lo, float hi) {
    unsigned r;
    asm("v_cvt_pk_bf16_f32 %0, %1, %2" : "=v"(r) : "v"(lo), "v"(hi));
    return r;
}

// ---------------- LDS-free MFMA GEMM core (bf16 A, dense B stride 64) ----------------
__device__ __forceinline__ void gemm_direct(
    const u16* __restrict__ A, const u16* __restrict__ Bpad,
    int M, int Astride, int kchunks, int m0, f32x4* acc)
{
    const int tid = threadIdx.x;
    const int lane = tid & 63, wv = tid >> 6;
    const int col = lane & 15, quad = lane >> 4;
    #pragma unroll
    for (int cf = 0; cf < 16; ++cf) { acc[cf][0]=0.f; acc[cf][1]=0.f; acc[cf][2]=0.f; acc[cf][3]=0.f; }

    int row = m0 + wv * 16 + col;
    int row_c = (row < M) ? row : (M - 1);

    for (int kc = 0; kc < kchunks; ++kc) {
        #pragma unroll
        for (int ks = 0; ks < 2; ++ks) {
            bf16x8 a = *(const bf16x8*)(A + (size_t)row_c * Astride + kc * 64 + ks * 32 + quad * 8);
            const u16* bb = Bpad + kc * BPAD + ks * 32 + quad * 8;
            #pragma unroll
            for (int cf = 0; cf < 16; ++cf) {
                bf16x8 b = *(const bf16x8*)(bb + (cf * 16 + col) * 64);
                acc[cf] = __builtin_amdgcn_mfma_f32_16x16x32_bf16(a, b, acc[cf], 0, 0, 0);
            }
        }
    }
}

// ---------------- fold: als/ald GEMVs + x->f16 cast; wdall staged in LDS ----------------
__global__ __launch_bounds__(256) void k_fold(
    const float* __restrict__ x, const float* __restrict__ wdall,
    float* __restrict__ als_all, float* __restrict__ ald_all, u16* __restrict__ x_h)
{
    __shared__ float wds[1024];
    {
        int tid = threadIdx.x;
        *(float4*)(wds + tid * 4) = *(const float4*)(wdall + tid * 4);
    }
    __syncthreads();

    int t = blockIdx.y;
    int idx = blockIdx.x * 256 + threadIdx.x;
    if (idx >= N_ * 4) return;
    int n = idx >> 2, q = idx & 3;
    const float* xr = x + ((size_t)t * N_ + n) * 64 + q * 16;
    float4 xv[4];
    #pragma unroll
    for (int i = 0; i < 4; ++i) xv[i] = *(const float4*)(xr + i * 4);

    {
        union { u16 h[16]; ushort4 s4[4]; } cv;
        #pragma unroll
        for (int i = 0; i < 4; ++i) {
            cv.h[i*4+0] = f2h(xv[i].x); cv.h[i*4+1] = f2h(xv[i].y);
            cv.h[i*4+2] = f2h(xv[i].z); cv.h[i*4+3] = f2h(xv[i].w);
        }
        u16* xo = x_h + ((size_t)t * N_ + n) * 64 + q * 16;
        #pragma unroll
        for (int i = 0; i < 4; ++i) *(ushort4*)(xo + i * 4) = cv.s4[i];
    }

    float s[16];
    #pragma unroll
    for (int i = 0; i < 16; ++i) s[i] = 0.f;
    #pragma unroll
    for (int i = 0; i < 4; ++i) {
        float xe[4] = {xv[i].x, xv[i].y, xv[i].z, xv[i].w};
        #pragma unroll
        for (int e = 0; e < 4; ++e) {
            int k = q * 16 + i * 4 + e;
            float xk = xe[e];
            #pragma unroll
            for (int tb = 0; tb < 4; ++tb) {
                float4 w = *(const float4*)(wds + tb * 256 + k * 4);
                s[tb*4+0] += xk * w.x; s[tb*4+1] += xk * w.y;
                s[tb*4+2] += xk * w.z; s[tb*4+3] += xk * w.w;
            }
        }
    }
    #pragma unroll
    for (int i = 0; i < 16; ++i) {
        s[i] += __shfl_xor(s[i], 1);
        s[i] += __shfl_xor(s[i], 2);
    }
    if (q == 0) {
        *(float4*)(als_all + ((size_t)(t*2+0) * N_ + n) * 4) = make_float4(s[0], s[1], s[2], s[3]);
        *(float4*)(als_all + ((size_t)(t*2+1) * N_ + n) * 4) = make_float4(s[4], s[5], s[6], s[7]);
        *(float4*)(ald_all + ((size_t)(t*2+0) * N_ + n) * 4) = make_float4(s[8], s[9], s[10], s[11]);
        *(float4*)(ald_all + ((size_t)(t*2+1) * N_ + n) * 4) = make_float4(s[12], s[13], s[14], s[15]);
    }
}

// ---------------- prep: folded GEMV tables, dense B-tables, folded bias ----------------
__global__ void k_prep(const float* __restrict__ Wdst, const float* __restrict__ att_dst,
                       const float* __restrict__ Wih, const float* __restrict__ Whh,
                       const float* __restrict__ bih, const float* __restrict__ bhh,
                       const float* __restrict__ Wsrc, const float* __restrict__ att_src,
                       const float* __restrict__ raW1,
                       const float* __restrict__ Wq, const float* __restrict__ Wk,
                       const float* __restrict__ Wv,
                       float* __restrict__ wdall, float* __restrict__ biasv,
                       u16* __restrict__ raW1_pad, u16* __restrict__ Wc_pad,
                       u16* __restrict__ qkv_pad, u16* __restrict__ postB_pad,
                       float* __restrict__ sspart)
{
    int tid = threadIdx.x, bid = blockIdx.x;
    if (bid == 0) {
        for (int i = tid; i < 1024; i += 256) sspart[i] = 0.f;
        int k = tid >> 2, h = tid & 3;
        for (int r = 0; r < 2; ++r) {
            float ss = 0.f, sd = 0.f;
            for (int c = 0; c < 64; ++c) {
                ss += Wsrc[((size_t)r * 64 + k) * 256 + h * 64 + c] * att_src[r * 256 + h * 64 + c];
                sd += Wdst[((size_t)r * 64 + k) * 256 + h * 64 + c] * att_dst[r * 256 + h * 64 + c];
            }
            wdall[r * 256 + k * 4 + h] = ss;
            wdall[512 + r * 256 + k * 4 + h] = sd;
        }
        biasv[tid] = bih[tid] + bhh[tid];
    }
    for (int i = bid * 256 + tid; i < BPAD; i += gridDim.x * 256) {
        int n = i >> 6, kk = i & 63;
        raW1_pad[i] = f2bf(raW1[kk * 256 + n]);
    }
    for (int i = bid * 256 + tid; i < 2 * BPAD; i += gridDim.x * 256) {
        int kc = i >> 14, q = i & (BPAD - 1), n = q >> 6, kk = q & 63;
        const float* W = kc ? Whh : Wih;
        Wc_pad[i] = f2bf(W[n * 64 + kk]);
    }
    for (int i = bid * 256 + tid; i < 192 * 64; i += gridDim.x * 256) {
        int g = i >> 6, kk = i & 63;
        int j = g >> 6, c = g & 63;
        const float* W = (j == 0) ? Wq : (j == 1) ? Wk : Wv;
        qkv_pad[i] = f2bf(W[kk * 64 + c]);
    }
    // K-permuted post-projection table: xagg K index K' = d*4 + h (d = input dim,
    // h = head), matching k_agg's packed uint2 epilogue. B~[g][K'] = Wsrc[d][h*64+g].
    for (int i = bid * 256 + tid; i < 2 * 4 * 4096; i += gridDim.x * 256) {
        int r = i >> 14, q = i & 16383, kc = q >> 12, qq = q & 4095;
        int c = qq >> 6, kk = qq & 63;
        int d = kc * 16 + (kk >> 2), h = kk & 3;
        postB_pad[i] = f2bf(Wsrc[(size_t)r * 16384 + d * 256 + h * 64 + c]);
    }
}

// ---------------- CSR build ----------------
__global__ __launch_bounds__(256) void k_hist(const int* __restrict__ ei,
                                              u16* __restrict__ rank, u16* __restrict__ partial)
{
    __shared__ unsigned int hist[N_ / 2];
    int b = blockIdx.x, p = blockIdx.y, tid = threadIdx.x;
    for (int i = tid; i < N_ / 2; i += 256) hist[i] = 0u;
    __syncthreads();
    const int* dsts = ei + ((size_t)p * 2 + 1) * E_ + b * EPB_;
    u16* rk = rank + (size_t)p * E_ + b * EPB_;
    for (int e = tid; e < EPB_; e += 256) {
        int dst = dsts[e];
        unsigned sh = (unsigned)(dst & 1) * 16u;
        unsigned old = atomicAdd(&hist[dst >> 1], 1u << sh);
        rk[e] = (u16)((old >> sh) & 0xffffu);
    }
    __syncthreads();
    u16* part = partial + ((size_t)p * NB_ + b) * N_;
    for (int n = tid; n < N_; n += 256) {
        unsigned hv = hist[n >> 1];
        part[n] = (u16)((hv >> ((unsigned)(n & 1) * 16u)) & 0xffffu);
    }
}

__global__ __launch_bounds__(256) void k_scan1(u16* __restrict__ partial,
                                               int* __restrict__ offsets, int* __restrict__ chunktot)
{
    int p = blockIdx.y, ch = blockIdx.x;
    int tid = threadIdx.x, lane = tid & 63, wid = tid >> 6;
    __shared__ int wtot[4];
    u16* part = partial + (size_t)p * NB_ * N_;
    int* ofs = offsets + (size_t)p * (N_ + 1);
    int n0 = ch * CHN_;
    int carry = 0;
    for (int rnd = 0; rnd < 3; ++rnd) {
        int i = rnd * 256 + tid;
        int n = n0 + i;
        int v = 0;
        if (i < CHN_) {
            int run = 0;
            #pragma unroll 8
            for (int b = 0; b < NB_; ++b) {
                int pv = part[b * N_ + n];
                part[b * N_ + n] = (u16)run;
                run += pv;
            }
            v = run;
        }
        int incl = v;
        for (int d = 1; d < 64; d <<= 1) { int u = __shfl_up(incl, d); if (lane >= d) incl += u; }
        if (lane == 63) wtot[wid] = incl;
        __syncthreads();
        if (tid < 4) {
            int iv = wtot[tid];
            for (int d = 1; d < 4; d <<= 1) { int u = __shfl_up(iv, d); if (tid >= d) iv += u; }
            wtot[tid] = iv;
        }
        __syncthreads();
        int woff = (wid > 0) ? wtot[wid - 1] : 0;
        int tot = wtot[3];
        int excl = carry + woff + incl - v;
        if (i < CHN_) ofs[n] = excl;
        carry += tot;
        __syncthreads();
    }
    if (tid == 0) chunktot[p * NB_ + ch] = carry;
}

// scan3 also does scan2's 32-element prefix locally
__global__ void k_scan3(int* __restrict__ offsets, const int* __restrict__ chunktot) {
    __shared__ int cb[NB_];
    int p = blockIdx.y;
    int tid = threadIdx.x;
    if (tid < 64) {
        int v = (tid < NB_) ? chunktot[p * NB_ + tid] : 0;
        #pragma unroll
        for (int d = 1; d < NB_; d <<= 1) { int u = __shfl_up(v, d); if (tid >= d) v += u; }
        if (tid < NB_) cb[tid] = v;   // inclusive prefix
    }
    __syncthreads();
    int n = blockIdx.x * 256 + tid;
    if (n < N_) {
        int c = n / CHN_;
        int base = (c > 0) ? cb[c - 1] : 0;
        offsets[(size_t)p * (N_ + 1) + n] += base;
    }
    if (n == 0)
        offsets[(size_t)p * (N_ + 1) + N_] = E_;
}

// 1-D grid, p = bid & 7: round-robin dispatch pins each p to one XCD, so the
// random 2B csr writes (640 KB/p) stay in that XCD's L2 (kills the 8x write amp).
__global__ void k_scatter(const int* __restrict__ ei, const int* __restrict__ offsets,
                          const u16* __restrict__ rank, const u16* __restrict__ partial,
                          u16* __restrict__ csr) {
    int bid = blockIdx.x;
    int p = bid & 7;
    int e = (bid >> 3) * 256 + threadIdx.x;
    int src = ei[((size_t)p * 2 + 0) * E_ + e];
    int dst = ei[((size_t)p * 2 + 1) * E_ + e];
    int b = e / EPB_;
    int pos = offsets[p * (N_ + 1) + dst]
            + (int)partial[((size_t)p * NB_ + b) * N_ + dst]
            + (int)rank[(size_t)p * E_ + e];
    csr[(size_t)p * E_ + pos] = (u16)src;
}

// ---------------- GAT aggregation: 4 nodes/wave, batched gather, dot2 pairs ----------------
__global__ __launch_bounds__(256) void k_agg(
    const int* __restrict__ offsets, const u16* __restrict__ csr,
    const float* __restrict__ als_all, const float* __restrict__ ald_all,
    const u16* __restrict__ x_h, u16* __restrict__ xagg4)
{
    // ptab[wv][g][pair*8 + h*2 + (el&1)]  (per-g 128B regions, 16B aligned)
    __shared__ __align__(16) u16 ptab[4][4][64];
    const int bid = blockIdx.x;
    const int p = bid & 7;
    const int t = p >> 1;
    const int* off   = offsets + (size_t)p * (N_ + 1);
    const u16* srcs  = csr + (size_t)p * E_;
    const float* als = als_all + (size_t)p * N_ * 4;
    const float* ald = ald_all + (size_t)p * N_ * 4;
    const u16* xb    = x_h + (size_t)t * N_ * 64;

    const int tid = threadIdx.x, lane = tid & 63, wv = tid >> 6;
    const int g = lane >> 4, el = lane & 15;
    const int n0 = (bid >> 3) * 16 + wv * 4;   // 4 nodes per wave
    const int ng = n0 + g;
    const int o0 = off[ng], o1 = off[ng + 1];
    const int deg = o1 - o0;
    const float4 aldv = *(const float4*)(ald + (size_t)ng * 4);
    u16* pt = &ptab[wv][0][0];
    const int pw = g * 64 + (el >> 1) * 8 + (el & 1);

    int sdeg[4];
    #pragma unroll
    for (int q = 0; q < 4; ++q) sdeg[q] = __builtin_amdgcn_readlane(deg, q * 16);
    int mdeg = max(max(sdeg[0], sdeg[1]), max(sdeg[2], sdeg[3]));
    int nrounds = (mdeg + 15) >> 4;

    float acc[4][4];
    #pragma unroll
    for (int q = 0; q < 4; ++q)
        #pragma unroll
        for (int h = 0; h < 4; ++h) acc[q][h] = 0.f;
    float d0 = 0.f, d1 = 0.f, d2 = 0.f, d3 = 0.f;

    for (int rr = 0; rr < nrounds; ++rr) {
        int e = rr * 16 + el;
        int sv = 0;
        float p0 = 0.f, p1 = 0.f, p2 = 0.f, p3 = 0.f;
        if (e < deg) {
            sv = (int)srcs[o0 + e];
            float4 av = *(const float4*)(als + (size_t)sv * 4);
            float e0 = av.x + aldv.x, e1 = av.y + aldv.y;
            float e2 = av.z + aldv.z, e3 = av.w + aldv.w;
            e0 = fmaxf(e0, 0.2f * e0); e1 = fmaxf(e1, 0.2f * e1);
            e2 = fmaxf(e2, 0.2f * e2); e3 = fmaxf(e3, 0.2f * e3);
            p0 = __expf(e0); p1 = __expf(e1); p2 = __expf(e2); p3 = __expf(e3);
        }
        d0 += p0; d1 += p1; d2 += p2; d3 += p3;
        pt[pw + 0] = f2h(p0); pt[pw + 2] = f2h(p1);
        pt[pw + 4] = f2h(p2); pt[pw + 6] = f2h(p3);
        // x-phase: in-order DS within the wave -> ptab written above is visible
        #pragma unroll
        for (int q = 0; q < 4; ++q) {
            int rem = sdeg[q] - rr * 16;   // scalar -> uniform branches
            if (rem > 0) {
                const u16* ptq = pt + q * 64;
                unsigned xl0[8], xl1[8];
                #pragma unroll
                for (int pr = 0; pr < 8; ++pr) {
                    if (pr * 2 < rem) {
                        int s0i = __builtin_amdgcn_readlane(sv, q * 16 + pr * 2);
                        int s1i = __builtin_amdgcn_readlane(sv, q * 16 + pr * 2 + 1);
                        xl0[pr] = xb[((size_t)(unsigned)s0i << 6) + lane];
                        xl1[pr] = xb[((size_t)(unsigned)s1i << 6) + lane];
                    }
                }
                #pragma unroll
                for (int pr = 0; pr < 8; ++pr) {
                    if (pr * 2 < rem) {
                        unsigned xp = xl0[pr] | (xl1[pr] << 16);
                        uint4 ppv = *(const uint4*)(ptq + pr * 8);
                        h2 xv, q0, q1, q2, q3;
                        __builtin_memcpy(&xv, &xp, 4);
                        __builtin_memcpy(&q0, &ppv.x, 4);
                        __builtin_memcpy(&q1, &ppv.y, 4);
                        __builtin_memcpy(&q2, &ppv.z, 4);
                        __builtin_memcpy(&q3, &ppv.w, 4);
                        acc[q][0] = fdot2(xv, q0, acc[q][0]);
                        acc[q][1] = fdot2(xv, q1, acc[q][1]);
                        acc[q][2] = fdot2(xv, q2, acc[q][2]);
                        acc[q][3] = fdot2(xv, q3, acc[q][3]);
                    }
                }
            }
        }
    }
    // den reduce within each 16-lane group (xor masks < 16 stay in-group)
    d0 += __shfl_xor(d0, 1); d0 += __shfl_xor(d0, 2);
    d0 += __shfl_xor(d0, 4); d0 += __shfl_xor(d0, 8);
    d1 += __shfl_xor(d1, 1); d1 += __shfl_xor(d1, 2);
    d1 += __shfl_xor(d1, 4); d1 += __shfl_xor(d1, 8);
    d2 += __shfl_xor(d2, 1); d2 += __shfl_xor(d2, 2);
    d2 += __shfl_xor(d2, 4); d2 += __shfl_xor(d2, 8);
    d3 += __shfl_xor(d3, 1); d3 += __shfl_xor(d3, 2);
    d3 += __shfl_xor(d3, 4); d3 += __shfl_xor(d3, 8);
    float inv0 = 0.25f / (d0 + 1e-16f);
    float inv1 = 0.25f / (d1 + 1e-16f);
    float inv2 = 0.25f / (d2 + 1e-16f);
    float inv3 = 0.25f / (d3 + 1e-16f);
    #pragma unroll
    for (int q = 0; q < 4; ++q) {
        float s0 = rdlanef(inv0, q * 16);
        float s1 = rdlanef(inv1, q * 16);
        float s2 = rdlanef(inv2, q * 16);
        float s3 = rdlanef(inv3, q * 16);
        // K' = d*4 + h packing: lane (=d) writes [h0,h1,h2,h3] as one uint2
        unsigned w01 = cvtpk_bf16(acc[q][0] * s0, acc[q][1] * s1);
        unsigned w23 = cvtpk_bf16(acc[q][2] * s2, acc[q][3] * s3);
        *(uint2*)(xagg4 + ((size_t)p * N_ + n0 + q) * 256 + lane * 4) = make_uint2(w01, w23);
    }
}

// ---------------- post-projection: intra = xagg @ B~ (all t in one dispatch) ----------------
__global__ __launch_bounds__(256) void k_post(
    const u16* __restrict__ xagg4, const u16* __restrict__ postB_pad,
    u16* __restrict__ intra)
{
    const int t = blockIdx.z, r = blockIdx.y;
    const u16* A = xagg4 + ((size_t)(t * 2 + r)) * N_ * 256;
    const u16* Bp = postB_pad + (size_t)r * 4 * 4096;
    const int tid = threadIdx.x, lane = tid & 63, wv = tid >> 6;
    const int col = lane & 15, quad = lane >> 4;
    int m0 = blockIdx.x * 64;
    int row = m0 + wv * 16 + col;
    int row_c = (row < N_) ? row : (N_ - 1);

    f32x4 acc[4];
    #pragma unroll
    for (int cf = 0; cf < 4; ++cf) { acc[cf][0]=0.f; acc[cf][1]=0.f; acc[cf][2]=0.f; acc[cf][3]=0.f; }
    #pragma unroll
    for (int kc = 0; kc < 4; ++kc) {
        #pragma unroll
        for (int ks = 0; ks < 2; ++ks) {
            bf16x8 a = *(const bf16x8*)(A + (size_t)row_c * 256 + kc * 64 + ks * 32 + quad * 8);
            const u16* bb = Bp + kc * 4096 + ks * 32 + quad * 8;
            #pragma unroll
            for (int cf = 0; cf < 4; ++cf) {
                bf16x8 b = *(const bf16x8*)(bb + (cf * 16 + col) * 64);
                acc[cf] = __builtin_amdgcn_mfma_f32_16x16x32_bf16(a, b, acc[cf], 0, 0, 0);
            }
        }
    }
    int rowbase = m0 + wv * 16 + quad * 4;
    #pragma unroll
    for (int cf = 0; cf < 4; ++cf) {
        int c = cf * 16 + col;
        #pragma unroll
        for (int reg = 0; reg < 4; ++reg) {
            int rr = rowbase + reg;
            if (rr < N_)
                intra[(((size_t)t * N_ + rr) * 2 + r) * 64 + c] = f2bf(acc[cf][reg]);
        }
    }
}

// ---------------- RelationAgg GEMM + fused ftanh(.)@W2 epilogue; partials spread
// over 64 cache lines (same-line atomic serialization was a hidden 2x regression) --------
__global__ __launch_bounds__(256) void k_relagg(
    const u16* __restrict__ A, const u16* __restrict__ W1pad, const float* __restrict__ b1,
    const float* __restrict__ W2, float* __restrict__ sspart)
{
    int m0 = blockIdx.x * 64;
    f32x4 acc[16];
    gemm_direct(A, W1pad, T_ * N_ * R_, 64, 1, m0, acc);

    const int tid = threadIdx.x, lane = tid & 63, wv = tid >> 6;
    const int col = lane & 15;
    float sp[4] = {0.f, 0.f, 0.f, 0.f};
    #pragma unroll
    for (int cf = 0; cf < 16; ++cf) {
        int gcol = cf * 16 + col;
        float bb = b1[gcol];
        float ww = W2[gcol];
        #pragma unroll
        for (int reg = 0; reg < 4; ++reg)
            sp[reg] += ftanh(acc[cf][reg] + bb) * ww;
    }
    #pragma unroll
    for (int reg = 0; reg < 4; ++reg) {
        float v = sp[reg];
        v += __shfl_xor(v, 1); v += __shfl_xor(v, 2);
        v += __shfl_xor(v, 4); v += __shfl_xor(v, 8);
        sp[reg] = v;
    }
    // rows = m0 + wv*16 + quad*4 + reg ; rowbase is even so reg parity == r
    float se = sp[0] + sp[2];   // r = 0 rows of this lane's quad
    float so = sp[1] + sp[3];   // r = 1 rows
    se += __shfl_xor(se, 16); se += __shfl_xor(se, 32);
    so += __shfl_xor(so, 16); so += __shfl_xor(so, 32);
    __shared__ float red[8];
    if (lane == 0) { red[wv * 2] = se; red[wv * 2 + 1] = so; }
    __syncthreads();
    if (tid == 0) {
        float s0 = red[0] + red[2] + red[4] + red[6];
        float s1 = red[1] + red[3] + red[5] + red[7];
        int t = m0 / (N_ * R_);
        float* line = sspart + (blockIdx.x & 63) * 16;   // 64 distinct 64B lines
        atomicAdd(&line[t * 2 + 0], s0);
        atomicAdd(&line[t * 2 + 1], s1);
    }
}

// ---------------- LSTM: all 4 timesteps in one kernel; betas from spread partials ---------
__global__ __launch_bounds__(256) void k_lstm(
    const u16* __restrict__ intra, const float* __restrict__ sspart,
    const u16* __restrict__ Wc_pad, const float* __restrict__ biasv,
    u16* __restrict__ feats)
{
    __shared__ __align__(16) u16 hl[64][72];   // h state, bf16, wave-private 16-row stripes
    __shared__ float betas_s[8];
    const int tid = threadIdx.x, lane = tid & 63, wv = tid >> 6;
    const int col = lane & 15, quad = lane >> 4;
    int m0 = blockIdx.x * 64;
    int row = m0 + wv * 16 + col;
    int row_c = (row < N_) ? row : (N_ - 1);
    int rowbase = m0 + wv * 16 + quad * 4;

    if (tid < 64) {
        float a8[8];
        #pragma unroll
        for (int s = 0; s < 8; ++s) a8[s] = sspart[tid * 16 + s];
        #pragma unroll
        for (int s = 0; s < 8; ++s) {
            float v = a8[s];
            v += __shfl_xor(v, 1); v += __shfl_xor(v, 2);
            v += __shfl_xor(v, 4); v += __shfl_xor(v, 8);
            v += __shfl_xor(v, 16); v += __shfl_xor(v, 32);
            a8[s] = v;
        }
        if (tid < 4) {
            float s0 = a8[tid * 2] * (1.f / N_), s1 = a8[tid * 2 + 1] * (1.f / N_);
            float mx = fmaxf(s0, s1);
            float e0 = __expf(s0 - mx), e1 = __expf(s1 - mx);
            float inv = 1.f / (e0 + e1);
            betas_s[tid * 2] = e0 * inv; betas_s[tid * 2 + 1] = e1 * inv;
        }
    }
    __syncthreads();
    float betas[8];
    #pragma unroll
    for (int i = 0; i < 8; ++i) betas[i] = betas_s[i];

    float cc[4][4];
    #pragma unroll
    for (int j = 0; j < 4; ++j)
        #pragma unroll
        for (int reg = 0; reg < 4; ++reg) cc[j][reg] = 0.f;

    for (int t = 0; t < 4; ++t) {
        float b0 = betas[t * 2], b1 = betas[t * 2 + 1];
        const u16* ib = intra + ((size_t)t * N_ + row_c) * 128;

        f32x4 acc[16];
        #pragma unroll
        for (int cf = 0; cf < 16; ++cf) { acc[cf][0]=0.f; acc[cf][1]=0.f; acc[cf][2]=0.f; acc[cf][3]=0.f; }

        #pragma unroll
        for (int ks = 0; ks < 2; ++ks) {
            int coff = ks * 32 + quad * 8;
            bf16x8 i0 = *(const bf16x8*)(ib + coff);
            bf16x8 i1 = *(const bf16x8*)(ib + 64 + coff);
            union { u16 h[8]; bf16x8 v; } cv;
            #pragma unroll
            for (int j = 0; j < 8; ++j)
                cv.h[j] = f2bf(b0 * bf2f((u16)i0[j]) + b1 * bf2f((u16)i1[j]));
            const u16* bb = Wc_pad + ks * 32 + quad * 8;
            #pragma unroll
            for (int cf = 0; cf < 16; ++cf) {
                bf16x8 b = *(const bf16x8*)(bb + (cf * 16 + col) * 64);
                acc[cf] = __builtin_amdgcn_mfma_f32_16x16x32_bf16(cv.v, b, acc[cf], 0, 0, 0);
            }
        }
        if (t > 0) {
            #pragma unroll
            for (int ks = 0; ks < 2; ++ks) {
                bf16x8 a = *(const bf16x8*)&hl[wv * 16 + col][ks * 32 + quad * 8];
                const u16* bb = Wc_pad + BPAD + ks * 32 + quad * 8;
                #pragma unroll
                for (int cf = 0; cf < 16; ++cf) {
                    bf16x8 b = *(const bf16x8*)(bb + (cf * 16 + col) * 64);
                    acc[cf] = __builtin_amdgcn_mfma_f32_16x16x32_bf16(a, b, acc[cf], 0, 0, 0);
                }
            }
        }

        #pragma unroll
        for (int j = 0; j < 4; ++j) {
            int c = j * 16 + col;
            float bi = biasv[c], bf_ = biasv[64 + c], bg = biasv[128 + c], bo = biasv[192 + c];
            #pragma unroll
            for (int reg = 0; reg < 4; ++reg) {
                float gi = acc[j][reg] + bi;
                float gf = acc[j + 4][reg] + bf_;
                float gg = acc[j + 8][reg] + bg;
                float go = acc[j + 12][reg] + bo;
                float c2 = sigm(gf) * cc[j][reg] + sigm(gi) * ftanh(gg);
                float hh = sigm(go) * ftanh(c2);
                cc[j][reg] = c2;
                u16 hb = f2bf(hh);
                hl[wv * 16 + quad * 4 + reg][c] = hb;
                int rr = rowbase + reg;
                if (rr < N_)
                    feats[(size_t)rr * 256 + t * 64 + c] = hb;
            }
        }
    }
}

// ---------------- temporal causal MHA: MFMA QKV + per-lane attention ----------------
__global__ __launch_bounds__(256) void k_attn(
    const u16* __restrict__ feats, const float* __restrict__ pos_emb,
    const u16* __restrict__ qkv_pad, float* __restrict__ out)
{
    __shared__ float qkv_s[64 * 200];
    const int tid = threadIdx.x, lane = tid & 63, wv = tid >> 6;
    const int col = lane & 15, quad = lane >> 4;
    int m0 = blockIdx.x * 64;
    int row = m0 + wv * 16 + col;
    int trow = row & 3;

    f32x4 acc[12];
    #pragma unroll
    for (int cf = 0; cf < 12; ++cf) { acc[cf][0]=0.f; acc[cf][1]=0.f; acc[cf][2]=0.f; acc[cf][3]=0.f; }
    #pragma unroll
    for (int ks = 0; ks < 2; ++ks) {
        int coff = ks * 32 + quad * 8;
        bf16x8 fv = *(const bf16x8*)(feats + (size_t)row * 64 + coff);
        float4 p0 = *(const float4*)(pos_emb + trow * 64 + coff);
        float4 p1 = *(const float4*)(pos_emb + trow * 64 + coff + 4);
        union { u16 h[8]; bf16x8 v; } cv;
        cv.h[0] = f2bf(bf2f((u16)fv[0]) + p0.x); cv.h[1] = f2bf(bf2f((u16)fv[1]) + p0.y);
        cv.h[2] = f2bf(bf2f((u16)fv[2]) + p0.z); cv.h[3] = f2bf(bf2f((u16)fv[3]) + p0.w);
        cv.h[4] = f2bf(bf2f((u16)fv[4]) + p1.x); cv.h[5] = f2bf(bf2f((u16)fv[5]) + p1.y);
        cv.h[6] = f2bf(bf2f((u16)fv[6]) + p1.z); cv.h[7] = f2bf(bf2f((u16)fv[7]) + p1.w);
        bf16x8 a = cv.v;
        const u16* bb = qkv_pad + ks * 32 + quad * 8;
        #pragma unroll
        for (int cf = 0; cf < 12; ++cf) {
            bf16x8 b = *(const bf16x8*)(bb + (cf * 16 + col) * 64);
            acc[cf] = __builtin_amdgcn_mfma_f32_16x16x32_bf16(a, b, acc[cf], 0, 0, 0);
        }
    }
    #pragma unroll
    for (int cf = 0; cf < 12; ++cf) {
        int g = cf * 16 + col;
        #pragma unroll
        for (int reg = 0; reg < 4; ++reg) {
            int rl = wv * 16 + quad * 4 + reg;
            qkv_s[rl * 200 + g] = acc[cf][reg];
        }
    }
    __syncthreads();

    int nl = wv * 4 + (lane >> 4);
    int sub = lane & 15;
    int h = sub >> 2, tq = sub & 3;
    const float* qrow = qkv_s + (nl * 4 + tq) * 200 + h * 16;

    float s[4];
    #pragma unroll
    for (int tk = 0; tk < 4; ++tk) {
        const float* krow = qkv_s + (nl * 4 + tk) * 200 + 64 + h * 16;
        float d = 0.f;
        #pragma unroll
        for (int j = 0; j < 16; ++j) d += qrow[j] * krow[j];
        s[tk] = (tk > tq) ? -4294967295.0f : d * 0.5f;
    }
    float mx = fmaxf(fmaxf(s[0], s[1]), fmaxf(s[2], s[3]));
    float a0 = __expf(s[0]-mx), a1 = __expf(s[1]-mx), a2 = __expf(s[2]-mx), a3 = __expf(s[3]-mx);
    float inv = 1.f / (a0 + a1 + a2 + a3);
    a0 *= inv; a1 *= inv; a2 *= inv; a3 *= inv;

    int n = blockIdx.x * 16 + nl;
    const float* v0 = qkv_s + (nl * 4 + 0) * 200 + 128 + h * 16;
    const float* v1 = v0 + 200, *v2 = v0 + 400, *v3 = v0 + 600;
    #pragma unroll
    for (int cc4 = 0; cc4 < 4; ++cc4) {
        float4 o;
        o.x = a0*v0[cc4*4+0] + a1*v1[cc4*4+0] + a2*v2[cc4*4+0] + a3*v3[cc4*4+0];
        o.y = a0*v0[cc4*4+1] + a1*v1[cc4*4+1] + a2*v2[cc4*4+1] + a3*v3[cc4*4+1];
        o.z = a0*v0[cc4*4+2] + a1*v1[cc4*4+2] + a2*v2[cc4*4+2] + a3*v3[cc4*4+2];
        o.w = a0*v0[cc4*4+3] + a1*v1[cc4*4+3] + a2*v2[cc4*4+3] + a3*v3[cc4*4+3];
        *(float4*)(out + (size_t)n * 256 + tq * 64 + h * 16 + cc4 * 4) = o;
    }
}

// ---------------- launcher ----------------
extern "C" void kernel_launch(void* const* d_in, const int* in_sizes, int n_in,
                              void* d_out, int out_size, void* d_ws, size_t ws_size,
                              hipStream_t stream) {
    const float* x     = (const float*)d_in[0];
    const int* ei      = (const int*)d_in[1];
    const float* Wsrc  = (const float*)d_in[2];
    const float* Wdst  = (const float*)d_in[3];
    const float* att_src = (const float*)d_in[4];
    const float* att_dst = (const float*)d_in[5];
    const float* raW1  = (const float*)d_in[6];
    const float* rab1  = (const float*)d_in[7];
    const float* raW2  = (const float*)d_in[8];
    const float* Wih   = (const float*)d_in[9];
    const float* Whh   = (const float*)d_in[10];
    const float* bih   = (const float*)d_in[11];
    const float* bhh   = (const float*)d_in[12];
    const float* pos   = (const float*)d_in[13];
    const float* Wq    = (const float*)d_in[14];
    const float* Wk    = (const float*)d_in[15];
    const float* Wv    = (const float*)d_in[16];
    float* out = (float*)d_out;

    char* w = (char*)d_ws;
    size_t off = 0;
    auto alloc = [&](size_t bytes) -> char* {
        char* pp = w + off; off += (bytes + 255) & ~(size_t)255; return pp;
    };
    // ---- long-lived ----
    u16*   intra     = (u16*)  alloc((size_t)T_ * N_ * R_ * 64 * 2);  // 20.48 MB
    u16*   x_h       = (u16*)  alloc((size_t)T_ * N_ * 64 * 2);       // 10.24 MB (f16)
    float* sspart    = (float*)alloc(1024 * 4);   // 64 lines x 16 floats
    float* wdall     = (float*)alloc(1024 * 4);
    float* biasv     = (float*)alloc(256 * 4);
    u16*   raW1_pad  = (u16*)  alloc(BPAD * 2);
    u16*   Wc_pad    = (u16*)  alloc(2 * BPAD * 2);
    u16*   qkv_pad   = (u16*)  alloc(192 * 64 * 2);
    u16*   postB_pad = (u16*)  alloc(2 * 4 * 4096 * 2);
    int*   chunktot  = (int*)  alloc(P_ * NB_ * 4);
    // ---- union region ----
    char*  ubase   = alloc(0);
    size_t uoff = 0;
    auto ualloc = [&](size_t bytes) -> char* {
        char* pp = ubase + uoff; uoff += (bytes + 255) & ~(size_t)255; return pp;
    };
    int*   offsets = (int*)  ualloc((size_t)P_ * (N_ + 1) * 4);
    u16*   csr     = (u16*)  ualloc((size_t)P_ * E_ * 2);
    float* als_all = (float*)ualloc((size_t)P_ * N_ * 4 * 4);
    float* ald_all = (float*)ualloc((size_t)P_ * N_ * 4 * 4);
    u16*   partial = (u16*)  ualloc((size_t)P_ * NB_ * N_ * 2);
    u16*   xagg4   = (u16*)  ualloc((size_t)P_ * N_ * 256 * 2);   // 81.92 MB (all t,r)
    u16*   rank    = (u16*)  xagg4;   // overlay: rank dead before k_agg
    // phase 2 overlay (phase-1 sub-buffers dead after k_post)
    u16*   feats   = (u16*)  ubase;   // 10.24 MB
    (void)ws_size; (void)in_sizes; (void)n_in; (void)out_size;

    k_prep<<<72, 256, 0, stream>>>(Wdst, att_dst, Wih, Whh, bih, bhh, Wsrc, att_src, raW1,
                                   Wq, Wk, Wv, wdall, biasv, raW1_pad, Wc_pad, qkv_pad,
                                   postB_pad, sspart);
    k_hist<<<dim3(NB_, 8), 256, 0, stream>>>(ei, rank, partial);
    k_scan1<<<dim3(NB_, 8), 256, 0, stream>>>(partial, offsets, chunktot);
    k_scan3<<<dim3(79, 8), 256, 0, stream>>>(offsets, chunktot);
    k_scatter<<<10000, 256, 0, stream>>>(ei, offsets, rank, partial, csr);
    k_fold<<<dim3(313, 4), 256, 0, stream>>>(x, wdall, als_all, ald_all, x_h);
    k_agg<<<10000, 256, 0, stream>>>(offsets, csr, als_all, ald_all, x_h, xagg4);
    k_post<<<dim3(313, 2, 4), 256, 0, stream>>>(xagg4, postB_pad, intra);
    k_relagg<<<2500, 256, 0, stream>>>(intra, raW1_pad, rab1, raW2, sspart);
    k_lstm<<<313, 256, 0, stream>>>(intra, sspart, Wc_pad, biasv, feats);
    k_attn<<<1250, 256, 0, stream>>>(feats, pos, qkv_pad, out);
}

// Round 9
// 419.620 us; speedup vs baseline: 1.1884x; 1.0269x over previous
//
#include <hip/hip_runtime.h>
#include <hip/hip_bf16.h>

#define T_ 4
#define N_ 20000
#define E_ 320000
#define R_ 2
#define DIN 64
#define G_ 256   // H*Dh
#define P_ 8     // T*R
#define BPAD 16384  // 256 * 64 dense B-table halves per 64-k chunk (global loads: no pad)
#define NB_ 32      // CSR-build blocks per p
#define EPB_ 10000  // edges per CSR-build block
#define CHN_ 625    // nodes per scan chunk (N_/32)

typedef unsigned short u16;
typedef __attribute__((ext_vector_type(8))) short bf16x8;
typedef __attribute__((ext_vector_type(2))) _Float16 h2;
typedef __attribute__((ext_vector_type(4))) float f32x4;

__device__ __forceinline__ float bf2f(u16 u) {
    unsigned int i = ((unsigned int)u) << 16; float f;
    __builtin_memcpy(&f, &i, 4); return f;
}
__device__ __forceinline__ u16 f2bf(float f) {
    unsigned int i; __builtin_memcpy(&i, &f, 4);
    unsigned int r = i + 0x7fffu + ((i >> 16) & 1u);
    return (u16)(r >> 16);
}
__device__ __forceinline__ u16 f2h(float f) {
    union { _Float16 h; u16 u; } c; c.h = (_Float16)f; return c.u;
}
__device__ __forceinline__ float sigm(float x) { return 1.f / (1.f + __expf(-x)); }
// fast tanh: 1 - 2/(exp(2x)+1); hardware v_exp_f32, correct saturation at +-inf
__device__ __forceinline__ float ftanh(float x) { return 1.f - 2.f / (__expf(2.f * x) + 1.f); }
// broadcast lane l's float to all lanes (SGPR result); l must be wave-uniform
__device__ __forceinline__ float rdlanef(float v, int l) {
    int i; __builtin_memcpy(&i, &v, 4);
    int r = __builtin_amdgcn_readlane(i, l);
    float f; __builtin_memcpy(&f, &r, 4); return f;
}
// v_dot2_f32_f16: a.x*b.x + a.y*b.y + c in one VALU op
__device__ __forceinline__ float fdot2(h2 a, h2 b, float c) {
#if __has_builtin(__builtin_amdgcn_fdot2)
    return __builtin_amdgcn_fdot2(a, b, c, false);
#else
    float r;
    asm("v_dot2_f32_f16 %0, %1, %2, %3" : "=v"(r) : "v"(a), "v"(b), "v"(c));
    return r;
#endif
}
// pack 2 f32 -> 2 bf16 (RNE) in one VALU op
__device__ __forceinline__ unsigned cvtpk_bf16(float lo, float hi) {
    unsigned r;
    asm("v_cvt_pk_bf16_f32 %0, %1, %2" : "=v"(r) : "v"(lo), "v"(hi));
    return r;
}

// ---------------- LDS-free MFMA GEMM core (bf16 A, dense B stride 64) ----------------
__device__ __forceinline__ void gemm_direct(
    const u16* __restrict__ A, const u16* __restrict__ Bpad,
    int M, int Astride, int kchunks, int m0, f32x4* acc)
{
    const int tid = threadIdx.x;
    const int lane = tid & 63, wv = tid >> 6;
    const int col = lane & 15, quad = lane >> 4;
    #pragma unroll
    for (int cf = 0; cf < 16; ++cf) { acc[cf][0]=0.f; acc[cf][1]=0.f; acc[cf][2]=0.f; acc[cf][3]=0.f; }

    int row = m0 + wv * 16 + col;
    int row_c = (row < M) ? row : (M - 1);

    for (int kc = 0; kc < kchunks; ++kc) {
        #pragma unroll
        for (int ks = 0; ks < 2; ++ks) {
            bf16x8 a = *(const bf16x8*)(A + (size_t)row_c * Astride + kc * 64 + ks * 32 + quad * 8);
            const u16* bb = Bpad + kc * BPAD + ks * 32 + quad * 8;
            #pragma unroll
            for (int cf = 0; cf < 16; ++cf) {
                bf16x8 b = *(const bf16x8*)(bb + (cf * 16 + col) * 64);
                acc[cf] = __builtin_amdgcn_mfma_f32_16x16x32_bf16(a, b, acc[cf], 0, 0, 0);
            }
        }
    }
}

// ---------------- fold: als/ald GEMVs + x->f16 cast; wdall staged in LDS ----------------
__global__ __launch_bounds__(256) void k_fold(
    const float* __restrict__ x, const float* __restrict__ wdall,
    float* __restrict__ als_all, float* __restrict__ ald_all, u16* __restrict__ x_h)
{
    __shared__ float wds[1024];
    {
        int tid = threadIdx.x;
        *(float4*)(wds + tid * 4) = *(const float4*)(wdall + tid * 4);
    }
    __syncthreads();

    int t = blockIdx.y;
    int idx = blockIdx.x * 256 + threadIdx.x;
    if (idx >= N_ * 4) return;
    int n = idx >> 2, q = idx & 3;
    const float* xr = x + ((size_t)t * N_ + n) * 64 + q * 16;
    float4 xv[4];
    #pragma unroll
    for (int i = 0; i < 4; ++i) xv[i] = *(const float4*)(xr + i * 4);

    {
        union { u16 h[16]; ushort4 s4[4]; } cv;
        #pragma unroll
        for (int i = 0; i < 4; ++i) {
            cv.h[i*4+0] = f2h(xv[i].x); cv.h[i*4+1] = f2h(xv[i].y);
            cv.h[i*4+2] = f2h(xv[i].z); cv.h[i*4+3] = f2h(xv[i].w);
        }
        u16* xo = x_h + ((size_t)t * N_ + n) * 64 + q * 16;
        #pragma unroll
        for (int i = 0; i < 4; ++i) *(ushort4*)(xo + i * 4) = cv.s4[i];
    }

    float s[16];
    #pragma unroll
    for (int i = 0; i < 16; ++i) s[i] = 0.f;
    #pragma unroll
    for (int i = 0; i < 4; ++i) {
        float xe[4] = {xv[i].x, xv[i].y, xv[i].z, xv[i].w};
        #pragma unroll
        for (int e = 0; e < 4; ++e) {
            int k = q * 16 + i * 4 + e;
            float xk = xe[e];
            #pragma unroll
            for (int tb = 0; tb < 4; ++tb) {
                float4 w = *(const float4*)(wds + tb * 256 + k * 4);
                s[tb*4+0] += xk * w.x; s[tb*4+1] += xk * w.y;
                s[tb*4+2] += xk * w.z; s[tb*4+3] += xk * w.w;
            }
        }
    }
    #pragma unroll
    for (int i = 0; i < 16; ++i) {
        s[i] += __shfl_xor(s[i], 1);
        s[i] += __shfl_xor(s[i], 2);
    }
    if (q == 0) {
        *(float4*)(als_all + ((size_t)(t*2+0) * N_ + n) * 4) = make_float4(s[0], s[1], s[2], s[3]);
        *(float4*)(als_all + ((size_t)(t*2+1) * N_ + n) * 4) = make_float4(s[4], s[5], s[6], s[7]);
        *(float4*)(ald_all + ((size_t)(t*2+0) * N_ + n) * 4) = make_float4(s[8], s[9], s[10], s[11]);
        *(float4*)(ald_all + ((size_t)(t*2+1) * N_ + n) * 4) = make_float4(s[12], s[13], s[14], s[15]);
    }
}

// ---------------- prep: folded GEMV tables, dense B-tables, folded bias ----------------
__global__ void k_prep(const float* __restrict__ Wdst, const float* __restrict__ att_dst,
                       const float* __restrict__ Wih, const float* __restrict__ Whh,
                       const float* __restrict__ bih, const float* __restrict__ bhh,
                       const float* __restrict__ Wsrc, const float* __restrict__ att_src,
                       const float* __restrict__ raW1,
                       const float* __restrict__ Wq, const float* __restrict__ Wk,
                       const float* __restrict__ Wv,
                       float* __restrict__ wdall, float* __restrict__ biasv,
                       u16* __restrict__ raW1_pad, u16* __restrict__ Wc_pad,
                       u16* __restrict__ qkv_pad, u16* __restrict__ postB_pad,
                       float* __restrict__ sspart)
{
    int tid = threadIdx.x, bid = blockIdx.x;
    if (bid == 0) {
        for (int i = tid; i < 1024; i += 256) sspart[i] = 0.f;
        int k = tid >> 2, h = tid & 3;
        for (int r = 0; r < 2; ++r) {
            float ss = 0.f, sd = 0.f;
            for (int c = 0; c < 64; ++c) {
                ss += Wsrc[((size_t)r * 64 + k) * 256 + h * 64 + c] * att_src[r * 256 + h * 64 + c];
                sd += Wdst[((size_t)r * 64 + k) * 256 + h * 64 + c] * att_dst[r * 256 + h * 64 + c];
            }
            wdall[r * 256 + k * 4 + h] = ss;
            wdall[512 + r * 256 + k * 4 + h] = sd;
        }
        biasv[tid] = bih[tid] + bhh[tid];
    }
    for (int i = bid * 256 + tid; i < BPAD; i += gridDim.x * 256) {
        int n = i >> 6, kk = i & 63;
        raW1_pad[i] = f2bf(raW1[kk * 256 + n]);
    }
    for (int i = bid * 256 + tid; i < 2 * BPAD; i += gridDim.x * 256) {
        int kc = i >> 14, q = i & (BPAD - 1), n = q >> 6, kk = q & 63;
        const float* W = kc ? Whh : Wih;
        Wc_pad[i] = f2bf(W[n * 64 + kk]);
    }
    for (int i = bid * 256 + tid; i < 192 * 64; i += gridDim.x * 256) {
        int g = i >> 6, kk = i & 63;
        int j = g >> 6, c = g & 63;
        const float* W = (j == 0) ? Wq : (j == 1) ? Wk : Wv;
        qkv_pad[i] = f2bf(W[kk * 64 + c]);
    }
    // K-permuted post-projection table: xagg K index K' = d*4 + h (d = input dim,
    // h = head), matching k_agg's packed uint2 epilogue. B~[g][K'] = Wsrc[d][h*64+g].
    for (int i = bid * 256 + tid; i < 2 * 4 * 4096; i += gridDim.x * 256) {
        int r = i >> 14, q = i & 16383, kc = q >> 12, qq = q & 4095;
        int c = qq >> 6, kk = qq & 63;
        int d = kc * 16 + (kk >> 2), h = kk & 3;
        postB_pad[i] = f2bf(Wsrc[(size_t)r * 16384 + d * 256 + h * 64 + c]);
    }
}

// ---------------- CSR build ----------------
__global__ __launch_bounds__(256) void k_hist(const int* __restrict__ ei,
                                              u16* __restrict__ rank, u16* __restrict__ partial)
{
    __shared__ unsigned int hist[N_ / 2];
    int b = blockIdx.x, p = blockIdx.y, tid = threadIdx.x;
    for (int i = tid; i < N_ / 2; i += 256) hist[i] = 0u;
    __syncthreads();
    const int* dsts = ei + ((size_t)p * 2 + 1) * E_ + b * EPB_;
    u16* rk = rank + (size_t)p * E_ + b * EPB_;
    for (int e = tid; e < EPB_; e += 256) {
        int dst = dsts[e];
        unsigned sh = (unsigned)(dst & 1) * 16u;
        unsigned old = atomicAdd(&hist[dst >> 1], 1u << sh);
        rk[e] = (u16)((old >> sh) & 0xffffu);
    }
    __syncthreads();
    u16* part = partial + ((size_t)p * NB_ + b) * N_;
    for (int n = tid; n < N_; n += 256) {
        unsigned hv = hist[n >> 1];
        part[n] = (u16)((hv >> ((unsigned)(n & 1) * 16u)) & 0xffffu);
    }
}

__global__ __launch_bounds__(256) void k_scan1(u16* __restrict__ partial,
                                               int* __restrict__ offsets, int* __restrict__ chunktot)
{
    int p = blockIdx.y, ch = blockIdx.x;
    int tid = threadIdx.x, lane = tid & 63, wid = tid >> 6;
    __shared__ int wtot[4];
    u16* part = partial + (size_t)p * NB_ * N_;
    int* ofs = offsets + (size_t)p * (N_ + 1);
    int n0 = ch * CHN_;
    int carry = 0;
    for (int rnd = 0; rnd < 3; ++rnd) {
        int i = rnd * 256 + tid;
        int n = n0 + i;
        int v = 0;
        if (i < CHN_) {
            int run = 0;
            #pragma unroll 8
            for (int b = 0; b < NB_; ++b) {
                int pv = part[b * N_ + n];
                part[b * N_ + n] = (u16)run;
                run += pv;
            }
            v = run;
        }
        int incl = v;
        for (int d = 1; d < 64; d <<= 1) { int u = __shfl_up(incl, d); if (lane >= d) incl += u; }
        if (lane == 63) wtot[wid] = incl;
        __syncthreads();
        if (tid < 4) {
            int iv = wtot[tid];
            for (int d = 1; d < 4; d <<= 1) { int u = __shfl_up(iv, d); if (tid >= d) iv += u; }
            wtot[tid] = iv;
        }
        __syncthreads();
        int woff = (wid > 0) ? wtot[wid - 1] : 0;
        int tot = wtot[3];
        int excl = carry + woff + incl - v;
        if (i < CHN_) ofs[n] = excl;
        carry += tot;
        __syncthreads();
    }
    if (tid == 0) chunktot[p * NB_ + ch] = carry;
}

// scan3 also does scan2's 32-element prefix locally
__global__ void k_scan3(int* __restrict__ offsets, const int* __restrict__ chunktot) {
    __shared__ int cb[NB_];
    int p = blockIdx.y;
    int tid = threadIdx.x;
    if (tid < 64) {
        int v = (tid < NB_) ? chunktot[p * NB_ + tid] : 0;
        #pragma unroll
        for (int d = 1; d < NB_; d <<= 1) { int u = __shfl_up(v, d); if (tid >= d) v += u; }
        if (tid < NB_) cb[tid] = v;   // inclusive prefix
    }
    __syncthreads();
    int n = blockIdx.x * 256 + tid;
    if (n < N_) {
        int c = n / CHN_;
        int base = (c > 0) ? cb[c - 1] : 0;
        offsets[(size_t)p * (N_ + 1) + n] += base;
    }
    if (n == 0)
        offsets[(size_t)p * (N_ + 1) + N_] = E_;
}

// 1-D grid, p = bid & 7: round-robin dispatch pins each p to one XCD, so the
// random 2B csr writes (640 KB/p) stay in that XCD's L2 (kills the 8x write amp).
__global__ void k_scatter(const int* __restrict__ ei, const int* __restrict__ offsets,
                          const u16* __restrict__ rank, const u16* __restrict__ partial,
                          u16* __restrict__ csr) {
    int bid = blockIdx.x;
    int p = bid & 7;
    int e = (bid >> 3) * 256 + threadIdx.x;
    int src = ei[((size_t)p * 2 + 0) * E_ + e];
    int dst = ei[((size_t)p * 2 + 1) * E_ + e];
    int b = e / EPB_;
    int pos = offsets[p * (N_ + 1) + dst]
            + (int)partial[((size_t)p * NB_ + b) * N_ + dst]
            + (int)rank[(size_t)p * E_ + e];
    csr[(size_t)p * E_ + pos] = (u16)src;
}

// ---------------- GAT aggregation: 4 nodes/wave, batched gather, dot2 pairs ----------------
__global__ __launch_bounds__(256) void k_agg(
    const int* __restrict__ offsets, const u16* __restrict__ csr,
    const float* __restrict__ als_all, const float* __restrict__ ald_all,
    const u16* __restrict__ x_h, u16* __restrict__ xagg4)
{
    // ptab[wv][g][pair*8 + h*2 + (el&1)]  (per-g 128B regions, 16B aligned)
    __shared__ __align__(16) u16 ptab[4][4][64];
    const int bid = blockIdx.x;
    const int p = bid & 7;
    const int t = p >> 1;
    const int* off   = offsets + (size_t)p * (N_ + 1);
    const u16* srcs  = csr + (size_t)p * E_;
    const float* als = als_all + (size_t)p * N_ * 4;
    const float* ald = ald_all + (size_t)p * N_ * 4;
    const u16* xb    = x_h + (size_t)t * N_ * 64;

    const int tid = threadIdx.x, lane = tid & 63, wv = tid >> 6;
    const int g = lane >> 4, el = lane & 15;
    const int n0 = (bid >> 3) * 16 + wv * 4;   // 4 nodes per wave
    const int ng = n0 + g;
    const int o0 = off[ng], o1 = off[ng + 1];
    const int deg = o1 - o0;
    const float4 aldv = *(const float4*)(ald + (size_t)ng * 4);
    u16* pt = &ptab[wv][0][0];
    const int pw = g * 64 + (el >> 1) * 8 + (el & 1);

    int sdeg[4];
    #pragma unroll
    for (int q = 0; q < 4; ++q) sdeg[q] = __builtin_amdgcn_readlane(deg, q * 16);
    int mdeg = max(max(sdeg[0], sdeg[1]), max(sdeg[2], sdeg[3]));
    int nrounds = (mdeg + 15) >> 4;

    float acc[4][4];
    #pragma unroll
    for (int q = 0; q < 4; ++q)
        #pragma unroll
        for (int h = 0; h < 4; ++h) acc[q][h] = 0.f;
    float d0 = 0.f, d1 = 0.f, d2 = 0.f, d3 = 0.f;

    for (int rr = 0; rr < nrounds; ++rr) {
        int e = rr * 16 + el;
        int sv = 0;
        float p0 = 0.f, p1 = 0.f, p2 = 0.f, p3 = 0.f;
        if (e < deg) {
            sv = (int)srcs[o0 + e];
            float4 av = *(const float4*)(als + (size_t)sv * 4);
            float e0 = av.x + aldv.x, e1 = av.y + aldv.y;
            float e2 = av.z + aldv.z, e3 = av.w + aldv.w;
            e0 = fmaxf(e0, 0.2f * e0); e1 = fmaxf(e1, 0.2f * e1);
            e2 = fmaxf(e2, 0.2f * e2); e3 = fmaxf(e3, 0.2f * e3);
            p0 = __expf(e0); p1 = __expf(e1); p2 = __expf(e2); p3 = __expf(e3);
        }
        d0 += p0; d1 += p1; d2 += p2; d3 += p3;
        pt[pw + 0] = f2h(p0); pt[pw + 2] = f2h(p1);
        pt[pw + 4] = f2h(p2); pt[pw + 6] = f2h(p3);
        // x-phase: in-order DS within the wave -> ptab written above is visible
        #pragma unroll
        for (int q = 0; q < 4; ++q) {
            int rem = sdeg[q] - rr * 16;   // scalar -> uniform branches
            if (rem > 0) {
                const u16* ptq = pt + q * 64;
                unsigned xl0[8], xl1[8];
                #pragma unroll
                for (int pr = 0; pr < 8; ++pr) {
                    if (pr * 2 < rem) {
                        int s0i = __builtin_amdgcn_readlane(sv, q * 16 + pr * 2);
                        int s1i = __builtin_amdgcn_readlane(sv, q * 16 + pr * 2 + 1);
                        xl0[pr] = xb[((size_t)(unsigned)s0i << 6) + lane];
                        xl1[pr] = xb[((size_t)(unsigned)s1i << 6) + lane];
                    }
                }
                #pragma unroll
                for (int pr = 0; pr < 8; ++pr) {
                    if (pr * 2 < rem) {
                        unsigned xp = xl0[pr] | (xl1[pr] << 16);
                        uint4 ppv = *(const uint4*)(ptq + pr * 8);
                        h2 xv, q0, q1, q2, q3;
                        __builtin_memcpy(&xv, &xp, 4);
                        __builtin_memcpy(&q0, &ppv.x, 4);
                        __builtin_memcpy(&q1, &ppv.y, 4);
                        __builtin_memcpy(&q2, &ppv.z, 4);
                        __builtin_memcpy(&q3, &ppv.w, 4);
                        acc[q][0] = fdot2(xv, q0, acc[q][0]);
                        acc[q][1] = fdot2(xv, q1, acc[q][1]);
                        acc[q][2] = fdot2(xv, q2, acc[q][2]);
                        acc[q][3] = fdot2(xv, q3, acc[q][3]);
                    }
                }
            }
        }
    }
    // den reduce within each 16-lane group (xor masks < 16 stay in-group)
    d0 += __shfl_xor(d0, 1); d0 += __shfl_xor(d0, 2);
    d0 += __shfl_xor(d0, 4); d0 += __shfl_xor(d0, 8);
    d1 += __shfl_xor(d1, 1); d1 += __shfl_xor(d1, 2);
    d1 += __shfl_xor(d1, 4); d1 += __shfl_xor(d1, 8);
    d2 += __shfl_xor(d2, 1); d2 += __shfl_xor(d2, 2);
    d2 += __shfl_xor(d2, 4); d2 += __shfl_xor(d2, 8);
    d3 += __shfl_xor(d3, 1); d3 += __shfl_xor(d3, 2);
    d3 += __shfl_xor(d3, 4); d3 += __shfl_xor(d3, 8);
    float inv0 = 0.25f / (d0 + 1e-16f);
    float inv1 = 0.25f / (d1 + 1e-16f);
    float inv2 = 0.25f / (d2 + 1e-16f);
    float inv3 = 0.25f / (d3 + 1e-16f);
    #pragma unroll
    for (int q = 0; q < 4; ++q) {
        float s0 = rdlanef(inv0, q * 16);
        float s1 = rdlanef(inv1, q * 16);
        float s2 = rdlanef(inv2, q * 16);
        float s3 = rdlanef(inv3, q * 16);
        // K' = d*4 + h packing: lane (=d) writes [h0,h1,h2,h3] as one uint2
        unsigned w01 = cvtpk_bf16(acc[q][0] * s0, acc[q][1] * s1);
        unsigned w23 = cvtpk_bf16(acc[q][2] * s2, acc[q][3] * s3);
        *(uint2*)(xagg4 + ((size_t)p * N_ + n0 + q) * 256 + lane * 4) = make_uint2(w01, w23);
    }
}

// ---------------- post-projection: intra = xagg @ B~ (all t in one dispatch) ----------------
__global__ __launch_bounds__(256) void k_post(
    const u16* __restrict__ xagg4, const u16* __restrict__ postB_pad,
    u16* __restrict__ intra)
{
    const int t = blockIdx.z, r = blockIdx.y;
    const u16* A = xagg4 + ((size_t)(t * 2 + r)) * N_ * 256;
    const u16* Bp = postB_pad + (size_t)r * 4 * 4096;
    const int tid = threadIdx.x, lane = tid & 63, wv = tid >> 6;
    const int col = lane & 15, quad = lane >> 4;
    int m0 = blockIdx.x * 64;
    int row = m0 + wv * 16 + col;
    int row_c = (row < N_) ? row : (N_ - 1);

    f32x4 acc[4];
    #pragma unroll
    for (int cf = 0; cf < 4; ++cf) { acc[cf][0]=0.f; acc[cf][1]=0.f; acc[cf][2]=0.f; acc[cf][3]=0.f; }
    #pragma unroll
    for (int kc = 0; kc < 4; ++kc) {
        #pragma unroll
        for (int ks = 0; ks < 2; ++ks) {
            bf16x8 a = *(const bf16x8*)(A + (size_t)row_c * 256 + kc * 64 + ks * 32 + quad * 8);
            const u16* bb = Bp + kc * 4096 + ks * 32 + quad * 8;
            #pragma unroll
            for (int cf = 0; cf < 4; ++cf) {
                bf16x8 b = *(const bf16x8*)(bb + (cf * 16 + col) * 64);
                acc[cf] = __builtin_amdgcn_mfma_f32_16x16x32_bf16(a, b, acc[cf], 0, 0, 0);
            }
        }
    }
    int rowbase = m0 + wv * 16 + quad * 4;
    #pragma unroll
    for (int cf = 0; cf < 4; ++cf) {
        int c = cf * 16 + col;
        #pragma unroll
        for (int reg = 0; reg < 4; ++reg) {
            int rr = rowbase + reg;
            if (rr < N_)
                intra[(((size_t)t * N_ + rr) * 2 + r) * 64 + c] = f2bf(acc[cf][reg]);
        }
    }
}

// ---------------- RelationAgg GEMM + fused ftanh(.)@W2 epilogue; partials spread
// over 64 cache lines (same-line atomic serialization was a hidden 2x regression) --------
__global__ __launch_bounds__(256) void k_relagg(
    const u16* __restrict__ A, const u16* __restrict__ W1pad, const float* __restrict__ b1,
    const float* __restrict__ W2, float* __restrict__ sspart)
{
    int m0 = blockIdx.x * 64;
    f32x4 acc[16];
    gemm_direct(A, W1pad, T_ * N_ * R_, 64, 1, m0, acc);

    const int tid = threadIdx.x, lane = tid & 63, wv = tid >> 6;
    const int col = lane & 15;
    float sp[4] = {0.f, 0.f, 0.f, 0.f};
    #pragma unroll
    for (int cf = 0; cf < 16; ++cf) {
        int gcol = cf * 16 + col;
        float bb = b1[gcol];
        float ww = W2[gcol];
        #pragma unroll
        for (int reg = 0; reg < 4; ++reg)
            sp[reg] += ftanh(acc[cf][reg] + bb) * ww;
    }
    #pragma unroll
    for (int reg = 0; reg < 4; ++reg) {
        float v = sp[reg];
        v += __shfl_xor(v, 1); v += __shfl_xor(v, 2);
        v += __shfl_xor(v, 4); v += __shfl_xor(v, 8);
        sp[reg] = v;
    }
    // rows = m0 + wv*16 + quad*4 + reg ; rowbase is even so reg parity == r
    float se = sp[0] + sp[2];   // r = 0 rows of this lane's quad
    float so = sp[1] + sp[3];   // r = 1 rows
    se += __shfl_xor(se, 16); se += __shfl_xor(se, 32);
    so += __shfl_xor(so, 16); so += __shfl_xor(so, 32);
    __shared__ float red[8];
    if (lane == 0) { red[wv * 2] = se; red[wv * 2 + 1] = so; }
    __syncthreads();
    if (tid == 0) {
        float s0 = red[0] + red[2] + red[4] + red[6];
        float s1 = red[1] + red[3] + red[5] + red[7];
        int t = m0 / (N_ * R_);
        float* line = sspart + (blockIdx.x & 63) * 16;   // 64 distinct 64B lines
        atomicAdd(&line[t * 2 + 0], s0);
        atomicAdd(&line[t * 2 + 1], s1);
    }
}

// ---------------- LSTM: 4 timesteps fused; Wc staged in LDS (XOR-swizzled),
// intra prefetched for all t (kernel was latency-bound: occ 6.7%, all pipes idle) -------
__global__ __launch_bounds__(256) void k_lstm(
    const u16* __restrict__ intra, const float* __restrict__ sspart,
    const u16* __restrict__ Wc_pad, const float* __restrict__ biasv,
    u16* __restrict__ feats)
{
    // B-table in LDS: 512 rows (kc*256+g) x 128B, 16B slots XOR-swizzled by (row&7)
    __shared__ __align__(16) u16 wtab[512][64];    // 64 KB
    __shared__ __align__(16) u16 hl[64][72];       // h state, wave-private 16-row stripes
    __shared__ float betas_s[8];
    const int tid = threadIdx.x, lane = tid & 63, wv = tid >> 6;
    const int col = lane & 15, quad = lane >> 4;
    int m0 = blockIdx.x * 64;
    int row = m0 + wv * 16 + col;
    int row_c = (row < N_) ? row : (N_ - 1);
    int rowbase = m0 + wv * 16 + quad * 4;

    // prefetch all 4 timesteps' intra rows (16 independent 16B loads, one
    // latency exposure instead of serial-per-t)
    bf16x8 pi[4][4];
    #pragma unroll
    for (int t = 0; t < 4; ++t) {
        const u16* ib = intra + ((size_t)t * N_ + row_c) * 128;
        #pragma unroll
        for (int k = 0; k < 4; ++k)
            pi[t][k] = *(const bf16x8*)(ib + k * 32 + quad * 8);
    }

    // stage Wc_pad -> LDS with slot-XOR swizzle (T2): 4096 16B units, conflict-free
    {
        const uint4* src = (const uint4*)Wc_pad;
        #pragma unroll
        for (int it = 0; it < 16; ++it) {
            int u = it * 256 + tid;
            int r = u >> 3, s = u & 7;
            uint4 v = src[u];
            *(uint4*)((char*)&wtab[0][0] + (size_t)r * 128 + ((s ^ (r & 7)) * 16)) = v;
        }
    }
    if (tid < 64) {
        float a8[8];
        #pragma unroll
        for (int s = 0; s < 8; ++s) a8[s] = sspart[tid * 16 + s];
        #pragma unroll
        for (int s = 0; s < 8; ++s) {
            float v = a8[s];
            v += __shfl_xor(v, 1); v += __shfl_xor(v, 2);
            v += __shfl_xor(v, 4); v += __shfl_xor(v, 8);
            v += __shfl_xor(v, 16); v += __shfl_xor(v, 32);
            a8[s] = v;
        }
        if (tid < 4) {
            float s0 = a8[tid * 2] * (1.f / N_), s1 = a8[tid * 2 + 1] * (1.f / N_);
            float mx = fmaxf(s0, s1);
            float e0 = __expf(s0 - mx), e1 = __expf(s1 - mx);
            float inv = 1.f / (e0 + e1);
            betas_s[tid * 2] = e0 * inv; betas_s[tid * 2 + 1] = e1 * inv;
        }
    }
    __syncthreads();
    float betas[8];
    #pragma unroll
    for (int i = 0; i < 8; ++i) betas[i] = betas_s[i];

    float cc[4][4];
    #pragma unroll
    for (int j = 0; j < 4; ++j)
        #pragma unroll
        for (int reg = 0; reg < 4; ++reg) cc[j][reg] = 0.f;

    const int c7 = col & 7;
    #pragma unroll
    for (int t = 0; t < 4; ++t) {
        float b0 = betas[t * 2], b1 = betas[t * 2 + 1];

        f32x4 acc[16];
        #pragma unroll
        for (int cf = 0; cf < 16; ++cf) { acc[cf][0]=0.f; acc[cf][1]=0.f; acc[cf][2]=0.f; acc[cf][3]=0.f; }

        #pragma unroll
        for (int ks = 0; ks < 2; ++ks) {
            bf16x8 i0 = pi[t][ks];
            bf16x8 i1 = pi[t][2 + ks];
            union { u16 h[8]; bf16x8 v; } cv;
            #pragma unroll
            for (int j = 0; j < 8; ++j)
                cv.h[j] = f2bf(b0 * bf2f((u16)i0[j]) + b1 * bf2f((u16)i1[j]));
            #pragma unroll
            for (int cf = 0; cf < 16; ++cf) {
                bf16x8 b = *(const bf16x8*)((const char*)&wtab[0][0]
                    + (size_t)(cf * 16 + col) * 128 + (((ks * 4 + quad) ^ c7) * 16));
                acc[cf] = __builtin_amdgcn_mfma_f32_16x16x32_bf16(cv.v, b, acc[cf], 0, 0, 0);
            }
        }
        if (t > 0) {
            #pragma unroll
            for (int ks = 0; ks < 2; ++ks) {
                bf16x8 a = *(const bf16x8*)&hl[wv * 16 + col][ks * 32 + quad * 8];
                #pragma unroll
                for (int cf = 0; cf < 16; ++cf) {
                    bf16x8 b = *(const bf16x8*)((const char*)&wtab[0][0]
                        + (size_t)(256 + cf * 16 + col) * 128 + (((ks * 4 + quad) ^ c7) * 16));
                    acc[cf] = __builtin_amdgcn_mfma_f32_16x16x32_bf16(a, b, acc[cf], 0, 0, 0);
                }
            }
        }

        #pragma unroll
        for (int j = 0; j < 4; ++j) {
            int c = j * 16 + col;
            float bi = biasv[c], bf_ = biasv[64 + c], bg = biasv[128 + c], bo = biasv[192 + c];
            #pragma unroll
            for (int reg = 0; reg < 4; ++reg) {
                float gi = acc[j][reg] + bi;
                float gf = acc[j + 4][reg] + bf_;
                float gg = acc[j + 8][reg] + bg;
                float go = acc[j + 12][reg] + bo;
                float c2 = sigm(gf) * cc[j][reg] + sigm(gi) * ftanh(gg);
                float hh = sigm(go) * ftanh(c2);
                cc[j][reg] = c2;
                u16 hb = f2bf(hh);
                hl[wv * 16 + quad * 4 + reg][c] = hb;
                int rr = rowbase + reg;
                if (rr < N_)
                    feats[(size_t)rr * 256 + t * 64 + c] = hb;
            }
        }
    }
}

// ---------------- temporal causal MHA: MFMA QKV + per-lane attention ----------------
__global__ __launch_bounds__(256) void k_attn(
    const u16* __restrict__ feats, const float* __restrict__ pos_emb,
    const u16* __restrict__ qkv_pad, float* __restrict__ out)
{
    __shared__ float qkv_s[64 * 200];
    const int tid = threadIdx.x, lane = tid & 63, wv = tid >> 6;
    const int col = lane & 15, quad = lane >> 4;
    int m0 = blockIdx.x * 64;
    int row = m0 + wv * 16 + col;
    int trow = row & 3;

    f32x4 acc[12];
    #pragma unroll
    for (int cf = 0; cf < 12; ++cf) { acc[cf][0]=0.f; acc[cf][1]=0.f; acc[cf][2]=0.f; acc[cf][3]=0.f; }
    #pragma unroll
    for (int ks = 0; ks < 2; ++ks) {
        int coff = ks * 32 + quad * 8;
        bf16x8 fv = *(const bf16x8*)(feats + (size_t)row * 64 + coff);
        float4 p0 = *(const float4*)(pos_emb + trow * 64 + coff);
        float4 p1 = *(const float4*)(pos_emb + trow * 64 + coff + 4);
        union { u16 h[8]; bf16x8 v; } cv;
        cv.h[0] = f2bf(bf2f((u16)fv[0]) + p0.x); cv.h[1] = f2bf(bf2f((u16)fv[1]) + p0.y);
        cv.h[2] = f2bf(bf2f((u16)fv[2]) + p0.z); cv.h[3] = f2bf(bf2f((u16)fv[3]) + p0.w);
        cv.h[4] = f2bf(bf2f((u16)fv[4]) + p1.x); cv.h[5] = f2bf(bf2f((u16)fv[5]) + p1.y);
        cv.h[6] = f2bf(bf2f((u16)fv[6]) + p1.z); cv.h[7] = f2bf(bf2f((u16)fv[7]) + p1.w);
        bf16x8 a = cv.v;
        const u16* bb = qkv_pad + ks * 32 + quad * 8;
        #pragma unroll
        for (int cf = 0; cf < 12; ++cf) {
            bf16x8 b = *(const bf16x8*)(bb + (cf * 16 + col) * 64);
            acc[cf] = __builtin_amdgcn_mfma_f32_16x16x32_bf16(a, b, acc[cf], 0, 0, 0);
        }
    }
    #pragma unroll
    for (int cf = 0; cf < 12; ++cf) {
        int g = cf * 16 + col;
        #pragma unroll
        for (int reg = 0; reg < 4; ++reg) {
            int rl = wv * 16 + quad * 4 + reg;
            qkv_s[rl * 200 + g] = acc[cf][reg];
        }
    }
    __syncthreads();

    int nl = wv * 4 + (lane >> 4);
    int sub = lane & 15;
    int h = sub >> 2, tq = sub & 3;
    const float* qrow = qkv_s + (nl * 4 + tq) * 200 + h * 16;

    float s[4];
    #pragma unroll
    for (int tk = 0; tk < 4; ++tk) {
        const float* krow = qkv_s + (nl * 4 + tk) * 200 + 64 + h * 16;
        float d = 0.f;
        #pragma unroll
        for (int j = 0; j < 16; ++j) d += qrow[j] * krow[j];
        s[tk] = (tk > tq) ? -4294967295.0f : d * 0.5f;
    }
    float mx = fmaxf(fmaxf(s[0], s[1]), fmaxf(s[2], s[3]));
    float a0 = __expf(s[0]-mx), a1 = __expf(s[1]-mx), a2 = __expf(s[2]-mx), a3 = __expf(s[3]-mx);
    float inv = 1.f / (a0 + a1 + a2 + a3);
    a0 *= inv; a1 *= inv; a2 *= inv; a3 *= inv;

    int n = blockIdx.x * 16 + nl;
    const float* v0 = qkv_s + (nl * 4 + 0) * 200 + 128 + h * 16;
    const float* v1 = v0 + 200, *v2 = v0 + 400, *v3 = v0 + 600;
    #pragma unroll
    for (int cc4 = 0; cc4 < 4; ++cc4) {
        float4 o;
        o.x = a0*v0[cc4*4+0] + a1*v1[cc4*4+0] + a2*v2[cc4*4+0] + a3*v3[cc4*4+0];
        o.y = a0*v0[cc4*4+1] + a1*v1[cc4*4+1] + a2*v2[cc4*4+1] + a3*v3[cc4*4+1];
        o.z = a0*v0[cc4*4+2] + a1*v1[cc4*4+2] + a2*v2[cc4*4+2] + a3*v3[cc4*4+2];
        o.w = a0*v0[cc4*4+3] + a1*v1[cc4*4+3] + a2*v2[cc4*4+3] + a3*v3[cc4*4+3];
        *(float4*)(out + (size_t)n * 256 + tq * 64 + h * 16 + cc4 * 4) = o;
    }
}

// ---------------- launcher ----------------
extern "C" void kernel_launch(void* const* d_in, const int* in_sizes, int n_in,
                              void* d_out, int out_size, void* d_ws, size_t ws_size,
                              hipStream_t stream) {
    const float* x     = (const float*)d_in[0];
    const int* ei      = (const int*)d_in[1];
    const float* Wsrc  = (const float*)d_in[2];
    const float* Wdst  = (const float*)d_in[3];
    const float* att_src = (const float*)d_in[4];
    const float* att_dst = (const float*)d_in[5];
    const float* raW1  = (const float*)d_in[6];
    const float* rab1  = (const float*)d_in[7];
    const float* raW2  = (const float*)d_in[8];
    const float* Wih   = (const float*)d_in[9];
    const float* Whh   = (const float*)d_in[10];
    const float* bih   = (const float*)d_in[11];
    const float* bhh   = (const float*)d_in[12];
    const float* pos   = (const float*)d_in[13];
    const float* Wq    = (const float*)d_in[14];
    const float* Wk    = (const float*)d_in[15];
    const float* Wv    = (const float*)d_in[16];
    float* out = (float*)d_out;

    char* w = (char*)d_ws;
    size_t off = 0;
    auto alloc = [&](size_t bytes) -> char* {
        char* pp = w + off; off += (bytes + 255) & ~(size_t)255; return pp;
    };
    // ---- long-lived ----
    u16*   intra     = (u16*)  alloc((size_t)T_ * N_ * R_ * 64 * 2);  // 20.48 MB
    u16*   x_h       = (u16*)  alloc((size_t)T_ * N_ * 64 * 2);       // 10.24 MB (f16)
    float* sspart    = (float*)alloc(1024 * 4);   // 64 lines x 16 floats
    float* wdall     = (float*)alloc(1024 * 4);
    float* biasv     = (float*)alloc(256 * 4);
    u16*   raW1_pad  = (u16*)  alloc(BPAD * 2);
    u16*   Wc_pad    = (u16*)  alloc(2 * BPAD * 2);
    u16*   qkv_pad   = (u16*)  alloc(192 * 64 * 2);
    u16*   postB_pad = (u16*)  alloc(2 * 4 * 4096 * 2);
    int*   chunktot  = (int*)  alloc(P_ * NB_ * 4);
    // ---- union region ----
    char*  ubase   = alloc(0);
    size_t uoff = 0;
    auto ualloc = [&](size_t bytes) -> char* {
        char* pp = ubase + uoff; uoff += (bytes + 255) & ~(size_t)255; return pp;
    };
    int*   offsets = (int*)  ualloc((size_t)P_ * (N_ + 1) * 4);
    u16*   csr     = (u16*)  ualloc((size_t)P_ * E_ * 2);
    float* als_all = (float*)ualloc((size_t)P_ * N_ * 4 * 4);
    float* ald_all = (float*)ualloc((size_t)P_ * N_ * 4 * 4);
    u16*   partial = (u16*)  ualloc((size_t)P_ * NB_ * N_ * 2);
    u16*   xagg4   = (u16*)  ualloc((size_t)P_ * N_ * 256 * 2);   // 81.92 MB (all t,r)
    u16*   rank    = (u16*)  xagg4;   // overlay: rank dead before k_agg
    // phase 2 overlay (phase-1 sub-buffers dead after k_post)
    u16*   feats   = (u16*)  ubase;   // 10.24 MB
    (void)ws_size; (void)in_sizes; (void)n_in; (void)out_size;

    k_prep<<<72, 256, 0, stream>>>(Wdst, att_dst, Wih, Whh, bih, bhh, Wsrc, att_src, raW1,
                                   Wq, Wk, Wv, wdall, biasv, raW1_pad, Wc_pad, qkv_pad,
                                   postB_pad, sspart);
    k_hist<<<dim3(NB_, 8), 256, 0, stream>>>(ei, rank, partial);
    k_scan1<<<dim3(NB_, 8), 256, 0, stream>>>(partial, offsets, chunktot);
    k_scan3<<<dim3(79, 8), 256, 0, stream>>>(offsets, chunktot);
    k_scatter<<<10000, 256, 0, stream>>>(ei, offsets, rank, partial, csr);
    k_fold<<<dim3(313, 4), 256, 0, stream>>>(x, wdall, als_all, ald_all, x_h);
    k_agg<<<10000, 256, 0, stream>>>(offsets, csr, als_all, ald_all, x_h, xagg4);
    k_post<<<dim3(313, 2, 4), 256, 0, stream>>>(xagg4, postB_pad, intra);
    k_relagg<<<2500, 256, 0, stream>>>(intra, raW1_pad, rab1, raW2, sspart);
    k_lstm<<<313, 256, 0, stream>>>(intra, sspart, Wc_pad, biasv, feats);
    k_attn<<<1250, 256, 0, stream>>>(feats, pos, qkv_pad, out);
}

// Round 10
// 397.943 us; speedup vs baseline: 1.2532x; 1.0545x over previous
//
#include <hip/hip_runtime.h>
#include <hip/hip_bf16.h>

#define T_ 4
#define N_ 20000
#define E_ 320000
#define R_ 2
#define DIN 64
#define G_ 256   // H*Dh
#define P_ 8     // T*R
#define BPAD 16384  // 256 * 64 dense B-table halves per 64-k chunk (global loads: no pad)
#define NB_ 32      // CSR-build blocks per p
#define EPB_ 10000  // edges per CSR-build block
#define CHN_ 625    // nodes per scan chunk (N_/32)

typedef unsigned short u16;
typedef __attribute__((ext_vector_type(8))) short bf16x8;
typedef __attribute__((ext_vector_type(2))) _Float16 h2;
typedef __attribute__((ext_vector_type(4))) float f32x4;

__device__ __forceinline__ float bf2f(u16 u) {
    unsigned int i = ((unsigned int)u) << 16; float f;
    __builtin_memcpy(&f, &i, 4); return f;
}
__device__ __forceinline__ u16 f2bf(float f) {
    unsigned int i; __builtin_memcpy(&i, &f, 4);
    unsigned int r = i + 0x7fffu + ((i >> 16) & 1u);
    return (u16)(r >> 16);
}
__device__ __forceinline__ u16 f2h(float f) {
    union { _Float16 h; u16 u; } c; c.h = (_Float16)f; return c.u;
}
__device__ __forceinline__ float sigm(float x) { return 1.f / (1.f + __expf(-x)); }
// fast tanh: 1 - 2/(exp(2x)+1); hardware v_exp_f32, correct saturation at +-inf
__device__ __forceinline__ float ftanh(float x) { return 1.f - 2.f / (__expf(2.f * x) + 1.f); }
// broadcast lane l's float to all lanes (SGPR result); l must be wave-uniform
__device__ __forceinline__ float rdlanef(float v, int l) {
    int i; __builtin_memcpy(&i, &v, 4);
    int r = __builtin_amdgcn_readlane(i, l);
    float f; __builtin_memcpy(&f, &r, 4); return f;
}
// v_dot2_f32_f16: a.x*b.x + a.y*b.y + c in one VALU op
__device__ __forceinline__ float fdot2(h2 a, h2 b, float c) {
#if __has_builtin(__builtin_amdgcn_fdot2)
    return __builtin_amdgcn_fdot2(a, b, c, false);
#else
    float r;
    asm("v_dot2_f32_f16 %0, %1, %2, %3" : "=v"(r) : "v"(a), "v"(b), "v"(c));
    return r;
#endif
}
// pack 2 f32 -> 2 bf16 (RNE) in one VALU op
__device__ __forceinline__ unsigned cvtpk_bf16(float lo, float hi) {
    unsigned r;
    asm("v_cvt_pk_bf16_f32 %0, %1, %2" : "=v"(r) : "v"(lo), "v"(hi));
    return r;
}

// ---------------- LDS-free MFMA GEMM core (bf16 A, dense B stride 64) ----------------
__device__ __forceinline__ void gemm_direct(
    const u16* __restrict__ A, const u16* __restrict__ Bpad,
    int M, int Astride, int kchunks, int m0, f32x4* acc)
{
    const int tid = threadIdx.x;
    const int lane = tid & 63, wv = tid >> 6;
    const int col = lane & 15, quad = lane >> 4;
    #pragma unroll
    for (int cf = 0; cf < 16; ++cf) { acc[cf][0]=0.f; acc[cf][1]=0.f; acc[cf][2]=0.f; acc[cf][3]=0.f; }

    int row = m0 + wv * 16 + col;
    int row_c = (row < M) ? row : (M - 1);

    for (int kc = 0; kc < kchunks; ++kc) {
        #pragma unroll
        for (int ks = 0; ks < 2; ++ks) {
            bf16x8 a = *(const bf16x8*)(A + (size_t)row_c * Astride + kc * 64 + ks * 32 + quad * 8);
            const u16* bb = Bpad + kc * BPAD + ks * 32 + quad * 8;
            #pragma unroll
            for (int cf = 0; cf < 16; ++cf) {
                bf16x8 b = *(const bf16x8*)(bb + (cf * 16 + col) * 64);
                acc[cf] = __builtin_amdgcn_mfma_f32_16x16x32_bf16(a, b, acc[cf], 0, 0, 0);
            }
        }
    }
}

// ---------------- fold: als/ald GEMVs + x->f16 cast; wdall staged in LDS ----------------
__global__ __launch_bounds__(256) void k_fold(
    const float* __restrict__ x, const float* __restrict__ wdall,
    float* __restrict__ als_all, float* __restrict__ ald_all, u16* __restrict__ x_h)
{
    __shared__ float wds[1024];
    {
        int tid = threadIdx.x;
        *(float4*)(wds + tid * 4) = *(const float4*)(wdall + tid * 4);
    }
    __syncthreads();

    int t = blockIdx.y;
    int idx = blockIdx.x * 256 + threadIdx.x;
    if (idx >= N_ * 4) return;
    int n = idx >> 2, q = idx & 3;
    const float* xr = x + ((size_t)t * N_ + n) * 64 + q * 16;
    float4 xv[4];
    #pragma unroll
    for (int i = 0; i < 4; ++i) xv[i] = *(const float4*)(xr + i * 4);

    {
        union { u16 h[16]; ushort4 s4[4]; } cv;
        #pragma unroll
        for (int i = 0; i < 4; ++i) {
            cv.h[i*4+0] = f2h(xv[i].x); cv.h[i*4+1] = f2h(xv[i].y);
            cv.h[i*4+2] = f2h(xv[i].z); cv.h[i*4+3] = f2h(xv[i].w);
        }
        u16* xo = x_h + ((size_t)t * N_ + n) * 64 + q * 16;
        #pragma unroll
        for (int i = 0; i < 4; ++i) *(ushort4*)(xo + i * 4) = cv.s4[i];
    }

    float s[16];
    #pragma unroll
    for (int i = 0; i < 16; ++i) s[i] = 0.f;
    #pragma unroll
    for (int i = 0; i < 4; ++i) {
        float xe[4] = {xv[i].x, xv[i].y, xv[i].z, xv[i].w};
        #pragma unroll
        for (int e = 0; e < 4; ++e) {
            int k = q * 16 + i * 4 + e;
            float xk = xe[e];
            #pragma unroll
            for (int tb = 0; tb < 4; ++tb) {
                float4 w = *(const float4*)(wds + tb * 256 + k * 4);
                s[tb*4+0] += xk * w.x; s[tb*4+1] += xk * w.y;
                s[tb*4+2] += xk * w.z; s[tb*4+3] += xk * w.w;
            }
        }
    }
    #pragma unroll
    for (int i = 0; i < 16; ++i) {
        s[i] += __shfl_xor(s[i], 1);
        s[i] += __shfl_xor(s[i], 2);
    }
    if (q == 0) {
        *(float4*)(als_all + ((size_t)(t*2+0) * N_ + n) * 4) = make_float4(s[0], s[1], s[2], s[3]);
        *(float4*)(als_all + ((size_t)(t*2+1) * N_ + n) * 4) = make_float4(s[4], s[5], s[6], s[7]);
        *(float4*)(ald_all + ((size_t)(t*2+0) * N_ + n) * 4) = make_float4(s[8], s[9], s[10], s[11]);
        *(float4*)(ald_all + ((size_t)(t*2+1) * N_ + n) * 4) = make_float4(s[12], s[13], s[14], s[15]);
    }
}

// ---------------- prep: folded GEMV tables, dense B-tables, folded bias ----------------
__global__ void k_prep(const float* __restrict__ Wdst, const float* __restrict__ att_dst,
                       const float* __restrict__ Wih, const float* __restrict__ Whh,
                       const float* __restrict__ bih, const float* __restrict__ bhh,
                       const float* __restrict__ Wsrc, const float* __restrict__ att_src,
                       const float* __restrict__ raW1,
                       const float* __restrict__ Wq, const float* __restrict__ Wk,
                       const float* __restrict__ Wv,
                       float* __restrict__ wdall, float* __restrict__ biasv,
                       u16* __restrict__ raW1_pad, u16* __restrict__ Wc_pad,
                       u16* __restrict__ qkv_pad, u16* __restrict__ postB_pad,
                       float* __restrict__ sspart)
{
    int tid = threadIdx.x, bid = blockIdx.x;
    if (bid == 0) {
        for (int i = tid; i < 1024; i += 256) sspart[i] = 0.f;
        int k = tid >> 2, h = tid & 3;
        for (int r = 0; r < 2; ++r) {
            float ss = 0.f, sd = 0.f;
            for (int c = 0; c < 64; ++c) {
                ss += Wsrc[((size_t)r * 64 + k) * 256 + h * 64 + c] * att_src[r * 256 + h * 64 + c];
                sd += Wdst[((size_t)r * 64 + k) * 256 + h * 64 + c] * att_dst[r * 256 + h * 64 + c];
            }
            wdall[r * 256 + k * 4 + h] = ss;
            wdall[512 + r * 256 + k * 4 + h] = sd;
        }
        biasv[tid] = bih[tid] + bhh[tid];
    }
    for (int i = bid * 256 + tid; i < BPAD; i += gridDim.x * 256) {
        int n = i >> 6, kk = i & 63;
        raW1_pad[i] = f2bf(raW1[kk * 256 + n]);
    }
    for (int i = bid * 256 + tid; i < 2 * BPAD; i += gridDim.x * 256) {
        int kc = i >> 14, q = i & (BPAD - 1), n = q >> 6, kk = q & 63;
        const float* W = kc ? Whh : Wih;
        Wc_pad[i] = f2bf(W[n * 64 + kk]);
    }
    for (int i = bid * 256 + tid; i < 192 * 64; i += gridDim.x * 256) {
        int g = i >> 6, kk = i & 63;
        int j = g >> 6, c = g & 63;
        const float* W = (j == 0) ? Wq : (j == 1) ? Wk : Wv;
        qkv_pad[i] = f2bf(W[kk * 64 + c]);
    }
    // K-permuted post-projection table: xagg K index K' = d*4 + h (d = input dim,
    // h = head), matching k_agg's packed epilogue. B~[g][K'] = Wsrc[d][h*64+g].
    for (int i = bid * 256 + tid; i < 2 * 4 * 4096; i += gridDim.x * 256) {
        int r = i >> 14, q = i & 16383, kc = q >> 12, qq = q & 4095;
        int c = qq >> 6, kk = qq & 63;
        int d = kc * 16 + (kk >> 2), h = kk & 3;
        postB_pad[i] = f2bf(Wsrc[(size_t)r * 16384 + d * 256 + h * 64 + c]);
    }
}

// ---------------- CSR build ----------------
__global__ __launch_bounds__(256) void k_hist(const int* __restrict__ ei,
                                              u16* __restrict__ rank, u16* __restrict__ partial)
{
    __shared__ unsigned int hist[N_ / 2];
    int b = blockIdx.x, p = blockIdx.y, tid = threadIdx.x;
    for (int i = tid; i < N_ / 2; i += 256) hist[i] = 0u;
    __syncthreads();
    const int* dsts = ei + ((size_t)p * 2 + 1) * E_ + b * EPB_;
    u16* rk = rank + (size_t)p * E_ + b * EPB_;
    for (int e = tid; e < EPB_; e += 256) {
        int dst = dsts[e];
        unsigned sh = (unsigned)(dst & 1) * 16u;
        unsigned old = atomicAdd(&hist[dst >> 1], 1u << sh);
        rk[e] = (u16)((old >> sh) & 0xffffu);
    }
    __syncthreads();
    u16* part = partial + ((size_t)p * NB_ + b) * N_;
    for (int n = tid; n < N_; n += 256) {
        unsigned hv = hist[n >> 1];
        part[n] = (u16)((hv >> ((unsigned)(n & 1) * 16u)) & 0xffffu);
    }
}

__global__ __launch_bounds__(256) void k_scan1(u16* __restrict__ partial,
                                               int* __restrict__ offsets, int* __restrict__ chunktot)
{
    int p = blockIdx.y, ch = blockIdx.x;
    int tid = threadIdx.x, lane = tid & 63, wid = tid >> 6;
    __shared__ int wtot[4];
    u16* part = partial + (size_t)p * NB_ * N_;
    int* ofs = offsets + (size_t)p * (N_ + 1);
    int n0 = ch * CHN_;
    int carry = 0;
    for (int rnd = 0; rnd < 3; ++rnd) {
        int i = rnd * 256 + tid;
        int n = n0 + i;
        int v = 0;
        if (i < CHN_) {
            int run = 0;
            #pragma unroll 8
            for (int b = 0; b < NB_; ++b) {
                int pv = part[b * N_ + n];
                part[b * N_ + n] = (u16)run;
                run += pv;
            }
            v = run;
        }
        int incl = v;
        for (int d = 1; d < 64; d <<= 1) { int u = __shfl_up(incl, d); if (lane >= d) incl += u; }
        if (lane == 63) wtot[wid] = incl;
        __syncthreads();
        if (tid < 4) {
            int iv = wtot[tid];
            for (int d = 1; d < 4; d <<= 1) { int u = __shfl_up(iv, d); if (tid >= d) iv += u; }
            wtot[tid] = iv;
        }
        __syncthreads();
        int woff = (wid > 0) ? wtot[wid - 1] : 0;
        int tot = wtot[3];
        int excl = carry + woff + incl - v;
        if (i < CHN_) ofs[n] = excl;
        carry += tot;
        __syncthreads();
    }
    if (tid == 0) chunktot[p * NB_ + ch] = carry;
}

// scan3 also does scan2's 32-element prefix locally
__global__ void k_scan3(int* __restrict__ offsets, const int* __restrict__ chunktot) {
    __shared__ int cb[NB_];
    int p = blockIdx.y;
    int tid = threadIdx.x;
    if (tid < 64) {
        int v = (tid < NB_) ? chunktot[p * NB_ + tid] : 0;
        #pragma unroll
        for (int d = 1; d < NB_; d <<= 1) { int u = __shfl_up(v, d); if (tid >= d) v += u; }
        if (tid < NB_) cb[tid] = v;   // inclusive prefix
    }
    __syncthreads();
    int n = blockIdx.x * 256 + tid;
    if (n < N_) {
        int c = n / CHN_;
        int base = (c > 0) ? cb[c - 1] : 0;
        offsets[(size_t)p * (N_ + 1) + n] += base;
    }
    if (n == 0)
        offsets[(size_t)p * (N_ + 1) + N_] = E_;
}

// 1-D grid, p = bid & 7: round-robin dispatch pins each p to one XCD, so the
// random 2B csr writes (640 KB/p) stay in that XCD's L2 (kills the 8x write amp).
__global__ void k_scatter(const int* __restrict__ ei, const int* __restrict__ offsets,
                          const u16* __restrict__ rank, const u16* __restrict__ partial,
                          u16* __restrict__ csr) {
    int bid = blockIdx.x;
    int p = bid & 7;
    int e = (bid >> 3) * 256 + threadIdx.x;
    int src = ei[((size_t)p * 2 + 0) * E_ + e];
    int dst = ei[((size_t)p * 2 + 1) * E_ + e];
    int b = e / EPB_;
    int pos = offsets[p * (N_ + 1) + dst]
            + (int)partial[((size_t)p * NB_ + b) * N_ + dst]
            + (int)rank[(size_t)p * E_ + e];
    csr[(size_t)p * E_ + pos] = (u16)src;
}

// ---------------- GAT aggregation + fused post-projection ----------------
// Phase 1 (per wave, 4 nodes): p-phase exps + dot2-pair x-phase as before, but the
// normalized bf16 output goes to a block-shared LDS tile xs[16][256] (16 nodes =
// whole block, slot-XOR swizzled). Phase 2 (per block, after one barrier): each
// wave computes its 16-column slice of D[16x64] = xs @ postB[r] with 8 MFMAs and
// writes intra directly. Kills the 82 MB xagg4 HBM round trip + the k_post dispatch.
__global__ __launch_bounds__(256) void k_agg(
    const int* __restrict__ offsets, const u16* __restrict__ csr,
    const float* __restrict__ als_all, const float* __restrict__ ald_all,
    const u16* __restrict__ x_h, const u16* __restrict__ postB_pad,
    u16* __restrict__ intra)
{
    // ptab[wv][g][pair*8 + h*2 + (el&1)]  (per-g 128B regions, 16B aligned)
    __shared__ __align__(16) u16 ptab[4][4][64];
    __shared__ __align__(16) u16 xs[16 * 256];   // 8 KB block tile, swizzled
    const int bid = blockIdx.x;
    const int p = bid & 7;
    const int t = p >> 1, rel = p & 1;
    const int* off   = offsets + (size_t)p * (N_ + 1);
    const u16* srcs  = csr + (size_t)p * E_;
    const float* als = als_all + (size_t)p * N_ * 4;
    const float* ald = ald_all + (size_t)p * N_ * 4;
    const u16* xb    = x_h + (size_t)t * N_ * 64;

    const int tid = threadIdx.x, lane = tid & 63, wv = tid >> 6;
    const int g = lane >> 4, el = lane & 15;
    const int nb0 = (bid >> 3) * 16;           // block's 16 nodes
    const int n0 = nb0 + wv * 4;               // wave's 4 nodes
    const int ng = n0 + g;
    const int o0 = off[ng], o1 = off[ng + 1];
    const int deg = o1 - o0;
    const float4 aldv = *(const float4*)(ald + (size_t)ng * 4);
    u16* pt = &ptab[wv][0][0];
    const int pw = g * 64 + (el >> 1) * 8 + (el & 1);

    int sdeg[4];
    #pragma unroll
    for (int q = 0; q < 4; ++q) sdeg[q] = __builtin_amdgcn_readlane(deg, q * 16);
    int mdeg = max(max(sdeg[0], sdeg[1]), max(sdeg[2], sdeg[3]));
    int nrounds = (mdeg + 15) >> 4;

    float acc[4][4];
    #pragma unroll
    for (int q = 0; q < 4; ++q)
        #pragma unroll
        for (int h = 0; h < 4; ++h) acc[q][h] = 0.f;
    float d0 = 0.f, d1 = 0.f, d2 = 0.f, d3 = 0.f;

    for (int rr = 0; rr < nrounds; ++rr) {
        int e = rr * 16 + el;
        int sv = 0;
        float p0 = 0.f, p1 = 0.f, p2 = 0.f, p3 = 0.f;
        if (e < deg) {
            sv = (int)srcs[o0 + e];
            float4 av = *(const float4*)(als + (size_t)sv * 4);
            float e0 = av.x + aldv.x, e1 = av.y + aldv.y;
            float e2 = av.z + aldv.z, e3 = av.w + aldv.w;
            e0 = fmaxf(e0, 0.2f * e0); e1 = fmaxf(e1, 0.2f * e1);
            e2 = fmaxf(e2, 0.2f * e2); e3 = fmaxf(e3, 0.2f * e3);
            p0 = __expf(e0); p1 = __expf(e1); p2 = __expf(e2); p3 = __expf(e3);
        }
        d0 += p0; d1 += p1; d2 += p2; d3 += p3;
        pt[pw + 0] = f2h(p0); pt[pw + 2] = f2h(p1);
        pt[pw + 4] = f2h(p2); pt[pw + 6] = f2h(p3);
        // x-phase: in-order DS within the wave -> ptab written above is visible
        #pragma unroll
        for (int q = 0; q < 4; ++q) {
            int rem = sdeg[q] - rr * 16;   // scalar -> uniform branches
            if (rem >= 16) {
                const u16* ptq = pt + q * 64;
                unsigned xl0[8], xl1[8];
                #pragma unroll
                for (int pr = 0; pr < 8; ++pr) {
                    int s0i = __builtin_amdgcn_readlane(sv, q * 16 + pr * 2);
                    int s1i = __builtin_amdgcn_readlane(sv, q * 16 + pr * 2 + 1);
                    xl0[pr] = xb[((size_t)(unsigned)s0i << 6) + lane];
                    xl1[pr] = xb[((size_t)(unsigned)s1i << 6) + lane];
                }
                #pragma unroll
                for (int pr = 0; pr < 8; ++pr) {
                    unsigned xp = xl0[pr] | (xl1[pr] << 16);
                    uint4 ppv = *(const uint4*)(ptq + pr * 8);
                    h2 xv, q0, q1, q2, q3;
                    __builtin_memcpy(&xv, &xp, 4);
                    __builtin_memcpy(&q0, &ppv.x, 4);
                    __builtin_memcpy(&q1, &ppv.y, 4);
                    __builtin_memcpy(&q2, &ppv.z, 4);
                    __builtin_memcpy(&q3, &ppv.w, 4);
                    acc[q][0] = fdot2(xv, q0, acc[q][0]);
                    acc[q][1] = fdot2(xv, q1, acc[q][1]);
                    acc[q][2] = fdot2(xv, q2, acc[q][2]);
                    acc[q][3] = fdot2(xv, q3, acc[q][3]);
                }
            } else if (rem > 0) {
                const u16* ptq = pt + q * 64;
                unsigned xl0[8], xl1[8];
                #pragma unroll
                for (int pr = 0; pr < 8; ++pr) {
                    if (pr * 2 < rem) {
                        int s0i = __builtin_amdgcn_readlane(sv, q * 16 + pr * 2);
                        int s1i = __builtin_amdgcn_readlane(sv, q * 16 + pr * 2 + 1);
                        xl0[pr] = xb[((size_t)(unsigned)s0i << 6) + lane];
                        xl1[pr] = xb[((size_t)(unsigned)s1i << 6) + lane];
                    }
                }
                #pragma unroll
                for (int pr = 0; pr < 8; ++pr) {
                    if (pr * 2 < rem) {
                        unsigned xp = xl0[pr] | (xl1[pr] << 16);
                        uint4 ppv = *(const uint4*)(ptq + pr * 8);
                        h2 xv, q0, q1, q2, q3;
                        __builtin_memcpy(&xv, &xp, 4);
                        __builtin_memcpy(&q0, &ppv.x, 4);
                        __builtin_memcpy(&q1, &ppv.y, 4);
                        __builtin_memcpy(&q2, &ppv.z, 4);
                        __builtin_memcpy(&q3, &ppv.w, 4);
                        acc[q][0] = fdot2(xv, q0, acc[q][0]);
                        acc[q][1] = fdot2(xv, q1, acc[q][1]);
                        acc[q][2] = fdot2(xv, q2, acc[q][2]);
                        acc[q][3] = fdot2(xv, q3, acc[q][3]);
                    }
                }
            }
        }
    }
    // den reduce within each 16-lane group (xor masks < 16 stay in-group)
    d0 += __shfl_xor(d0, 1); d0 += __shfl_xor(d0, 2);
    d0 += __shfl_xor(d0, 4); d0 += __shfl_xor(d0, 8);
    d1 += __shfl_xor(d1, 1); d1 += __shfl_xor(d1, 2);
    d1 += __shfl_xor(d1, 4); d1 += __shfl_xor(d1, 8);
    d2 += __shfl_xor(d2, 1); d2 += __shfl_xor(d2, 2);
    d2 += __shfl_xor(d2, 4); d2 += __shfl_xor(d2, 8);
    d3 += __shfl_xor(d3, 1); d3 += __shfl_xor(d3, 2);
    d3 += __shfl_xor(d3, 4); d3 += __shfl_xor(d3, 8);
    float inv0 = 0.25f / (d0 + 1e-16f);
    float inv1 = 0.25f / (d1 + 1e-16f);
    float inv2 = 0.25f / (d2 + 1e-16f);
    float inv3 = 0.25f / (d3 + 1e-16f);
    #pragma unroll
    for (int q = 0; q < 4; ++q) {
        float s0 = rdlanef(inv0, q * 16);
        float s1 = rdlanef(inv1, q * 16);
        float s2 = rdlanef(inv2, q * 16);
        float s3 = rdlanef(inv3, q * 16);
        // K' = d*4 + h packing; store to swizzled LDS tile row (wv*4+q)
        unsigned w01 = cvtpk_bf16(acc[q][0] * s0, acc[q][1] * s1);
        unsigned w23 = cvtpk_bf16(acc[q][2] * s2, acc[q][3] * s3);
        int rowt = wv * 4 + q;
        char* dst = (char*)xs + rowt * 512 + (((lane >> 1) ^ (rowt & 7)) * 16) + (lane & 1) * 8;
        *(uint2*)dst = make_uint2(w01, w23);
    }
    __syncthreads();

    // ---- fused post-projection: D[16 nodes][64] = xs(16x256) @ postB[rel](256x64) ----
    {
        const int col = lane & 15, quad = lane >> 4;
        const u16* Bp = postB_pad + (size_t)rel * 4 * 4096;
        f32x4 pacc;
        pacc[0] = 0.f; pacc[1] = 0.f; pacc[2] = 0.f; pacc[3] = 0.f;
        #pragma unroll
        for (int kc = 0; kc < 4; ++kc) {
            #pragma unroll
            for (int ks = 0; ks < 2; ++ks) {
                int slot = kc * 8 + ks * 4 + quad;
                bf16x8 a = *(const bf16x8*)((const char*)xs + col * 512 + ((slot ^ (col & 7)) * 16));
                bf16x8 b = *(const bf16x8*)(Bp + (size_t)kc * 4096 + (wv * 16 + col) * 64 + ks * 32 + quad * 8);
                pacc = __builtin_amdgcn_mfma_f32_16x16x32_bf16(a, b, pacc, 0, 0, 0);
            }
        }
        #pragma unroll
        for (int reg = 0; reg < 4; ++reg) {
            int node = nb0 + quad * 4 + reg;
            intra[(((size_t)t * N_ + node) * 2 + rel) * 64 + wv * 16 + col] = f2bf(pacc[reg]);
        }
    }
}

// ---------------- RelationAgg GEMM + fused ftanh(.)@W2 epilogue; partials spread
// over 64 cache lines (same-line atomic serialization was a hidden 2x regression) --------
__global__ __launch_bounds__(256) void k_relagg(
    const u16* __restrict__ A, const u16* __restrict__ W1pad, const float* __restrict__ b1,
    const float* __restrict__ W2, float* __restrict__ sspart)
{
    int m0 = blockIdx.x * 64;
    f32x4 acc[16];
    gemm_direct(A, W1pad, T_ * N_ * R_, 64, 1, m0, acc);

    const int tid = threadIdx.x, lane = tid & 63, wv = tid >> 6;
    const int col = lane & 15;
    float sp[4] = {0.f, 0.f, 0.f, 0.f};
    #pragma unroll
    for (int cf = 0; cf < 16; ++cf) {
        int gcol = cf * 16 + col;
        float bb = b1[gcol];
        float ww = W2[gcol];
        #pragma unroll
        for (int reg = 0; reg < 4; ++reg)
            sp[reg] += ftanh(acc[cf][reg] + bb) * ww;
    }
    #pragma unroll
    for (int reg = 0; reg < 4; ++reg) {
        float v = sp[reg];
        v += __shfl_xor(v, 1); v += __shfl_xor(v, 2);
        v += __shfl_xor(v, 4); v += __shfl_xor(v, 8);
        sp[reg] = v;
    }
    // rows = m0 + wv*16 + quad*4 + reg ; rowbase is even so reg parity == r
    float se = sp[0] + sp[2];   // r = 0 rows of this lane's quad
    float so = sp[1] + sp[3];   // r = 1 rows
    se += __shfl_xor(se, 16); se += __shfl_xor(se, 32);
    so += __shfl_xor(so, 16); so += __shfl_xor(so, 32);
    __shared__ float red[8];
    if (lane == 0) { red[wv * 2] = se; red[wv * 2 + 1] = so; }
    __syncthreads();
    if (tid == 0) {
        float s0 = red[0] + red[2] + red[4] + red[6];
        float s1 = red[1] + red[3] + red[5] + red[7];
        int t = m0 / (N_ * R_);
        float* line = sspart + (blockIdx.x & 63) * 16;   // 64 distinct 64B lines
        atomicAdd(&line[t * 2 + 0], s0);
        atomicAdd(&line[t * 2 + 1], s1);
    }
}

// ---------------- LSTM: 4 timesteps fused; Wc staged in LDS (XOR-swizzled),
// intra prefetched for all t ----------------
__global__ __launch_bounds__(256) void k_lstm(
    const u16* __restrict__ intra, const float* __restrict__ sspart,
    const u16* __restrict__ Wc_pad, const float* __restrict__ biasv,
    u16* __restrict__ feats)
{
    // B-table in LDS: 512 rows (kc*256+g) x 128B, 16B slots XOR-swizzled by (row&7)
    __shared__ __align__(16) u16 wtab[512][64];    // 64 KB
    __shared__ __align__(16) u16 hl[64][72];       // h state, wave-private 16-row stripes
    __shared__ float betas_s[8];
    const int tid = threadIdx.x, lane = tid & 63, wv = tid >> 6;
    const int col = lane & 15, quad = lane >> 4;
    int m0 = blockIdx.x * 64;
    int row = m0 + wv * 16 + col;
    int row_c = (row < N_) ? row : (N_ - 1);
    int rowbase = m0 + wv * 16 + quad * 4;

    // prefetch all 4 timesteps' intra rows (16 independent 16B loads, one
    // latency exposure instead of serial-per-t)
    bf16x8 pi[4][4];
    #pragma unroll
    for (int t = 0; t < 4; ++t) {
        const u16* ib = intra + ((size_t)t * N_ + row_c) * 128;
        #pragma unroll
        for (int k = 0; k < 4; ++k)
            pi[t][k] = *(const bf16x8*)(ib + k * 32 + quad * 8);
    }

    // stage Wc_pad -> LDS with slot-XOR swizzle (T2): 4096 16B units, conflict-free
    {
        const uint4* src = (const uint4*)Wc_pad;
        #pragma unroll
        for (int it = 0; it < 16; ++it) {
            int u = it * 256 + tid;
            int r = u >> 3, s = u & 7;
            uint4 v = src[u];
            *(uint4*)((char*)&wtab[0][0] + (size_t)r * 128 + ((s ^ (r & 7)) * 16)) = v;
        }
    }
    if (tid < 64) {
        float a8[8];
        #pragma unroll
        for (int s = 0; s < 8; ++s) a8[s] = sspart[tid * 16 + s];
        #pragma unroll
        for (int s = 0; s < 8; ++s) {
            float v = a8[s];
            v += __shfl_xor(v, 1); v += __shfl_xor(v, 2);
            v += __shfl_xor(v, 4); v += __shfl_xor(v, 8);
            v += __shfl_xor(v, 16); v += __shfl_xor(v, 32);
            a8[s] = v;
        }
        if (tid < 4) {
            float s0 = a8[tid * 2] * (1.f / N_), s1 = a8[tid * 2 + 1] * (1.f / N_);
            float mx = fmaxf(s0, s1);
            float e0 = __expf(s0 - mx), e1 = __expf(s1 - mx);
            float inv = 1.f / (e0 + e1);
            betas_s[tid * 2] = e0 * inv; betas_s[tid * 2 + 1] = e1 * inv;
        }
    }
    __syncthreads();
    float betas[8];
    #pragma unroll
    for (int i = 0; i < 8; ++i) betas[i] = betas_s[i];

    float cc[4][4];
    #pragma unroll
    for (int j = 0; j < 4; ++j)
        #pragma unroll
        for (int reg = 0; reg < 4; ++reg) cc[j][reg] = 0.f;

    const int c7 = col & 7;
    #pragma unroll
    for (int t = 0; t < 4; ++t) {
        float b0 = betas[t * 2], b1 = betas[t * 2 + 1];

        f32x4 acc[16];
        #pragma unroll
        for (int cf = 0; cf < 16; ++cf) { acc[cf][0]=0.f; acc[cf][1]=0.f; acc[cf][2]=0.f; acc[cf][3]=0.f; }

        #pragma unroll
        for (int ks = 0; ks < 2; ++ks) {
            bf16x8 i0 = pi[t][ks];
            bf16x8 i1 = pi[t][2 + ks];
            union { u16 h[8]; bf16x8 v; } cv;
            #pragma unroll
            for (int j = 0; j < 8; ++j)
                cv.h[j] = f2bf(b0 * bf2f((u16)i0[j]) + b1 * bf2f((u16)i1[j]));
            #pragma unroll
            for (int cf = 0; cf < 16; ++cf) {
                bf16x8 b = *(const bf16x8*)((const char*)&wtab[0][0]
                    + (size_t)(cf * 16 + col) * 128 + (((ks * 4 + quad) ^ c7) * 16));
                acc[cf] = __builtin_amdgcn_mfma_f32_16x16x32_bf16(cv.v, b, acc[cf], 0, 0, 0);
            }
        }
        if (t > 0) {
            #pragma unroll
            for (int ks = 0; ks < 2; ++ks) {
                bf16x8 a = *(const bf16x8*)&hl[wv * 16 + col][ks * 32 + quad * 8];
                #pragma unroll
                for (int cf = 0; cf < 16; ++cf) {
                    bf16x8 b = *(const bf16x8*)((const char*)&wtab[0][0]
                        + (size_t)(256 + cf * 16 + col) * 128 + (((ks * 4 + quad) ^ c7) * 16));
                    acc[cf] = __builtin_amdgcn_mfma_f32_16x16x32_bf16(a, b, acc[cf], 0, 0, 0);
                }
            }
        }

        #pragma unroll
        for (int j = 0; j < 4; ++j) {
            int c = j * 16 + col;
            float bi = biasv[c], bf_ = biasv[64 + c], bg = biasv[128 + c], bo = biasv[192 + c];
            #pragma unroll
            for (int reg = 0; reg < 4; ++reg) {
                float gi = acc[j][reg] + bi;
                float gf = acc[j + 4][reg] + bf_;
                float gg = acc[j + 8][reg] + bg;
                float go = acc[j + 12][reg] + bo;
                float c2 = sigm(gf) * cc[j][reg] + sigm(gi) * ftanh(gg);
                float hh = sigm(go) * ftanh(c2);
                cc[j][reg] = c2;
                u16 hb = f2bf(hh);
                hl[wv * 16 + quad * 4 + reg][c] = hb;
                int rr = rowbase + reg;
                if (rr < N_)
                    feats[(size_t)rr * 256 + t * 64 + c] = hb;
            }
        }
    }
}

// ---------------- temporal causal MHA: MFMA QKV + per-lane attention ----------------
__global__ __launch_bounds__(256) void k_attn(
    const u16* __restrict__ feats, const float* __restrict__ pos_emb,
    const u16* __restrict__ qkv_pad, float* __restrict__ out)
{
    __shared__ float qkv_s[64 * 200];
    const int tid = threadIdx.x, lane = tid & 63, wv = tid >> 6;
    const int col = lane & 15, quad = lane >> 4;
    int m0 = blockIdx.x * 64;
    int row = m0 + wv * 16 + col;
    int trow = row & 3;

    f32x4 acc[12];
    #pragma unroll
    for (int cf = 0; cf < 12; ++cf) { acc[cf][0]=0.f; acc[cf][1]=0.f; acc[cf][2]=0.f; acc[cf][3]=0.f; }
    #pragma unroll
    for (int ks = 0; ks < 2; ++ks) {
        int coff = ks * 32 + quad * 8;
        bf16x8 fv = *(const bf16x8*)(feats + (size_t)row * 64 + coff);
        float4 p0 = *(const float4*)(pos_emb + trow * 64 + coff);
        float4 p1 = *(const float4*)(pos_emb + trow * 64 + coff + 4);
        union { u16 h[8]; bf16x8 v; } cv;
        cv.h[0] = f2bf(bf2f((u16)fv[0]) + p0.x); cv.h[1] = f2bf(bf2f((u16)fv[1]) + p0.y);
        cv.h[2] = f2bf(bf2f((u16)fv[2]) + p0.z); cv.h[3] = f2bf(bf2f((u16)fv[3]) + p0.w);
        cv.h[4] = f2bf(bf2f((u16)fv[4]) + p1.x); cv.h[5] = f2bf(bf2f((u16)fv[5]) + p1.y);
        cv.h[6] = f2bf(bf2f((u16)fv[6]) + p1.z); cv.h[7] = f2bf(bf2f((u16)fv[7]) + p1.w);
        bf16x8 a = cv.v;
        const u16* bb = qkv_pad + ks * 32 + quad * 8;
        #pragma unroll
        for (int cf = 0; cf < 12; ++cf) {
            bf16x8 b = *(const bf16x8*)(bb + (cf * 16 + col) * 64);
            acc[cf] = __builtin_amdgcn_mfma_f32_16x16x32_bf16(a, b, acc[cf], 0, 0, 0);
        }
    }
    #pragma unroll
    for (int cf = 0; cf < 12; ++cf) {
        int g = cf * 16 + col;
        #pragma unroll
        for (int reg = 0; reg < 4; ++reg) {
            int rl = wv * 16 + quad * 4 + reg;
            qkv_s[rl * 200 + g] = acc[cf][reg];
        }
    }
    __syncthreads();

    int nl = wv * 4 + (lane >> 4);
    int sub = lane & 15;
    int h = sub >> 2, tq = sub & 3;
    const float* qrow = qkv_s + (nl * 4 + tq) * 200 + h * 16;

    float s[4];
    #pragma unroll
    for (int tk = 0; tk < 4; ++tk) {
        const float* krow = qkv_s + (nl * 4 + tk) * 200 + 64 + h * 16;
        float d = 0.f;
        #pragma unroll
        for (int j = 0; j < 16; ++j) d += qrow[j] * krow[j];
        s[tk] = (tk > tq) ? -4294967295.0f : d * 0.5f;
    }
    float mx = fmaxf(fmaxf(s[0], s[1]), fmaxf(s[2], s[3]));
    float a0 = __expf(s[0]-mx), a1 = __expf(s[1]-mx), a2 = __expf(s[2]-mx), a3 = __expf(s[3]-mx);
    float inv = 1.f / (a0 + a1 + a2 + a3);
    a0 *= inv; a1 *= inv; a2 *= inv; a3 *= inv;

    int n = blockIdx.x * 16 + nl;
    const float* v0 = qkv_s + (nl * 4 + 0) * 200 + 128 + h * 16;
    const float* v1 = v0 + 200, *v2 = v0 + 400, *v3 = v0 + 600;
    #pragma unroll
    for (int cc4 = 0; cc4 < 4; ++cc4) {
        float4 o;
        o.x = a0*v0[cc4*4+0] + a1*v1[cc4*4+0] + a2*v2[cc4*4+0] + a3*v3[cc4*4+0];
        o.y = a0*v0[cc4*4+1] + a1*v1[cc4*4+1] + a2*v2[cc4*4+1] + a3*v3[cc4*4+1];
        o.z = a0*v0[cc4*4+2] + a1*v1[cc4*4+2] + a2*v2[cc4*4+2] + a3*v3[cc4*4+2];
        o.w = a0*v0[cc4*4+3] + a1*v1[cc4*4+3] + a2*v2[cc4*4+3] + a3*v3[cc4*4+3];
        *(float4*)(out + (size_t)n * 256 + tq * 64 + h * 16 + cc4 * 4) = o;
    }
}

// ---------------- launcher ----------------
extern "C" void kernel_launch(void* const* d_in, const int* in_sizes, int n_in,
                              void* d_out, int out_size, void* d_ws, size_t ws_size,
                              hipStream_t stream) {
    const float* x     = (const float*)d_in[0];
    const int* ei      = (const int*)d_in[1];
    const float* Wsrc  = (const float*)d_in[2];
    const float* Wdst  = (const float*)d_in[3];
    const float* att_src = (const float*)d_in[4];
    const float* att_dst = (const float*)d_in[5];
    const float* raW1  = (const float*)d_in[6];
    const float* rab1  = (const float*)d_in[7];
    const float* raW2  = (const float*)d_in[8];
    const float* Wih   = (const float*)d_in[9];
    const float* Whh   = (const float*)d_in[10];
    const float* bih   = (const float*)d_in[11];
    const float* bhh   = (const float*)d_in[12];
    const float* pos   = (const float*)d_in[13];
    const float* Wq    = (const float*)d_in[14];
    const float* Wk    = (const float*)d_in[15];
    const float* Wv    = (const float*)d_in[16];
    float* out = (float*)d_out;

    char* w = (char*)d_ws;
    size_t off = 0;
    auto alloc = [&](size_t bytes) -> char* {
        char* pp = w + off; off += (bytes + 255) & ~(size_t)255; return pp;
    };
    // ---- long-lived ----
    u16*   intra     = (u16*)  alloc((size_t)T_ * N_ * R_ * 64 * 2);  // 20.48 MB
    u16*   x_h       = (u16*)  alloc((size_t)T_ * N_ * 64 * 2);       // 10.24 MB (f16)
    float* sspart    = (float*)alloc(1024 * 4);   // 64 lines x 16 floats
    float* wdall     = (float*)alloc(1024 * 4);
    float* biasv     = (float*)alloc(256 * 4);
    u16*   raW1_pad  = (u16*)  alloc(BPAD * 2);
    u16*   Wc_pad    = (u16*)  alloc(2 * BPAD * 2);
    u16*   qkv_pad   = (u16*)  alloc(192 * 64 * 2);
    u16*   postB_pad = (u16*)  alloc(2 * 4 * 4096 * 2);
    int*   chunktot  = (int*)  alloc(P_ * NB_ * 4);
    // ---- union region ----
    char*  ubase   = alloc(0);
    size_t uoff = 0;
    auto ualloc = [&](size_t bytes) -> char* {
        char* pp = ubase + uoff; uoff += (bytes + 255) & ~(size_t)255; return pp;
    };
    int*   offsets = (int*)  ualloc((size_t)P_ * (N_ + 1) * 4);
    u16*   csr     = (u16*)  ualloc((size_t)P_ * E_ * 2);
    float* als_all = (float*)ualloc((size_t)P_ * N_ * 4 * 4);
    float* ald_all = (float*)ualloc((size_t)P_ * N_ * 4 * 4);
    u16*   partial = (u16*)  ualloc((size_t)P_ * NB_ * N_ * 2);
    u16*   rank    = (u16*)  ualloc((size_t)P_ * E_ * 2);
    // phase 2 overlay (phase-1 sub-buffers dead after k_agg)
    u16*   feats   = (u16*)  ubase;   // 10.24 MB
    (void)ws_size; (void)in_sizes; (void)n_in; (void)out_size;

    k_prep<<<72, 256, 0, stream>>>(Wdst, att_dst, Wih, Whh, bih, bhh, Wsrc, att_src, raW1,
                                   Wq, Wk, Wv, wdall, biasv, raW1_pad, Wc_pad, qkv_pad,
                                   postB_pad, sspart);
    k_hist<<<dim3(NB_, 8), 256, 0, stream>>>(ei, rank, partial);
    k_scan1<<<dim3(NB_, 8), 256, 0, stream>>>(partial, offsets, chunktot);
    k_scan3<<<dim3(79, 8), 256, 0, stream>>>(offsets, chunktot);
    k_scatter<<<10000, 256, 0, stream>>>(ei, offsets, rank, partial, csr);
    k_fold<<<dim3(313, 4), 256, 0, stream>>>(x, wdall, als_all, ald_all, x_h);
    k_agg<<<10000, 256, 0, stream>>>(offsets, csr, als_all, ald_all, x_h, postB_pad, intra);
    k_relagg<<<2500, 256, 0, stream>>>(intra, raW1_pad, rab1, raW2, sspart);
    k_lstm<<<313, 256, 0, stream>>>(intra, sspart, Wc_pad, biasv, feats);
    k_attn<<<1250, 256, 0, stream>>>(feats, pos, qkv_pad, out);
}

// Round 11
// 389.540 us; speedup vs baseline: 1.2802x; 1.0216x over previous
//
#include <hip/hip_runtime.h>
#include <hip/hip_bf16.h>

#define T_ 4
#define N_ 20000
#define E_ 320000
#define R_ 2
#define DIN 64
#define G_ 256   // H*Dh
#define P_ 8     // T*R
#define BPAD 16384  // 256 * 64 dense B-table halves per 64-k chunk (global loads: no pad)
#define NB_ 32      // CSR-build blocks per p
#define EPB_ 10000  // edges per CSR-build block
#define CHN_ 625    // nodes per scan chunk (N_/32)

typedef unsigned short u16;
typedef __attribute__((ext_vector_type(8))) short bf16x8;
typedef __attribute__((ext_vector_type(2))) _Float16 h2;
typedef __attribute__((ext_vector_type(4))) float f32x4;

__device__ __forceinline__ float bf2f(u16 u) {
    unsigned int i = ((unsigned int)u) << 16; float f;
    __builtin_memcpy(&f, &i, 4); return f;
}
__device__ __forceinline__ u16 f2bf(float f) {
    unsigned int i; __builtin_memcpy(&i, &f, 4);
    unsigned int r = i + 0x7fffu + ((i >> 16) & 1u);
    return (u16)(r >> 16);
}
__device__ __forceinline__ u16 f2h(float f) {
    union { _Float16 h; u16 u; } c; c.h = (_Float16)f; return c.u;
}
__device__ __forceinline__ float sigm(float x) { return 1.f / (1.f + __expf(-x)); }
// fast tanh: 1 - 2/(exp(2x)+1); hardware v_exp_f32, correct saturation at +-inf
__device__ __forceinline__ float ftanh(float x) { return 1.f - 2.f / (__expf(2.f * x) + 1.f); }
// broadcast lane l's float to all lanes (SGPR result); l must be wave-uniform
__device__ __forceinline__ float rdlanef(float v, int l) {
    int i; __builtin_memcpy(&i, &v, 4);
    int r = __builtin_amdgcn_readlane(i, l);
    float f; __builtin_memcpy(&f, &r, 4); return f;
}
// v_dot2_f32_f16: a.x*b.x + a.y*b.y + c in one VALU op
__device__ __forceinline__ float fdot2(h2 a, h2 b, float c) {
#if __has_builtin(__builtin_amdgcn_fdot2)
    return __builtin_amdgcn_fdot2(a, b, c, false);
#else
    float r;
    asm("v_dot2_f32_f16 %0, %1, %2, %3" : "=v"(r) : "v"(a), "v"(b), "v"(c));
    return r;
#endif
}
// pack 2 f32 -> 2 bf16 (RNE) in one VALU op
__device__ __forceinline__ unsigned cvtpk_bf16(float lo, float hi) {
    unsigned r;
    asm("v_cvt_pk_bf16_f32 %0, %1, %2" : "=v"(r) : "v"(lo), "v"(hi));
    return r;
}

// ---------------- LDS-free MFMA GEMM core (bf16 A, dense B stride 64) ----------------
__device__ __forceinline__ void gemm_direct(
    const u16* __restrict__ A, const u16* __restrict__ Bpad,
    int M, int Astride, int kchunks, int m0, f32x4* acc)
{
    const int tid = threadIdx.x;
    const int lane = tid & 63, wv = tid >> 6;
    const int col = lane & 15, quad = lane >> 4;
    #pragma unroll
    for (int cf = 0; cf < 16; ++cf) { acc[cf][0]=0.f; acc[cf][1]=0.f; acc[cf][2]=0.f; acc[cf][3]=0.f; }

    int row = m0 + wv * 16 + col;
    int row_c = (row < M) ? row : (M - 1);

    for (int kc = 0; kc < kchunks; ++kc) {
        #pragma unroll
        for (int ks = 0; ks < 2; ++ks) {
            bf16x8 a = *(const bf16x8*)(A + (size_t)row_c * Astride + kc * 64 + ks * 32 + quad * 8);
            const u16* bb = Bpad + kc * BPAD + ks * 32 + quad * 8;
            #pragma unroll
            for (int cf = 0; cf < 16; ++cf) {
                bf16x8 b = *(const bf16x8*)(bb + (cf * 16 + col) * 64);
                acc[cf] = __builtin_amdgcn_mfma_f32_16x16x32_bf16(a, b, acc[cf], 0, 0, 0);
            }
        }
    }
}

// ---------------- fold: als/ald GEMVs + x->f16 cast; wdall staged in LDS ----------------
__global__ __launch_bounds__(256) void k_fold(
    const float* __restrict__ x, const float* __restrict__ wdall,
    float* __restrict__ als_all, float* __restrict__ ald_all, u16* __restrict__ x_h)
{
    __shared__ float wds[1024];
    {
        int tid = threadIdx.x;
        *(float4*)(wds + tid * 4) = *(const float4*)(wdall + tid * 4);
    }
    __syncthreads();

    int t = blockIdx.y;
    int idx = blockIdx.x * 256 + threadIdx.x;
    if (idx >= N_ * 4) return;
    int n = idx >> 2, q = idx & 3;
    const float* xr = x + ((size_t)t * N_ + n) * 64 + q * 16;
    float4 xv[4];
    #pragma unroll
    for (int i = 0; i < 4; ++i) xv[i] = *(const float4*)(xr + i * 4);

    {
        union { u16 h[16]; ushort4 s4[4]; } cv;
        #pragma unroll
        for (int i = 0; i < 4; ++i) {
            cv.h[i*4+0] = f2h(xv[i].x); cv.h[i*4+1] = f2h(xv[i].y);
            cv.h[i*4+2] = f2h(xv[i].z); cv.h[i*4+3] = f2h(xv[i].w);
        }
        u16* xo = x_h + ((size_t)t * N_ + n) * 64 + q * 16;
        #pragma unroll
        for (int i = 0; i < 4; ++i) *(ushort4*)(xo + i * 4) = cv.s4[i];
    }

    float s[16];
    #pragma unroll
    for (int i = 0; i < 16; ++i) s[i] = 0.f;
    #pragma unroll
    for (int i = 0; i < 4; ++i) {
        float xe[4] = {xv[i].x, xv[i].y, xv[i].z, xv[i].w};
        #pragma unroll
        for (int e = 0; e < 4; ++e) {
            int k = q * 16 + i * 4 + e;
            float xk = xe[e];
            #pragma unroll
            for (int tb = 0; tb < 4; ++tb) {
                float4 w = *(const float4*)(wds + tb * 256 + k * 4);
                s[tb*4+0] += xk * w.x; s[tb*4+1] += xk * w.y;
                s[tb*4+2] += xk * w.z; s[tb*4+3] += xk * w.w;
            }
        }
    }
    #pragma unroll
    for (int i = 0; i < 16; ++i) {
        s[i] += __shfl_xor(s[i], 1);
        s[i] += __shfl_xor(s[i], 2);
    }
    if (q == 0) {
        *(float4*)(als_all + ((size_t)(t*2+0) * N_ + n) * 4) = make_float4(s[0], s[1], s[2], s[3]);
        *(float4*)(als_all + ((size_t)(t*2+1) * N_ + n) * 4) = make_float4(s[4], s[5], s[6], s[7]);
        *(float4*)(ald_all + ((size_t)(t*2+0) * N_ + n) * 4) = make_float4(s[8], s[9], s[10], s[11]);
        *(float4*)(ald_all + ((size_t)(t*2+1) * N_ + n) * 4) = make_float4(s[12], s[13], s[14], s[15]);
    }
}

// ---------------- prep: folded GEMV tables, dense B-tables, folded bias ----------------
__global__ void k_prep(const float* __restrict__ Wdst, const float* __restrict__ att_dst,
                       const float* __restrict__ Wih, const float* __restrict__ Whh,
                       const float* __restrict__ bih, const float* __restrict__ bhh,
                       const float* __restrict__ Wsrc, const float* __restrict__ att_src,
                       const float* __restrict__ raW1,
                       const float* __restrict__ Wq, const float* __restrict__ Wk,
                       const float* __restrict__ Wv,
                       float* __restrict__ wdall, float* __restrict__ biasv,
                       u16* __restrict__ raW1_pad, u16* __restrict__ Wc_pad,
                       u16* __restrict__ qkv_pad, u16* __restrict__ postB_pad,
                       float* __restrict__ sspart)
{
    int tid = threadIdx.x, bid = blockIdx.x;
    if (bid == 0) {
        for (int i = tid; i < 1024; i += 256) sspart[i] = 0.f;
        int k = tid >> 2, h = tid & 3;
        for (int r = 0; r < 2; ++r) {
            float ss = 0.f, sd = 0.f;
            for (int c = 0; c < 64; ++c) {
                ss += Wsrc[((size_t)r * 64 + k) * 256 + h * 64 + c] * att_src[r * 256 + h * 64 + c];
                sd += Wdst[((size_t)r * 64 + k) * 256 + h * 64 + c] * att_dst[r * 256 + h * 64 + c];
            }
            wdall[r * 256 + k * 4 + h] = ss;
            wdall[512 + r * 256 + k * 4 + h] = sd;
        }
        biasv[tid] = bih[tid] + bhh[tid];
    }
    for (int i = bid * 256 + tid; i < BPAD; i += gridDim.x * 256) {
        int n = i >> 6, kk = i & 63;
        raW1_pad[i] = f2bf(raW1[kk * 256 + n]);
    }
    for (int i = bid * 256 + tid; i < 2 * BPAD; i += gridDim.x * 256) {
        int kc = i >> 14, q = i & (BPAD - 1), n = q >> 6, kk = q & 63;
        const float* W = kc ? Whh : Wih;
        Wc_pad[i] = f2bf(W[n * 64 + kk]);
    }
    for (int i = bid * 256 + tid; i < 192 * 64; i += gridDim.x * 256) {
        int g = i >> 6, kk = i & 63;
        int j = g >> 6, c = g & 63;
        const float* W = (j == 0) ? Wq : (j == 1) ? Wk : Wv;
        qkv_pad[i] = f2bf(W[kk * 64 + c]);
    }
    // K-permuted post-projection table: xagg K index K' = d*4 + h (d = input dim,
    // h = head), matching k_agg's packed epilogue. B~[g][K'] = Wsrc[d][h*64+g].
    for (int i = bid * 256 + tid; i < 2 * 4 * 4096; i += gridDim.x * 256) {
        int r = i >> 14, q = i & 16383, kc = q >> 12, qq = q & 4095;
        int c = qq >> 6, kk = qq & 63;
        int d = kc * 16 + (kk >> 2), h = kk & 3;
        postB_pad[i] = f2bf(Wsrc[(size_t)r * 16384 + d * 256 + h * 64 + c]);
    }
}

// ---------------- CSR build ----------------
__global__ __launch_bounds__(256) void k_hist(const int* __restrict__ ei,
                                              u16* __restrict__ rank, u16* __restrict__ partial)
{
    __shared__ unsigned int hist[N_ / 2];
    int b = blockIdx.x, p = blockIdx.y, tid = threadIdx.x;
    for (int i = tid; i < N_ / 2; i += 256) hist[i] = 0u;
    __syncthreads();
    const int* dsts = ei + ((size_t)p * 2 + 1) * E_ + b * EPB_;
    u16* rk = rank + (size_t)p * E_ + b * EPB_;
    for (int e = tid; e < EPB_; e += 256) {
        int dst = dsts[e];
        unsigned sh = (unsigned)(dst & 1) * 16u;
        unsigned old = atomicAdd(&hist[dst >> 1], 1u << sh);
        rk[e] = (u16)((old >> sh) & 0xffffu);
    }
    __syncthreads();
    u16* part = partial + ((size_t)p * NB_ + b) * N_;
    for (int n = tid; n < N_; n += 256) {
        unsigned hv = hist[n >> 1];
        part[n] = (u16)((hv >> ((unsigned)(n & 1) * 16u)) & 0xffffu);
    }
}

__global__ __launch_bounds__(256) void k_scan1(u16* __restrict__ partial,
                                               int* __restrict__ offsets, int* __restrict__ chunktot)
{
    int p = blockIdx.y, ch = blockIdx.x;
    int tid = threadIdx.x, lane = tid & 63, wid = tid >> 6;
    __shared__ int wtot[4];
    u16* part = partial + (size_t)p * NB_ * N_;
    int* ofs = offsets + (size_t)p * (N_ + 1);
    int n0 = ch * CHN_;
    int carry = 0;
    for (int rnd = 0; rnd < 3; ++rnd) {
        int i = rnd * 256 + tid;
        int n = n0 + i;
        int v = 0;
        if (i < CHN_) {
            int run = 0;
            #pragma unroll 8
            for (int b = 0; b < NB_; ++b) {
                int pv = part[b * N_ + n];
                part[b * N_ + n] = (u16)run;
                run += pv;
            }
            v = run;
        }
        int incl = v;
        for (int d = 1; d < 64; d <<= 1) { int u = __shfl_up(incl, d); if (lane >= d) incl += u; }
        if (lane == 63) wtot[wid] = incl;
        __syncthreads();
        if (tid < 4) {
            int iv = wtot[tid];
            for (int d = 1; d < 4; d <<= 1) { int u = __shfl_up(iv, d); if (tid >= d) iv += u; }
            wtot[tid] = iv;
        }
        __syncthreads();
        int woff = (wid > 0) ? wtot[wid - 1] : 0;
        int tot = wtot[3];
        int excl = carry + woff + incl - v;
        if (i < CHN_) ofs[n] = excl;
        carry += tot;
        __syncthreads();
    }
    if (tid == 0) chunktot[p * NB_ + ch] = carry;
}

// scan3 also does scan2's 32-element prefix locally
__global__ void k_scan3(int* __restrict__ offsets, const int* __restrict__ chunktot) {
    __shared__ int cb[NB_];
    int p = blockIdx.y;
    int tid = threadIdx.x;
    if (tid < 64) {
        int v = (tid < NB_) ? chunktot[p * NB_ + tid] : 0;
        #pragma unroll
        for (int d = 1; d < NB_; d <<= 1) { int u = __shfl_up(v, d); if (tid >= d) v += u; }
        if (tid < NB_) cb[tid] = v;   // inclusive prefix
    }
    __syncthreads();
    int n = blockIdx.x * 256 + tid;
    if (n < N_) {
        int c = n / CHN_;
        int base = (c > 0) ? cb[c - 1] : 0;
        offsets[(size_t)p * (N_ + 1) + n] += base;
    }
    if (n == 0)
        offsets[(size_t)p * (N_ + 1) + N_] = E_;
}

// 1-D grid, p = bid & 7: round-robin dispatch pins each p to one XCD, so the
// random 2B csr writes (640 KB/p) stay in that XCD's L2 (kills the 8x write amp).
__global__ void k_scatter(const int* __restrict__ ei, const int* __restrict__ offsets,
                          const u16* __restrict__ rank, const u16* __restrict__ partial,
                          u16* __restrict__ csr) {
    int bid = blockIdx.x;
    int p = bid & 7;
    int e = (bid >> 3) * 256 + threadIdx.x;
    int src = ei[((size_t)p * 2 + 0) * E_ + e];
    int dst = ei[((size_t)p * 2 + 1) * E_ + e];
    int b = e / EPB_;
    int pos = offsets[p * (N_ + 1) + dst]
            + (int)partial[((size_t)p * NB_ + b) * N_ + dst]
            + (int)rank[(size_t)p * E_ + e];
    csr[(size_t)p * E_ + pos] = (u16)src;
}

// ---------------- GAT aggregation + fused post-projection ----------------
// Phase 1 (per wave, 4 nodes): software-pipelined — round rr+1's p-phase (srcs
// load, als gather, exps -> double-buffered ptab) is issued BEFORE round rr's
// x-phase, so both L2 hops hide under the dot2 work (per-lane summation order
// unchanged: rounds still accumulate sequentially). Single guarded x-phase body
// (r10's duplicated fast path bloated codegen). Phase 2 (per block, one barrier):
// D[16x64] = xs @ postB[rel] via 8 MFMAs per wave, direct intra store.
__global__ __launch_bounds__(256, 6) void k_agg(
    const int* __restrict__ offsets, const u16* __restrict__ csr,
    const float* __restrict__ als_all, const float* __restrict__ ald_all,
    const u16* __restrict__ x_h, const u16* __restrict__ postB_pad,
    u16* __restrict__ intra)
{
    // ptab[wv][buf][g*64 + pair*8 + h*2 + (el&1)]  (double-buffered for pipeline)
    __shared__ __align__(16) u16 ptab[4][2][256];
    __shared__ __align__(16) u16 xs[16 * 256];   // 8 KB block tile, swizzled
    const int bid = blockIdx.x;
    const int p = bid & 7;
    const int t = p >> 1, rel = p & 1;
    const int* off   = offsets + (size_t)p * (N_ + 1);
    const u16* srcs  = csr + (size_t)p * E_;
    const float* als = als_all + (size_t)p * N_ * 4;
    const float* ald = ald_all + (size_t)p * N_ * 4;
    const u16* xb    = x_h + (size_t)t * N_ * 64;

    const int tid = threadIdx.x, lane = tid & 63, wv = tid >> 6;
    const int g = lane >> 4, el = lane & 15;
    const int nb0 = (bid >> 3) * 16;           // block's 16 nodes
    const int n0 = nb0 + wv * 4;               // wave's 4 nodes
    const int ng = n0 + g;
    const int o0 = off[ng], o1 = off[ng + 1];
    const int deg = o1 - o0;
    const float4 aldv = *(const float4*)(ald + (size_t)ng * 4);
    const int pw = g * 64 + (el >> 1) * 8 + (el & 1);

    int sdeg[4];
    #pragma unroll
    for (int q = 0; q < 4; ++q) sdeg[q] = __builtin_amdgcn_readlane(deg, q * 16);
    int mdeg = max(max(sdeg[0], sdeg[1]), max(sdeg[2], sdeg[3]));
    int nrounds = (mdeg + 15) >> 4;

    float acc[4][4];
    #pragma unroll
    for (int q = 0; q < 4; ++q)
        #pragma unroll
        for (int h = 0; h < 4; ++h) acc[q][h] = 0.f;
    float d0 = 0.f, d1 = 0.f, d2 = 0.f, d3 = 0.f;

    // p-phase for round rr -> ptab[wv][buf]; returns this lane's src index
    auto pphase = [&](int rr, int buf) -> int {
        int e = rr * 16 + el;
        int sv = 0;
        float p0 = 0.f, p1 = 0.f, p2 = 0.f, p3 = 0.f;
        if (e < deg) {
            sv = (int)srcs[o0 + e];
            float4 av = *(const float4*)(als + (size_t)sv * 4);
            float e0 = av.x + aldv.x, e1 = av.y + aldv.y;
            float e2 = av.z + aldv.z, e3 = av.w + aldv.w;
            e0 = fmaxf(e0, 0.2f * e0); e1 = fmaxf(e1, 0.2f * e1);
            e2 = fmaxf(e2, 0.2f * e2); e3 = fmaxf(e3, 0.2f * e3);
            p0 = __expf(e0); p1 = __expf(e1); p2 = __expf(e2); p3 = __expf(e3);
        }
        d0 += p0; d1 += p1; d2 += p2; d3 += p3;
        u16* pt = &ptab[wv][buf][0];
        pt[pw + 0] = f2h(p0); pt[pw + 2] = f2h(p1);
        pt[pw + 4] = f2h(p2); pt[pw + 6] = f2h(p3);
        return sv;
    };

    int cur = 0;
    int sv_cur = (nrounds > 0) ? pphase(0, 0) : 0;
    for (int rr = 0; rr < nrounds; ++rr) {
        // pipeline: issue next round's p-phase before this round's x-phase
        int sv_nxt = 0;
        if (rr + 1 < nrounds) sv_nxt = pphase(rr + 1, cur ^ 1);
        const u16* ptb = &ptab[wv][cur][0];
        // x-phase: in-order DS within the wave -> ptab[cur] (written last iter
        // or prologue) is visible without a barrier
        #pragma unroll
        for (int q = 0; q < 4; ++q) {
            int rem = sdeg[q] - rr * 16;   // scalar -> uniform branches
            if (rem > 0) {
                const u16* ptq = ptb + q * 64;
                unsigned xl0[8], xl1[8];
                #pragma unroll
                for (int pr = 0; pr < 8; ++pr) {
                    if (pr * 2 < rem) {
                        int s0i = __builtin_amdgcn_readlane(sv_cur, q * 16 + pr * 2);
                        int s1i = __builtin_amdgcn_readlane(sv_cur, q * 16 + pr * 2 + 1);
                        xl0[pr] = xb[((size_t)(unsigned)s0i << 6) + lane];
                        xl1[pr] = xb[((size_t)(unsigned)s1i << 6) + lane];
                    }
                }
                #pragma unroll
                for (int pr = 0; pr < 8; ++pr) {
                    if (pr * 2 < rem) {
                        unsigned xp = xl0[pr] | (xl1[pr] << 16);
                        uint4 ppv = *(const uint4*)(ptq + pr * 8);
                        h2 xv, q0, q1, q2, q3;
                        __builtin_memcpy(&xv, &xp, 4);
                        __builtin_memcpy(&q0, &ppv.x, 4);
                        __builtin_memcpy(&q1, &ppv.y, 4);
                        __builtin_memcpy(&q2, &ppv.z, 4);
                        __builtin_memcpy(&q3, &ppv.w, 4);
                        acc[q][0] = fdot2(xv, q0, acc[q][0]);
                        acc[q][1] = fdot2(xv, q1, acc[q][1]);
                        acc[q][2] = fdot2(xv, q2, acc[q][2]);
                        acc[q][3] = fdot2(xv, q3, acc[q][3]);
                    }
                }
            }
        }
        sv_cur = sv_nxt;
        cur ^= 1;
    }
    // den reduce within each 16-lane group (xor masks < 16 stay in-group)
    d0 += __shfl_xor(d0, 1); d0 += __shfl_xor(d0, 2);
    d0 += __shfl_xor(d0, 4); d0 += __shfl_xor(d0, 8);
    d1 += __shfl_xor(d1, 1); d1 += __shfl_xor(d1, 2);
    d1 += __shfl_xor(d1, 4); d1 += __shfl_xor(d1, 8);
    d2 += __shfl_xor(d2, 1); d2 += __shfl_xor(d2, 2);
    d2 += __shfl_xor(d2, 4); d2 += __shfl_xor(d2, 8);
    d3 += __shfl_xor(d3, 1); d3 += __shfl_xor(d3, 2);
    d3 += __shfl_xor(d3, 4); d3 += __shfl_xor(d3, 8);
    float inv0 = 0.25f / (d0 + 1e-16f);
    float inv1 = 0.25f / (d1 + 1e-16f);
    float inv2 = 0.25f / (d2 + 1e-16f);
    float inv3 = 0.25f / (d3 + 1e-16f);
    #pragma unroll
    for (int q = 0; q < 4; ++q) {
        float s0 = rdlanef(inv0, q * 16);
        float s1 = rdlanef(inv1, q * 16);
        float s2 = rdlanef(inv2, q * 16);
        float s3 = rdlanef(inv3, q * 16);
        // K' = d*4 + h packing; store to swizzled LDS tile row (wv*4+q)
        unsigned w01 = cvtpk_bf16(acc[q][0] * s0, acc[q][1] * s1);
        unsigned w23 = cvtpk_bf16(acc[q][2] * s2, acc[q][3] * s3);
        int rowt = wv * 4 + q;
        char* dst = (char*)xs + rowt * 512 + (((lane >> 1) ^ (rowt & 7)) * 16) + (lane & 1) * 8;
        *(uint2*)dst = make_uint2(w01, w23);
    }
    __syncthreads();

    // ---- fused post-projection: D[16 nodes][64] = xs(16x256) @ postB[rel](256x64) ----
    {
        const int col = lane & 15, quad = lane >> 4;
        const u16* Bp = postB_pad + (size_t)rel * 4 * 4096;
        f32x4 pacc;
        pacc[0] = 0.f; pacc[1] = 0.f; pacc[2] = 0.f; pacc[3] = 0.f;
        #pragma unroll
        for (int kc = 0; kc < 4; ++kc) {
            #pragma unroll
            for (int ks = 0; ks < 2; ++ks) {
                int slot = kc * 8 + ks * 4 + quad;
                bf16x8 a = *(const bf16x8*)((const char*)xs + col * 512 + ((slot ^ (col & 7)) * 16));
                bf16x8 b = *(const bf16x8*)(Bp + (size_t)kc * 4096 + (wv * 16 + col) * 64 + ks * 32 + quad * 8);
                pacc = __builtin_amdgcn_mfma_f32_16x16x32_bf16(a, b, pacc, 0, 0, 0);
            }
        }
        #pragma unroll
        for (int reg = 0; reg < 4; ++reg) {
            int node = nb0 + quad * 4 + reg;
            intra[(((size_t)t * N_ + node) * 2 + rel) * 64 + wv * 16 + col] = f2bf(pacc[reg]);
        }
    }
}

// ---------------- RelationAgg GEMM + fused ftanh(.)@W2 epilogue; partials spread
// over 64 cache lines (same-line atomic serialization was a hidden 2x regression) --------
__global__ __launch_bounds__(256) void k_relagg(
    const u16* __restrict__ A, const u16* __restrict__ W1pad, const float* __restrict__ b1,
    const float* __restrict__ W2, float* __restrict__ sspart)
{
    int m0 = blockIdx.x * 64;
    f32x4 acc[16];
    gemm_direct(A, W1pad, T_ * N_ * R_, 64, 1, m0, acc);

    const int tid = threadIdx.x, lane = tid & 63, wv = tid >> 6;
    const int col = lane & 15;
    float sp[4] = {0.f, 0.f, 0.f, 0.f};
    #pragma unroll
    for (int cf = 0; cf < 16; ++cf) {
        int gcol = cf * 16 + col;
        float bb = b1[gcol];
        float ww = W2[gcol];
        #pragma unroll
        for (int reg = 0; reg < 4; ++reg)
            sp[reg] += ftanh(acc[cf][reg] + bb) * ww;
    }
    #pragma unroll
    for (int reg = 0; reg < 4; ++reg) {
        float v = sp[reg];
        v += __shfl_xor(v, 1); v += __shfl_xor(v, 2);
        v += __shfl_xor(v, 4); v += __shfl_xor(v, 8);
        sp[reg] = v;
    }
    // rows = m0 + wv*16 + quad*4 + reg ; rowbase is even so reg parity == r
    float se = sp[0] + sp[2];   // r = 0 rows of this lane's quad
    float so = sp[1] + sp[3];   // r = 1 rows
    se += __shfl_xor(se, 16); se += __shfl_xor(se, 32);
    so += __shfl_xor(so, 16); so += __shfl_xor(so, 32);
    __shared__ float red[8];
    if (lane == 0) { red[wv * 2] = se; red[wv * 2 + 1] = so; }
    __syncthreads();
    if (tid == 0) {
        float s0 = red[0] + red[2] + red[4] + red[6];
        float s1 = red[1] + red[3] + red[5] + red[7];
        int t = m0 / (N_ * R_);
        float* line = sspart + (blockIdx.x & 63) * 16;   // 64 distinct 64B lines
        atomicAdd(&line[t * 2 + 0], s0);
        atomicAdd(&line[t * 2 + 1], s1);
    }
}

// ---------------- LSTM: 4 timesteps fused; Wc staged in LDS (XOR-swizzled),
// intra prefetched for all t ----------------
__global__ __launch_bounds__(256) void k_lstm(
    const u16* __restrict__ intra, const float* __restrict__ sspart,
    const u16* __restrict__ Wc_pad, const float* __restrict__ biasv,
    u16* __restrict__ feats)
{
    // B-table in LDS: 512 rows (kc*256+g) x 128B, 16B slots XOR-swizzled by (row&7)
    __shared__ __align__(16) u16 wtab[512][64];    // 64 KB
    __shared__ __align__(16) u16 hl[64][72];       // h state, wave-private 16-row stripes
    __shared__ float betas_s[8];
    const int tid = threadIdx.x, lane = tid & 63, wv = tid >> 6;
    const int col = lane & 15, quad = lane >> 4;
    int m0 = blockIdx.x * 64;
    int row = m0 + wv * 16 + col;
    int row_c = (row < N_) ? row : (N_ - 1);
    int rowbase = m0 + wv * 16 + quad * 4;

    // prefetch all 4 timesteps' intra rows (16 independent 16B loads, one
    // latency exposure instead of serial-per-t)
    bf16x8 pi[4][4];
    #pragma unroll
    for (int t = 0; t < 4; ++t) {
        const u16* ib = intra + ((size_t)t * N_ + row_c) * 128;
        #pragma unroll
        for (int k = 0; k < 4; ++k)
            pi[t][k] = *(const bf16x8*)(ib + k * 32 + quad * 8);
    }

    // stage Wc_pad -> LDS with slot-XOR swizzle (T2): 4096 16B units, conflict-free
    {
        const uint4* src = (const uint4*)Wc_pad;
        #pragma unroll
        for (int it = 0; it < 16; ++it) {
            int u = it * 256 + tid;
            int r = u >> 3, s = u & 7;
            uint4 v = src[u];
            *(uint4*)((char*)&wtab[0][0] + (size_t)r * 128 + ((s ^ (r & 7)) * 16)) = v;
        }
    }
    if (tid < 64) {
        float a8[8];
        #pragma unroll
        for (int s = 0; s < 8; ++s) a8[s] = sspart[tid * 16 + s];
        #pragma unroll
        for (int s = 0; s < 8; ++s) {
            float v = a8[s];
            v += __shfl_xor(v, 1); v += __shfl_xor(v, 2);
            v += __shfl_xor(v, 4); v += __shfl_xor(v, 8);
            v += __shfl_xor(v, 16); v += __shfl_xor(v, 32);
            a8[s] = v;
        }
        if (tid < 4) {
            float s0 = a8[tid * 2] * (1.f / N_), s1 = a8[tid * 2 + 1] * (1.f / N_);
            float mx = fmaxf(s0, s1);
            float e0 = __expf(s0 - mx), e1 = __expf(s1 - mx);
            float inv = 1.f / (e0 + e1);
            betas_s[tid * 2] = e0 * inv; betas_s[tid * 2 + 1] = e1 * inv;
        }
    }
    __syncthreads();
    float betas[8];
    #pragma unroll
    for (int i = 0; i < 8; ++i) betas[i] = betas_s[i];

    float cc[4][4];
    #pragma unroll
    for (int j = 0; j < 4; ++j)
        #pragma unroll
        for (int reg = 0; reg < 4; ++reg) cc[j][reg] = 0.f;

    const int c7 = col & 7;
    #pragma unroll
    for (int t = 0; t < 4; ++t) {
        float b0 = betas[t * 2], b1 = betas[t * 2 + 1];

        f32x4 acc[16];
        #pragma unroll
        for (int cf = 0; cf < 16; ++cf) { acc[cf][0]=0.f; acc[cf][1]=0.f; acc[cf][2]=0.f; acc[cf][3]=0.f; }

        #pragma unroll
        for (int ks = 0; ks < 2; ++ks) {
            bf16x8 i0 = pi[t][ks];
            bf16x8 i1 = pi[t][2 + ks];
            union { u16 h[8]; bf16x8 v; } cv;
            #pragma unroll
            for (int j = 0; j < 8; ++j)
                cv.h[j] = f2bf(b0 * bf2f((u16)i0[j]) + b1 * bf2f((u16)i1[j]));
            #pragma unroll
            for (int cf = 0; cf < 16; ++cf) {
                bf16x8 b = *(const bf16x8*)((const char*)&wtab[0][0]
                    + (size_t)(cf * 16 + col) * 128 + (((ks * 4 + quad) ^ c7) * 16));
                acc[cf] = __builtin_amdgcn_mfma_f32_16x16x32_bf16(cv.v, b, acc[cf], 0, 0, 0);
            }
        }
        if (t > 0) {
            #pragma unroll
            for (int ks = 0; ks < 2; ++ks) {
                bf16x8 a = *(const bf16x8*)&hl[wv * 16 + col][ks * 32 + quad * 8];
                #pragma unroll
                for (int cf = 0; cf < 16; ++cf) {
                    bf16x8 b = *(const bf16x8*)((const char*)&wtab[0][0]
                        + (size_t)(256 + cf * 16 + col) * 128 + (((ks * 4 + quad) ^ c7) * 16));
                    acc[cf] = __builtin_amdgcn_mfma_f32_16x16x32_bf16(a, b, acc[cf], 0, 0, 0);
                }
            }
        }

        #pragma unroll
        for (int j = 0; j < 4; ++j) {
            int c = j * 16 + col;
            float bi = biasv[c], bf_ = biasv[64 + c], bg = biasv[128 + c], bo = biasv[192 + c];
            #pragma unroll
            for (int reg = 0; reg < 4; ++reg) {
                float gi = acc[j][reg] + bi;
                float gf = acc[j + 4][reg] + bf_;
                float gg = acc[j + 8][reg] + bg;
                float go = acc[j + 12][reg] + bo;
                float c2 = sigm(gf) * cc[j][reg] + sigm(gi) * ftanh(gg);
                float hh = sigm(go) * ftanh(c2);
                cc[j][reg] = c2;
                u16 hb = f2bf(hh);
                hl[wv * 16 + quad * 4 + reg][c] = hb;
                int rr = rowbase + reg;
                if (rr < N_)
                    feats[(size_t)rr * 256 + t * 64 + c] = hb;
            }
        }
    }
}

// ---------------- temporal causal MHA: MFMA QKV + per-lane attention ----------------
__global__ __launch_bounds__(256) void k_attn(
    const u16* __restrict__ feats, const float* __restrict__ pos_emb,
    const u16* __restrict__ qkv_pad, float* __restrict__ out)
{
    __shared__ float qkv_s[64 * 200];
    const int tid = threadIdx.x, lane = tid & 63, wv = tid >> 6;
    const int col = lane & 15, quad = lane >> 4;
    int m0 = blockIdx.x * 64;
    int row = m0 + wv * 16 + col;
    int trow = row & 3;

    f32x4 acc[12];
    #pragma unroll
    for (int cf = 0; cf < 12; ++cf) { acc[cf][0]=0.f; acc[cf][1]=0.f; acc[cf][2]=0.f; acc[cf][3]=0.f; }
    #pragma unroll
    for (int ks = 0; ks < 2; ++ks) {
        int coff = ks * 32 + quad * 8;
        bf16x8 fv = *(const bf16x8*)(feats + (size_t)row * 64 + coff);
        float4 p0 = *(const float4*)(pos_emb + trow * 64 + coff);
        float4 p1 = *(const float4*)(pos_emb + trow * 64 + coff + 4);
        union { u16 h[8]; bf16x8 v; } cv;
        cv.h[0] = f2bf(bf2f((u16)fv[0]) + p0.x); cv.h[1] = f2bf(bf2f((u16)fv[1]) + p0.y);
        cv.h[2] = f2bf(bf2f((u16)fv[2]) + p0.z); cv.h[3] = f2bf(bf2f((u16)fv[3]) + p0.w);
        cv.h[4] = f2bf(bf2f((u16)fv[4]) + p1.x); cv.h[5] = f2bf(bf2f((u16)fv[5]) + p1.y);
        cv.h[6] = f2bf(bf2f((u16)fv[6]) + p1.z); cv.h[7] = f2bf(bf2f((u16)fv[7]) + p1.w);
        bf16x8 a = cv.v;
        const u16* bb = qkv_pad + ks * 32 + quad * 8;
        #pragma unroll
        for (int cf = 0; cf < 12; ++cf) {
            bf16x8 b = *(const bf16x8*)(bb + (cf * 16 + col) * 64);
            acc[cf] = __builtin_amdgcn_mfma_f32_16x16x32_bf16(a, b, acc[cf], 0, 0, 0);
        }
    }
    #pragma unroll
    for (int cf = 0; cf < 12; ++cf) {
        int g = cf * 16 + col;
        #pragma unroll
        for (int reg = 0; reg < 4; ++reg) {
            int rl = wv * 16 + quad * 4 + reg;
            qkv_s[rl * 200 + g] = acc[cf][reg];
        }
    }
    __syncthreads();

    int nl = wv * 4 + (lane >> 4);
    int sub = lane & 15;
    int h = sub >> 2, tq = sub & 3;
    const float* qrow = qkv_s + (nl * 4 + tq) * 200 + h * 16;

    float s[4];
    #pragma unroll
    for (int tk = 0; tk < 4; ++tk) {
        const float* krow = qkv_s + (nl * 4 + tk) * 200 + 64 + h * 16;
        float d = 0.f;
        #pragma unroll
        for (int j = 0; j < 16; ++j) d += qrow[j] * krow[j];
        s[tk] = (tk > tq) ? -4294967295.0f : d * 0.5f;
    }
    float mx = fmaxf(fmaxf(s[0], s[1]), fmaxf(s[2], s[3]));
    float a0 = __expf(s[0]-mx), a1 = __expf(s[1]-mx), a2 = __expf(s[2]-mx), a3 = __expf(s[3]-mx);
    float inv = 1.f / (a0 + a1 + a2 + a3);
    a0 *= inv; a1 *= inv; a2 *= inv; a3 *= inv;

    int n = blockIdx.x * 16 + nl;
    const float* v0 = qkv_s + (nl * 4 + 0) * 200 + 128 + h * 16;
    const float* v1 = v0 + 200, *v2 = v0 + 400, *v3 = v0 + 600;
    #pragma unroll
    for (int cc4 = 0; cc4 < 4; ++cc4) {
        float4 o;
        o.x = a0*v0[cc4*4+0] + a1*v1[cc4*4+0] + a2*v2[cc4*4+0] + a3*v3[cc4*4+0];
        o.y = a0*v0[cc4*4+1] + a1*v1[cc4*4+1] + a2*v2[cc4*4+1] + a3*v3[cc4*4+1];
        o.z = a0*v0[cc4*4+2] + a1*v1[cc4*4+2] + a2*v2[cc4*4+2] + a3*v3[cc4*4+2];
        o.w = a0*v0[cc4*4+3] + a1*v1[cc4*4+3] + a2*v2[cc4*4+3] + a3*v3[cc4*4+3];
        *(float4*)(out + (size_t)n * 256 + tq * 64 + h * 16 + cc4 * 4) = o;
    }
}

// ---------------- launcher ----------------
extern "C" void kernel_launch(void* const* d_in, const int* in_sizes, int n_in,
                              void* d_out, int out_size, void* d_ws, size_t ws_size,
                              hipStream_t stream) {
    const float* x     = (const float*)d_in[0];
    const int* ei      = (const int*)d_in[1];
    const float* Wsrc  = (const float*)d_in[2];
    const float* Wdst  = (const float*)d_in[3];
    const float* att_src = (const float*)d_in[4];
    const float* att_dst = (const float*)d_in[5];
    const float* raW1  = (const float*)d_in[6];
    const float* rab1  = (const float*)d_in[7];
    const float* raW2  = (const float*)d_in[8];
    const float* Wih   = (const float*)d_in[9];
    const float* Whh   = (const float*)d_in[10];
    const float* bih   = (const float*)d_in[11];
    const float* bhh   = (const float*)d_in[12];
    const float* pos   = (const float*)d_in[13];
    const float* Wq    = (const float*)d_in[14];
    const float* Wk    = (const float*)d_in[15];
    const float* Wv    = (const float*)d_in[16];
    float* out = (float*)d_out;

    char* w = (char*)d_ws;
    size_t off = 0;
    auto alloc = [&](size_t bytes) -> char* {
        char* pp = w + off; off += (bytes + 255) & ~(size_t)255; return pp;
    };
    // ---- long-lived ----
    u16*   intra     = (u16*)  alloc((size_t)T_ * N_ * R_ * 64 * 2);  // 20.48 MB
    u16*   x_h       = (u16*)  alloc((size_t)T_ * N_ * 64 * 2);       // 10.24 MB (f16)
    float* sspart    = (float*)alloc(1024 * 4);   // 64 lines x 16 floats
    float* wdall     = (float*)alloc(1024 * 4);
    float* biasv     = (float*)alloc(256 * 4);
    u16*   raW1_pad  = (u16*)  alloc(BPAD * 2);
    u16*   Wc_pad    = (u16*)  alloc(2 * BPAD * 2);
    u16*   qkv_pad   = (u16*)  alloc(192 * 64 * 2);
    u16*   postB_pad = (u16*)  alloc(2 * 4 * 4096 * 2);
    int*   chunktot  = (int*)  alloc(P_ * NB_ * 4);
    // ---- union region ----
    char*  ubase   = alloc(0);
    size_t uoff = 0;
    auto ualloc = [&](size_t bytes) -> char* {
        char* pp = ubase + uoff; uoff += (bytes + 255) & ~(size_t)255; return pp;
    };
    int*   offsets = (int*)  ualloc((size_t)P_ * (N_ + 1) * 4);
    u16*   csr     = (u16*)  ualloc((size_t)P_ * E_ * 2);
    float* als_all = (float*)ualloc((size_t)P_ * N_ * 4 * 4);
    float* ald_all = (float*)ualloc((size_t)P_ * N_ * 4 * 4);
    u16*   partial = (u16*)  ualloc((size_t)P_ * NB_ * N_ * 2);
    u16*   rank    = (u16*)  ualloc((size_t)P_ * E_ * 2);
    // phase 2 overlay (phase-1 sub-buffers dead after k_agg)
    u16*   feats   = (u16*)  ubase;   // 10.24 MB
    (void)ws_size; (void)in_sizes; (void)n_in; (void)out_size;

    k_prep<<<72, 256, 0, stream>>>(Wdst, att_dst, Wih, Whh, bih, bhh, Wsrc, att_src, raW1,
                                   Wq, Wk, Wv, wdall, biasv, raW1_pad, Wc_pad, qkv_pad,
                                   postB_pad, sspart);
    k_hist<<<dim3(NB_, 8), 256, 0, stream>>>(ei, rank, partial);
    k_scan1<<<dim3(NB_, 8), 256, 0, stream>>>(partial, offsets, chunktot);
    k_scan3<<<dim3(79, 8), 256, 0, stream>>>(offsets, chunktot);
    k_scatter<<<10000, 256, 0, stream>>>(ei, offsets, rank, partial, csr);
    k_fold<<<dim3(313, 4), 256, 0, stream>>>(x, wdall, als_all, ald_all, x_h);
    k_agg<<<10000, 256, 0, stream>>>(offsets, csr, als_all, ald_all, x_h, postB_pad, intra);
    k_relagg<<<2500, 256, 0, stream>>>(intra, raW1_pad, rab1, raW2, sspart);
    k_lstm<<<313, 256, 0, stream>>>(intra, sspart, Wc_pad, biasv, feats);
    k_attn<<<1250, 256, 0, stream>>>(feats, pos, qkv_pad, out);
}